// Round 1
// baseline (5085.109 us; speedup 1.0000x reference)
//
#include <hip/hip_runtime.h>
#include <hip/hip_bf16.h>

#define NFEAT 256
#define NHID 128
#define RELL 86

// ---------------------------------------------------------------------------
// Fused row-blocked GEMM: S_m = X @ W_m for up to 3 weight matrices.
// X: [Nrows, K] row-major, W: [K, 128] row-major, S: [Nrows, 128].
// Block = 128 threads (thread = output col), 32 rows per block staged in LDS.
// ---------------------------------------------------------------------------
template <int K>
__global__ __launch_bounds__(128) void gemm_rk(
    const float* __restrict__ X,
    const float* __restrict__ W0, float* __restrict__ S0,
    const float* __restrict__ W1, float* __restrict__ S1,
    const float* __restrict__ W2, float* __restrict__ S2,
    int nmat, int Nrows)
{
    __shared__ __align__(16) float xs[32 * K];
    const int t = threadIdx.x;
    const long r0 = (long)blockIdx.x * 32;

    if (r0 + 32 <= Nrows) {
        const float4* X4 = (const float4*)(X + r0 * K);
        float4* xs4w = (float4*)xs;
        #pragma unroll 4
        for (int i = t; i < 32 * K / 4; i += 128) xs4w[i] = X4[i];
    } else {
        for (int i = t; i < 32 * K; i += 128) {
            long g = r0 * K + i;
            xs[i] = (g < (long)Nrows * K) ? X[g] : 0.f;
        }
    }
    __syncthreads();

    const float4* xs4 = (const float4*)xs;
    for (int m = 0; m < nmat; ++m) {
        const float* W = (m == 0) ? W0 : ((m == 1) ? W1 : W2);
        float* S = (m == 0) ? S0 : ((m == 1) ? S1 : S2);
        float acc[32];
        #pragma unroll
        for (int r = 0; r < 32; ++r) acc[r] = 0.f;
        for (int kc = 0; kc < K / 4; ++kc) {
            const float w0 = W[(kc * 4 + 0) * 128 + t];
            const float w1 = W[(kc * 4 + 1) * 128 + t];
            const float w2 = W[(kc * 4 + 2) * 128 + t];
            const float w3 = W[(kc * 4 + 3) * 128 + t];
            #pragma unroll
            for (int r = 0; r < 32; ++r) {
                const float4 xv = xs4[r * (K / 4) + kc];
                acc[r] = fmaf(xv.x, w0, acc[r]);
                acc[r] = fmaf(xv.y, w1, acc[r]);
                acc[r] = fmaf(xv.z, w2, acc[r]);
                acc[r] = fmaf(xv.w, w3, acc[r]);
            }
        }
        #pragma unroll
        for (int r = 0; r < 32; ++r) {
            long rr = r0 + r;
            if (rr < Nrows) S[rr * 128 + t] = acc[r];
        }
    }
}

// ---------------------------------------------------------------------------
// SpMM via atomics: acc[rows[e]][:] += vals[e] * S[cols[e]][:]
// One wave (64 lanes) per edge; each lane handles 2 of the 128 features.
// ---------------------------------------------------------------------------
__global__ __launch_bounds__(256) void spmm_atomic(
    const int* __restrict__ rows, const int* __restrict__ cols,
    const float* __restrict__ vals,
    const float* __restrict__ S, float* __restrict__ acc, int E)
{
    const int e = blockIdx.x * 4 + (threadIdx.x >> 6);
    if (e >= E) return;
    const int lane = threadIdx.x & 63;
    const int r = rows[e];
    const int c = cols[e];
    const float v = vals[e];
    const float* srow = S + (size_t)c * 128;
    float* arow = acc + (size_t)r * 128;
    atomicAdd(&arow[lane],      v * srow[lane]);
    atomicAdd(&arow[lane + 64], v * srow[lane + 64]);
}

// acc[i] = b1[i % 128] + b2[i % 128]
__global__ __launch_bounds__(256) void init_bias(
    float* __restrict__ acc, const float* __restrict__ b1,
    const float* __restrict__ b2, long n)
{
    long i = (long)blockIdx.x * 256 + threadIdx.x;
    if (i < n) acc[i] = b1[i & 127] + b2[i & 127];
}

__global__ __launch_bounds__(256) void relu_ip(float* __restrict__ a, long n)
{
    long i = (long)blockIdx.x * 256 + threadIdx.x;
    if (i < n) a[i] = fmaxf(a[i], 0.f);
}

// ---------------------------------------------------------------------------
// Decoder stage 1: out[b] = concat(h[idx0[b]], h[idx1[b]]) @ W + bias  -> [B,128]
// ---------------------------------------------------------------------------
__global__ __launch_bounds__(128) void dec1_kernel(
    const float* __restrict__ h,
    const int* __restrict__ idx0, const int* __restrict__ idx1,
    const float* __restrict__ W, const float* __restrict__ bias,
    float* __restrict__ out, int B)
{
    __shared__ __align__(16) float fs[16 * 256];
    const int t = threadIdx.x;
    const int b0 = blockIdx.x * 16;
    #pragma unroll
    for (int r = 0; r < 16; ++r) {
        const int b = b0 + r;
        fs[r * 256 + t]       = h[(long)idx0[b] * 128 + t];
        fs[r * 256 + 128 + t] = h[(long)idx1[b] * 128 + t];
    }
    __syncthreads();

    const float4* fs4 = (const float4*)fs;
    float acc[16];
    #pragma unroll
    for (int r = 0; r < 16; ++r) acc[r] = 0.f;
    for (int kc = 0; kc < 64; ++kc) {
        const float w0 = W[(kc * 4 + 0) * 128 + t];
        const float w1 = W[(kc * 4 + 1) * 128 + t];
        const float w2 = W[(kc * 4 + 2) * 128 + t];
        const float w3 = W[(kc * 4 + 3) * 128 + t];
        #pragma unroll
        for (int r = 0; r < 16; ++r) {
            const float4 xv = fs4[r * 64 + kc];
            acc[r] = fmaf(xv.x, w0, acc[r]);
            acc[r] = fmaf(xv.y, w1, acc[r]);
            acc[r] = fmaf(xv.z, w2, acc[r]);
            acc[r] = fmaf(xv.w, w3, acc[r]);
        }
    }
    #pragma unroll
    for (int r = 0; r < 16; ++r)
        out[(long)(b0 + r) * 128 + t] = acc[r] + bias[t];
}

// ---------------------------------------------------------------------------
// Decoder stage 2: out[b] = o1[b] @ W + bias  -> [B, 86]
// ---------------------------------------------------------------------------
__global__ __launch_bounds__(128) void dec2_kernel(
    const float* __restrict__ o1,
    const float* __restrict__ W, const float* __restrict__ bias,
    float* __restrict__ out, int B)
{
    __shared__ __align__(16) float os[16 * 128];
    const int t = threadIdx.x;
    const int b0 = blockIdx.x * 16;
    #pragma unroll
    for (int r = 0; r < 16; ++r)
        os[r * 128 + t] = o1[(long)(b0 + r) * 128 + t];
    __syncthreads();

    const float4* os4 = (const float4*)os;
    float acc[16];
    #pragma unroll
    for (int r = 0; r < 16; ++r) acc[r] = 0.f;
    const bool act = (t < RELL);
    for (int kc = 0; kc < 32; ++kc) {
        const float w0 = act ? W[(kc * 4 + 0) * RELL + t] : 0.f;
        const float w1 = act ? W[(kc * 4 + 1) * RELL + t] : 0.f;
        const float w2 = act ? W[(kc * 4 + 2) * RELL + t] : 0.f;
        const float w3 = act ? W[(kc * 4 + 3) * RELL + t] : 0.f;
        #pragma unroll
        for (int r = 0; r < 16; ++r) {
            const float4 xv = os4[r * 32 + kc];
            acc[r] = fmaf(xv.x, w0, acc[r]);
            acc[r] = fmaf(xv.y, w1, acc[r]);
            acc[r] = fmaf(xv.z, w2, acc[r]);
            acc[r] = fmaf(xv.w, w3, acc[r]);
        }
    }
    if (act) {
        #pragma unroll
        for (int r = 0; r < 16; ++r)
            out[(long)(b0 + r) * RELL + t] = acc[r] + bias[t];
    }
}

extern "C" void kernel_launch(void* const* d_in, const int* in_sizes, int n_in,
                              void* d_out, int out_size, void* d_ws, size_t ws_size,
                              hipStream_t stream) {
    const float* x      = (const float*)d_in[0];
    const int*   o_rows = (const int*)  d_in[1];
    const int*   o_cols = (const int*)  d_in[2];
    const float* o_vals = (const float*)d_in[3];
    const int*   s_rows = (const int*)  d_in[4];
    const int*   s_cols = (const int*)  d_in[5];
    const float* s_vals = (const float*)d_in[6];
    const int*   idx    = (const int*)  d_in[7];
    const float* W_ogc1  = (const float*)d_in[8];   const float* b_ogc1  = (const float*)d_in[9];
    const float* W_sgc1o = (const float*)d_in[10];  const float* b_sgc1o = (const float*)d_in[11];
    const float* W_sgc1  = (const float*)d_in[12];  const float* b_sgc1  = (const float*)d_in[13];
    const float* W_ogc1s = (const float*)d_in[14];  const float* b_ogc1s = (const float*)d_in[15];
    const float* W_ogc2  = (const float*)d_in[16];  const float* b_ogc2  = (const float*)d_in[17];
    const float* W_sgc2o = (const float*)d_in[18];  const float* b_sgc2o = (const float*)d_in[19];
    const float* W_dec1  = (const float*)d_in[20];  const float* b_dec1  = (const float*)d_in[21];
    const float* W_dec2  = (const float*)d_in[22];  const float* b_dec2  = (const float*)d_in[23];

    const int N = in_sizes[0] / NFEAT;   // 100000
    const int E = in_sizes[1];           // 1600000
    const int B = in_sizes[7] / 2;       // 16384
    const int* idx0 = idx;
    const int* idx1 = idx + B;

    float* ws = (float*)d_ws;
    const size_t NB = (size_t)N * NHID;
    float* buf0 = ws;            // S1 / S4 / S6
    float* buf1 = ws + NB;       // S2 / acc_sx -> s_x
    float* buf2 = ws + 2 * NB;   // S3 / S5
    float* buf3 = ws + 3 * NB;   // acc_ox -> o_x / acc_h -> h
    float* buf4 = ws + 4 * NB;   // o1 [B,128]

    const long n_acc = (long)N * NHID;
    const int gN = (N + 31) / 32;                 // 3125
    const int gAcc = (int)((n_acc + 255) / 256);  // 50000
    const int gE = (E + 3) / 4;                   // 400000
    const int gB = B / 16;                        // 1024

    // ---- Layer 1: o_x = relu(gcn(x,W_ogc1,o) + gcn(x,W_sgc1o,s)); also S3 = x@W_sgc1
    gemm_rk<NFEAT><<<gN, 128, 0, stream>>>(x, W_ogc1, buf0, W_sgc1o, buf1, W_sgc1, buf2, 3, N);
    init_bias<<<gAcc, 256, 0, stream>>>(buf3, b_ogc1, b_sgc1o, n_acc);
    spmm_atomic<<<gE, 256, 0, stream>>>(o_rows, o_cols, o_vals, buf0, buf3, E);
    spmm_atomic<<<gE, 256, 0, stream>>>(s_rows, s_cols, s_vals, buf1, buf3, E);
    relu_ip<<<gAcc, 256, 0, stream>>>(buf3, n_acc);          // buf3 = o_x

    // ---- Layer 2: s_x = relu(gcn(x,W_sgc1,s) + gcn(o_x,W_ogc1s,o))
    gemm_rk<NHID><<<gN, 128, 0, stream>>>(buf3, W_ogc1s, buf0, nullptr, nullptr, nullptr, nullptr, 1, N);
    init_bias<<<gAcc, 256, 0, stream>>>(buf1, b_sgc1, b_ogc1s, n_acc);
    spmm_atomic<<<gE, 256, 0, stream>>>(s_rows, s_cols, s_vals, buf2, buf1, E);
    spmm_atomic<<<gE, 256, 0, stream>>>(o_rows, o_cols, o_vals, buf0, buf1, E);
    relu_ip<<<gAcc, 256, 0, stream>>>(buf1, n_acc);          // buf1 = s_x

    // ---- Layer 3: h = gcn(o_x,W_ogc2,o) + gcn(s_x,W_sgc2o,s)
    gemm_rk<NHID><<<gN, 128, 0, stream>>>(buf3, W_ogc2, buf2, nullptr, nullptr, nullptr, nullptr, 1, N);
    gemm_rk<NHID><<<gN, 128, 0, stream>>>(buf1, W_sgc2o, buf0, nullptr, nullptr, nullptr, nullptr, 1, N);
    init_bias<<<gAcc, 256, 0, stream>>>(buf3, b_ogc2, b_sgc2o, n_acc);
    spmm_atomic<<<gE, 256, 0, stream>>>(o_rows, o_cols, o_vals, buf2, buf3, E);
    spmm_atomic<<<gE, 256, 0, stream>>>(s_rows, s_cols, s_vals, buf0, buf3, E);  // buf3 = h

    // ---- Decoder
    dec1_kernel<<<gB, 128, 0, stream>>>(buf3, idx0, idx1, W_dec1, b_dec1, buf4, B);
    dec2_kernel<<<gB, 128, 0, stream>>>(buf4, W_dec2, b_dec2, (float*)d_out, B);
}

// Round 2
// 4303.625 us; speedup vs baseline: 1.1816x; 1.1816x over previous
//
#include <hip/hip_runtime.h>
#include <hip/hip_bf16.h>

#define NFEAT 256
#define NHID 128
#define RELL 86

typedef __attribute__((ext_vector_type(8))) short short8v;
typedef __attribute__((ext_vector_type(4))) float float4v;

static __device__ __forceinline__ unsigned short f2bf(float f) {
    union { float f; unsigned int u; } v; v.f = f;
    unsigned int r = v.u + 0x7FFF + ((v.u >> 16) & 1);   // RNE
    return (unsigned short)(r >> 16);
}

// ---------------------------------------------------------------------------
// Weight prep: Wt[col][k] = bf16(W[k][col]).  W: [K,128] fp32 -> Wt: [128,K] bf16
// ---------------------------------------------------------------------------
__global__ __launch_bounds__(256) void wt_prep(
    const float* __restrict__ W, unsigned short* __restrict__ Wt, int K)
{
    int i = blockIdx.x * 256 + threadIdx.x;
    if (i < K * 128) {
        int col = i & 127, k = i >> 7;
        Wt[col * K + k] = f2bf(W[i]);
    }
}

// ---------------------------------------------------------------------------
// MFMA GEMM: S = X @ W, X:[Nrows,K] fp32, Wt:[128,K] bf16 (pre-transposed),
// S:[Nrows,128] fp32.  Block 256 thr (4 waves), tile BM=128 x BN=128, BK=64.
// Wave w owns rows [w*32, w*32+32) of the tile: acc = 2x8 grid of 16x16 frags.
// LDS stride 72 bf16 (144B): 8B-aligned b64 frag reads, 2-way banks (free).
// ---------------------------------------------------------------------------
template <int K>
__global__ __launch_bounds__(256) void gemm_mfma(
    const float* __restrict__ X, const unsigned short* __restrict__ Wt,
    float* __restrict__ S, int Nrows)
{
    __shared__ unsigned short As[128 * 72];
    __shared__ unsigned short Bs[128 * 72];

    const int t = threadIdx.x;
    const int l = t & 63;
    const int w = t >> 6;
    const int row_in = l & 15;
    const int kgrp = l >> 4;        // 0..3
    const int wr0 = w * 32;
    const int row0 = blockIdx.x * 128;

    float4v acc[2][8];
    #pragma unroll
    for (int m = 0; m < 2; ++m)
        #pragma unroll
        for (int n = 0; n < 8; ++n)
            acc[m][n] = (float4v)(0.f);

    for (int kt = 0; kt < K / 64; ++kt) {
        if (kt > 0) __syncthreads();
        // stage A chunk: 128 rows x 64 k, fp32 -> bf16
        #pragma unroll
        for (int it = 0; it < 8; ++it) {
            int i = t + it * 256;           // 0..2047
            int r = i >> 4, c4 = i & 15;
            int gr = row0 + r;
            float4 v = make_float4(0.f, 0.f, 0.f, 0.f);
            if (gr < Nrows)
                v = *(const float4*)(X + (size_t)gr * K + kt * 64 + c4 * 4);
            ushort4 b4;
            b4.x = f2bf(v.x); b4.y = f2bf(v.y); b4.z = f2bf(v.z); b4.w = f2bf(v.w);
            *(ushort4*)&As[r * 72 + c4 * 4] = b4;
        }
        // stage B chunk: Wt[128 cols][64 k] bf16 straight copy
        #pragma unroll
        for (int it = 0; it < 8; ++it) {
            int i = t + it * 256;
            int r = i >> 4, c4 = i & 15;
            *(ushort4*)&Bs[r * 72 + c4 * 4] =
                *(const ushort4*)(Wt + (size_t)r * K + kt * 64 + c4 * 4);
        }
        __syncthreads();

        #pragma unroll
        for (int kc = 0; kc < 2; ++kc) {
            short8v a[2], b[8];
            #pragma unroll
            for (int m = 0; m < 2; ++m) {
                const unsigned short* p =
                    &As[(wr0 + m * 16 + row_in) * 72 + kc * 32 + kgrp * 8];
                ((uint2*)&a[m])[0] = *(const uint2*)p;
                ((uint2*)&a[m])[1] = *(const uint2*)(p + 4);
            }
            #pragma unroll
            for (int n = 0; n < 8; ++n) {
                const unsigned short* p =
                    &Bs[(n * 16 + row_in) * 72 + kc * 32 + kgrp * 8];
                ((uint2*)&b[n])[0] = *(const uint2*)p;
                ((uint2*)&b[n])[1] = *(const uint2*)(p + 4);
            }
            #pragma unroll
            for (int m = 0; m < 2; ++m)
                #pragma unroll
                for (int n = 0; n < 8; ++n)
                    acc[m][n] = __builtin_amdgcn_mfma_f32_16x16x32_bf16(
                        a[m], b[n], acc[m][n], 0, 0, 0);
        }
    }

    // epilogue: C/D layout col=lane&15, row=(lane>>4)*4+reg
    #pragma unroll
    for (int m = 0; m < 2; ++m)
        #pragma unroll
        for (int n = 0; n < 8; ++n)
            #pragma unroll
            for (int r = 0; r < 4; ++r) {
                int gr = row0 + wr0 + m * 16 + kgrp * 4 + r;
                int gc = n * 16 + row_in;
                if (gr < Nrows) S[(size_t)gr * 128 + gc] = acc[m][n][r];
            }
}

// ---------------------------------------------------------------------------
// SpMM via atomics: acc[rows[e]][:] += vals[e] * S[cols[e]][:]
// ---------------------------------------------------------------------------
__global__ __launch_bounds__(256) void spmm_atomic(
    const int* __restrict__ rows, const int* __restrict__ cols,
    const float* __restrict__ vals,
    const float* __restrict__ S, float* __restrict__ acc, int E)
{
    const int e = blockIdx.x * 4 + (threadIdx.x >> 6);
    if (e >= E) return;
    const int lane = threadIdx.x & 63;
    const int r = rows[e];
    const int c = cols[e];
    const float v = vals[e];
    const float* srow = S + (size_t)c * 128;
    float* arow = acc + (size_t)r * 128;
    atomicAdd(&arow[lane],      v * srow[lane]);
    atomicAdd(&arow[lane + 64], v * srow[lane + 64]);
}

__global__ __launch_bounds__(256) void init_bias(
    float* __restrict__ acc, const float* __restrict__ b1,
    const float* __restrict__ b2, long n)
{
    long i = (long)blockIdx.x * 256 + threadIdx.x;
    if (i < n) acc[i] = b1[i & 127] + b2[i & 127];
}

__global__ __launch_bounds__(256) void relu_ip(float* __restrict__ a, long n)
{
    long i = (long)blockIdx.x * 256 + threadIdx.x;
    if (i < n) a[i] = fmaxf(a[i], 0.f);
}

// ---------------------------------------------------------------------------
// Decoder stage 1: out[b] = concat(h[idx0[b]], h[idx1[b]]) @ W + bias -> [B,128]
// ---------------------------------------------------------------------------
__global__ __launch_bounds__(128) void dec1_kernel(
    const float* __restrict__ h,
    const int* __restrict__ idx0, const int* __restrict__ idx1,
    const float* __restrict__ W, const float* __restrict__ bias,
    float* __restrict__ out, int B)
{
    __shared__ __align__(16) float fs[16 * 256];
    const int t = threadIdx.x;
    const int b0 = blockIdx.x * 16;
    #pragma unroll
    for (int r = 0; r < 16; ++r) {
        const int b = b0 + r;
        fs[r * 256 + t]       = h[(long)idx0[b] * 128 + t];
        fs[r * 256 + 128 + t] = h[(long)idx1[b] * 128 + t];
    }
    __syncthreads();

    const float4* fs4 = (const float4*)fs;
    float acc[16];
    #pragma unroll
    for (int r = 0; r < 16; ++r) acc[r] = 0.f;
    for (int kc = 0; kc < 64; ++kc) {
        const float w0 = W[(kc * 4 + 0) * 128 + t];
        const float w1 = W[(kc * 4 + 1) * 128 + t];
        const float w2 = W[(kc * 4 + 2) * 128 + t];
        const float w3 = W[(kc * 4 + 3) * 128 + t];
        #pragma unroll
        for (int r = 0; r < 16; ++r) {
            const float4 xv = fs4[r * 64 + kc];
            acc[r] = fmaf(xv.x, w0, acc[r]);
            acc[r] = fmaf(xv.y, w1, acc[r]);
            acc[r] = fmaf(xv.z, w2, acc[r]);
            acc[r] = fmaf(xv.w, w3, acc[r]);
        }
    }
    #pragma unroll
    for (int r = 0; r < 16; ++r)
        out[(long)(b0 + r) * 128 + t] = acc[r] + bias[t];
}

// ---------------------------------------------------------------------------
// Decoder stage 2: out[b] = o1[b] @ W + bias -> [B, 86]
// ---------------------------------------------------------------------------
__global__ __launch_bounds__(128) void dec2_kernel(
    const float* __restrict__ o1,
    const float* __restrict__ W, const float* __restrict__ bias,
    float* __restrict__ out, int B)
{
    __shared__ __align__(16) float os[16 * 128];
    const int t = threadIdx.x;
    const int b0 = blockIdx.x * 16;
    #pragma unroll
    for (int r = 0; r < 16; ++r)
        os[r * 128 + t] = o1[(long)(b0 + r) * 128 + t];
    __syncthreads();

    const float4* os4 = (const float4*)os;
    float acc[16];
    #pragma unroll
    for (int r = 0; r < 16; ++r) acc[r] = 0.f;
    const bool act = (t < RELL);
    for (int kc = 0; kc < 32; ++kc) {
        const float w0 = act ? W[(kc * 4 + 0) * RELL + t] : 0.f;
        const float w1 = act ? W[(kc * 4 + 1) * RELL + t] : 0.f;
        const float w2 = act ? W[(kc * 4 + 2) * RELL + t] : 0.f;
        const float w3 = act ? W[(kc * 4 + 3) * RELL + t] : 0.f;
        #pragma unroll
        for (int r = 0; r < 16; ++r) {
            const float4 xv = os4[r * 32 + kc];
            acc[r] = fmaf(xv.x, w0, acc[r]);
            acc[r] = fmaf(xv.y, w1, acc[r]);
            acc[r] = fmaf(xv.z, w2, acc[r]);
            acc[r] = fmaf(xv.w, w3, acc[r]);
        }
    }
    if (act) {
        #pragma unroll
        for (int r = 0; r < 16; ++r)
            out[(long)(b0 + r) * RELL + t] = acc[r] + bias[t];
    }
}

extern "C" void kernel_launch(void* const* d_in, const int* in_sizes, int n_in,
                              void* d_out, int out_size, void* d_ws, size_t ws_size,
                              hipStream_t stream) {
    const float* x      = (const float*)d_in[0];
    const int*   o_rows = (const int*)  d_in[1];
    const int*   o_cols = (const int*)  d_in[2];
    const float* o_vals = (const float*)d_in[3];
    const int*   s_rows = (const int*)  d_in[4];
    const int*   s_cols = (const int*)  d_in[5];
    const float* s_vals = (const float*)d_in[6];
    const int*   idx    = (const int*)  d_in[7];
    const float* W_ogc1  = (const float*)d_in[8];   const float* b_ogc1  = (const float*)d_in[9];
    const float* W_sgc1o = (const float*)d_in[10];  const float* b_sgc1o = (const float*)d_in[11];
    const float* W_sgc1  = (const float*)d_in[12];  const float* b_sgc1  = (const float*)d_in[13];
    const float* W_ogc1s = (const float*)d_in[14];  const float* b_ogc1s = (const float*)d_in[15];
    const float* W_ogc2  = (const float*)d_in[16];  const float* b_ogc2  = (const float*)d_in[17];
    const float* W_sgc2o = (const float*)d_in[18];  const float* b_sgc2o = (const float*)d_in[19];
    const float* W_dec1  = (const float*)d_in[20];  const float* b_dec1  = (const float*)d_in[21];
    const float* W_dec2  = (const float*)d_in[22];  const float* b_dec2  = (const float*)d_in[23];

    const int N = in_sizes[0] / NFEAT;   // 100000
    const int E = in_sizes[1];           // 1600000
    const int B = in_sizes[7] / 2;       // 16384
    const int* idx0 = idx;
    const int* idx1 = idx + B;

    float* ws = (float*)d_ws;
    const size_t NB = (size_t)N * NHID;
    float* buf0 = ws;            // S1 / S4 / S6 / o1
    float* buf1 = ws + NB;       // S2 / acc_sx -> s_x
    float* buf2 = ws + 2 * NB;   // S3 / S5
    float* buf3 = ws + 3 * NB;   // acc_ox -> o_x / acc_h -> h

    // bf16 transposed weights live where buf4 used to be (freed before decoder)
    unsigned short* wt1 = (unsigned short*)(ws + 4 * NB);     // [128,256]
    unsigned short* wt2 = wt1 + 128 * 256;                    // [128,256]
    unsigned short* wt3 = wt2 + 128 * 256;                    // [128,256]
    unsigned short* wt4 = wt3 + 128 * 256;                    // [128,128]
    unsigned short* wt5 = wt4 + 128 * 128;
    unsigned short* wt6 = wt5 + 128 * 128;

    const long n_acc = (long)N * NHID;
    const int gM = (N + 127) / 128;               // 782
    const int gAcc = (int)((n_acc + 255) / 256);  // 50000
    const int gE = (E + 3) / 4;                   // 400000
    const int gB = B / 16;                        // 1024

    // ---- weight prep (bf16 transpose)
    wt_prep<<<(NFEAT * 128 + 255) / 256, 256, 0, stream>>>(W_ogc1, wt1, NFEAT);
    wt_prep<<<(NFEAT * 128 + 255) / 256, 256, 0, stream>>>(W_sgc1o, wt2, NFEAT);
    wt_prep<<<(NFEAT * 128 + 255) / 256, 256, 0, stream>>>(W_sgc1, wt3, NFEAT);
    wt_prep<<<(NHID * 128 + 255) / 256, 256, 0, stream>>>(W_ogc1s, wt4, NHID);
    wt_prep<<<(NHID * 128 + 255) / 256, 256, 0, stream>>>(W_ogc2, wt5, NHID);
    wt_prep<<<(NHID * 128 + 255) / 256, 256, 0, stream>>>(W_sgc2o, wt6, NHID);

    // ---- Layer 1: o_x = relu(gcn(x,W_ogc1,o) + gcn(x,W_sgc1o,s)); also S3 = x@W_sgc1
    gemm_mfma<NFEAT><<<gM, 256, 0, stream>>>(x, wt1, buf0, N);
    gemm_mfma<NFEAT><<<gM, 256, 0, stream>>>(x, wt2, buf1, N);
    gemm_mfma<NFEAT><<<gM, 256, 0, stream>>>(x, wt3, buf2, N);
    init_bias<<<gAcc, 256, 0, stream>>>(buf3, b_ogc1, b_sgc1o, n_acc);
    spmm_atomic<<<gE, 256, 0, stream>>>(o_rows, o_cols, o_vals, buf0, buf3, E);
    spmm_atomic<<<gE, 256, 0, stream>>>(s_rows, s_cols, s_vals, buf1, buf3, E);
    relu_ip<<<gAcc, 256, 0, stream>>>(buf3, n_acc);          // buf3 = o_x

    // ---- Layer 2: s_x = relu(gcn(x,W_sgc1,s) + gcn(o_x,W_ogc1s,o))
    gemm_mfma<NHID><<<gM, 256, 0, stream>>>(buf3, wt4, buf0, N);
    init_bias<<<gAcc, 256, 0, stream>>>(buf1, b_sgc1, b_ogc1s, n_acc);
    spmm_atomic<<<gE, 256, 0, stream>>>(s_rows, s_cols, s_vals, buf2, buf1, E);
    spmm_atomic<<<gE, 256, 0, stream>>>(o_rows, o_cols, o_vals, buf0, buf1, E);
    relu_ip<<<gAcc, 256, 0, stream>>>(buf1, n_acc);          // buf1 = s_x

    // ---- Layer 3: h = gcn(o_x,W_ogc2,o) + gcn(s_x,W_sgc2o,s)
    gemm_mfma<NHID><<<gM, 256, 0, stream>>>(buf3, wt5, buf2, N);
    gemm_mfma<NHID><<<gM, 256, 0, stream>>>(buf1, wt6, buf0, N);
    init_bias<<<gAcc, 256, 0, stream>>>(buf3, b_ogc2, b_sgc2o, n_acc);
    spmm_atomic<<<gE, 256, 0, stream>>>(o_rows, o_cols, o_vals, buf2, buf3, E);
    spmm_atomic<<<gE, 256, 0, stream>>>(s_rows, s_cols, s_vals, buf0, buf3, E);  // buf3 = h

    // ---- Decoder (o1 goes into buf0, free after last spmm)
    dec1_kernel<<<gB, 128, 0, stream>>>(buf3, idx0, idx1, W_dec1, b_dec1, buf0, B);
    dec2_kernel<<<gB, 128, 0, stream>>>(buf0, W_dec2, b_dec2, (float*)d_out, B);
}

// Round 3
// 1711.999 us; speedup vs baseline: 2.9703x; 2.5138x over previous
//
#include <hip/hip_runtime.h>
#include <hip/hip_bf16.h>

#define NFEAT 256
#define NHID 128
#define RELL 86

typedef __attribute__((ext_vector_type(8))) short short8v;
typedef __attribute__((ext_vector_type(4))) float float4v;

static __device__ __forceinline__ unsigned short f2bf(float f) {
    union { float f; unsigned int u; } v; v.f = f;
    unsigned int r = v.u + 0x7FFF + ((v.u >> 16) & 1);   // RNE
    return (unsigned short)(r >> 16);
}
static __device__ __forceinline__ float asf(unsigned int u) {
    union { unsigned int u; float f; } v; v.u = u; return v.f;
}

// ---------------------------------------------------------------------------
// Weight prep: Wt[col][k] = bf16(W[k][col]).  W: [K,128] fp32 -> Wt: [128,K] bf16
// ---------------------------------------------------------------------------
__global__ __launch_bounds__(256) void wt_prep(
    const float* __restrict__ W, unsigned short* __restrict__ Wt, int K)
{
    int i = blockIdx.x * 256 + threadIdx.x;
    if (i < K * 128) {
        int col = i & 127, k = i >> 7;
        Wt[col * K + k] = f2bf(W[i]);
    }
}

// ---------------------------------------------------------------------------
// CSR build: histogram -> single-block scan -> scatter
// ---------------------------------------------------------------------------
__global__ __launch_bounds__(256) void hist_kernel(
    const int* __restrict__ rows, int* __restrict__ cnt, int E)
{
    int e = blockIdx.x * 256 + threadIdx.x;
    if (e < E) atomicAdd(&cnt[rows[e]], 1);
}

// cnt_cur: in = per-row counts, out = cursor (== exclusive prefix). rp gets prefix, rp[N]=E.
__global__ __launch_bounds__(1024) void scan_kernel(
    int* __restrict__ cnt_cur, int* __restrict__ rp, int N)
{
    __shared__ int part[1024];
    const int t = threadIdx.x;
    const int chunk = (N + 1023) / 1024;
    const int begin = t * chunk;
    const int end = min(begin + chunk, N);
    int s = 0;
    for (int i = begin; i < end; ++i) s += cnt_cur[i];
    part[t] = s;
    __syncthreads();
    for (int off = 1; off < 1024; off <<= 1) {
        int v = (t >= off) ? part[t - off] : 0;
        __syncthreads();
        part[t] += v;
        __syncthreads();
    }
    int run = part[t] - s;          // exclusive base for this thread's chunk
    for (int i = begin; i < end; ++i) {
        int c = cnt_cur[i];
        rp[i] = run;
        cnt_cur[i] = run;           // cursor copy for scatter
        run += c;
    }
    if (t == 1023) rp[N] = run;     // == E
}

__global__ __launch_bounds__(256) void scatter_kernel(
    const int* __restrict__ rows, const int* __restrict__ cols,
    const float* __restrict__ vals, int* __restrict__ cursor,
    int* __restrict__ sc, float* __restrict__ sv, int E)
{
    int e = blockIdx.x * 256 + threadIdx.x;
    if (e < E) {
        int r = rows[e];
        int p = atomicAdd(&cursor[r], 1);
        sc[p] = cols[e];
        sv[p] = vals[e];
    }
}

// ---------------------------------------------------------------------------
// MFMA GEMM: S = X @ W, X:[Nrows,K] fp32, Wt:[128,K] bf16 (pre-transposed),
// S:[Nrows,128] bf16.  Block 256 thr (4 waves), tile 128x128, BK=64.
// ---------------------------------------------------------------------------
template <int K>
__global__ __launch_bounds__(256) void gemm_mfma(
    const float* __restrict__ X, const unsigned short* __restrict__ Wt,
    unsigned short* __restrict__ S, int Nrows)
{
    __shared__ unsigned short As[128 * 72];
    __shared__ unsigned short Bs[128 * 72];

    const int t = threadIdx.x;
    const int l = t & 63;
    const int w = t >> 6;
    const int row_in = l & 15;
    const int kgrp = l >> 4;        // 0..3
    const int wr0 = w * 32;
    const int row0 = blockIdx.x * 128;

    float4v acc[2][8];
    #pragma unroll
    for (int m = 0; m < 2; ++m)
        #pragma unroll
        for (int n = 0; n < 8; ++n)
            acc[m][n] = (float4v)(0.f);

    for (int kt = 0; kt < K / 64; ++kt) {
        if (kt > 0) __syncthreads();
        #pragma unroll
        for (int it = 0; it < 8; ++it) {
            int i = t + it * 256;           // 0..2047
            int r = i >> 4, c4 = i & 15;
            int gr = row0 + r;
            float4 v = make_float4(0.f, 0.f, 0.f, 0.f);
            if (gr < Nrows)
                v = *(const float4*)(X + (size_t)gr * K + kt * 64 + c4 * 4);
            ushort4 b4;
            b4.x = f2bf(v.x); b4.y = f2bf(v.y); b4.z = f2bf(v.z); b4.w = f2bf(v.w);
            *(ushort4*)&As[r * 72 + c4 * 4] = b4;
        }
        #pragma unroll
        for (int it = 0; it < 8; ++it) {
            int i = t + it * 256;
            int r = i >> 4, c4 = i & 15;
            *(ushort4*)&Bs[r * 72 + c4 * 4] =
                *(const ushort4*)(Wt + (size_t)r * K + kt * 64 + c4 * 4);
        }
        __syncthreads();

        #pragma unroll
        for (int kc = 0; kc < 2; ++kc) {
            short8v a[2], b[8];
            #pragma unroll
            for (int m = 0; m < 2; ++m) {
                const unsigned short* p =
                    &As[(wr0 + m * 16 + row_in) * 72 + kc * 32 + kgrp * 8];
                ((uint2*)&a[m])[0] = *(const uint2*)p;
                ((uint2*)&a[m])[1] = *(const uint2*)(p + 4);
            }
            #pragma unroll
            for (int n = 0; n < 8; ++n) {
                const unsigned short* p =
                    &Bs[(n * 16 + row_in) * 72 + kc * 32 + kgrp * 8];
                ((uint2*)&b[n])[0] = *(const uint2*)p;
                ((uint2*)&b[n])[1] = *(const uint2*)(p + 4);
            }
            #pragma unroll
            for (int m = 0; m < 2; ++m)
                #pragma unroll
                for (int n = 0; n < 8; ++n)
                    acc[m][n] = __builtin_amdgcn_mfma_f32_16x16x32_bf16(
                        a[m], b[n], acc[m][n], 0, 0, 0);
        }
    }

    // epilogue: C/D layout col=lane&15, row=(lane>>4)*4+reg; write bf16
    #pragma unroll
    for (int m = 0; m < 2; ++m)
        #pragma unroll
        for (int n = 0; n < 8; ++n)
            #pragma unroll
            for (int r = 0; r < 4; ++r) {
                int gr = row0 + wr0 + m * 16 + kgrp * 4 + r;
                int gc = n * 16 + row_in;
                if (gr < Nrows) S[(size_t)gr * 128 + gc] = f2bf(acc[m][n][r]);
            }
}

// ---------------------------------------------------------------------------
// Fused dual-graph CSR SpMM: out[row] = maybe_relu(b1+b2 + sum_A + sum_B)
// One wave per row; lane l owns features 2l, 2l+1. Tables are bf16.
// ---------------------------------------------------------------------------
__global__ __launch_bounds__(256) void spmm2_csr(
    const int* __restrict__ rp_a, const int* __restrict__ cs_a,
    const float* __restrict__ vs_a, const unsigned short* __restrict__ Sa,
    const int* __restrict__ rp_b, const int* __restrict__ cs_b,
    const float* __restrict__ vs_b, const unsigned short* __restrict__ Sb,
    const float* __restrict__ b1, const float* __restrict__ b2,
    float* __restrict__ out, int N, int do_relu)
{
    const int row = blockIdx.x * 4 + (threadIdx.x >> 6);
    if (row >= N) return;
    const int l = threadIdx.x & 63;

    float2 bv1 = *(const float2*)(b1 + 2 * l);
    float2 bv2 = *(const float2*)(b2 + 2 * l);
    float ax = bv1.x + bv2.x;
    float ay = bv1.y + bv2.y;

    // graph A
    {
        int e0 = rp_a[row], e1 = rp_a[row + 1];
        int c = 0; float v = 0.f;
        if (e0 < e1) { c = cs_a[e0]; v = vs_a[e0]; }
        for (int e = e0; e < e1; ++e) {
            int cc = c; float vv = v;
            if (e + 1 < e1) { c = cs_a[e + 1]; v = vs_a[e + 1]; }
            unsigned int u = *(const unsigned int*)(Sa + ((size_t)cc << 7) + (l << 1));
            ax = fmaf(vv, asf(u << 16), ax);
            ay = fmaf(vv, asf(u & 0xffff0000u), ay);
        }
    }
    // graph B
    {
        int e0 = rp_b[row], e1 = rp_b[row + 1];
        int c = 0; float v = 0.f;
        if (e0 < e1) { c = cs_b[e0]; v = vs_b[e0]; }
        for (int e = e0; e < e1; ++e) {
            int cc = c; float vv = v;
            if (e + 1 < e1) { c = cs_b[e + 1]; v = vs_b[e + 1]; }
            unsigned int u = *(const unsigned int*)(Sb + ((size_t)cc << 7) + (l << 1));
            ax = fmaf(vv, asf(u << 16), ax);
            ay = fmaf(vv, asf(u & 0xffff0000u), ay);
        }
    }
    if (do_relu) { ax = fmaxf(ax, 0.f); ay = fmaxf(ay, 0.f); }
    float2 o; o.x = ax; o.y = ay;
    *(float2*)(out + ((size_t)row << 7) + (l << 1)) = o;
}

// ---------------------------------------------------------------------------
// Decoder stage 1: out[b] = concat(h[idx0[b]], h[idx1[b]]) @ W + bias -> [B,128]
// ---------------------------------------------------------------------------
__global__ __launch_bounds__(128) void dec1_kernel(
    const float* __restrict__ h,
    const int* __restrict__ idx0, const int* __restrict__ idx1,
    const float* __restrict__ W, const float* __restrict__ bias,
    float* __restrict__ out, int B)
{
    __shared__ __align__(16) float fs[16 * 256];
    const int t = threadIdx.x;
    const int b0 = blockIdx.x * 16;
    #pragma unroll
    for (int r = 0; r < 16; ++r) {
        const int b = b0 + r;
        fs[r * 256 + t]       = h[(long)idx0[b] * 128 + t];
        fs[r * 256 + 128 + t] = h[(long)idx1[b] * 128 + t];
    }
    __syncthreads();

    const float4* fs4 = (const float4*)fs;
    float acc[16];
    #pragma unroll
    for (int r = 0; r < 16; ++r) acc[r] = 0.f;
    for (int kc = 0; kc < 64; ++kc) {
        const float w0 = W[(kc * 4 + 0) * 128 + t];
        const float w1 = W[(kc * 4 + 1) * 128 + t];
        const float w2 = W[(kc * 4 + 2) * 128 + t];
        const float w3 = W[(kc * 4 + 3) * 128 + t];
        #pragma unroll
        for (int r = 0; r < 16; ++r) {
            const float4 xv = fs4[r * 64 + kc];
            acc[r] = fmaf(xv.x, w0, acc[r]);
            acc[r] = fmaf(xv.y, w1, acc[r]);
            acc[r] = fmaf(xv.z, w2, acc[r]);
            acc[r] = fmaf(xv.w, w3, acc[r]);
        }
    }
    #pragma unroll
    for (int r = 0; r < 16; ++r)
        out[(long)(b0 + r) * 128 + t] = acc[r] + bias[t];
}

// ---------------------------------------------------------------------------
// Decoder stage 2: out[b] = o1[b] @ W + bias -> [B, 86]
// ---------------------------------------------------------------------------
__global__ __launch_bounds__(128) void dec2_kernel(
    const float* __restrict__ o1,
    const float* __restrict__ W, const float* __restrict__ bias,
    float* __restrict__ out, int B)
{
    __shared__ __align__(16) float os[16 * 128];
    const int t = threadIdx.x;
    const int b0 = blockIdx.x * 16;
    #pragma unroll
    for (int r = 0; r < 16; ++r)
        os[r * 128 + t] = o1[(long)(b0 + r) * 128 + t];
    __syncthreads();

    const float4* os4 = (const float4*)os;
    float acc[16];
    #pragma unroll
    for (int r = 0; r < 16; ++r) acc[r] = 0.f;
    const bool act = (t < RELL);
    for (int kc = 0; kc < 32; ++kc) {
        const float w0 = act ? W[(kc * 4 + 0) * RELL + t] : 0.f;
        const float w1 = act ? W[(kc * 4 + 1) * RELL + t] : 0.f;
        const float w2 = act ? W[(kc * 4 + 2) * RELL + t] : 0.f;
        const float w3 = act ? W[(kc * 4 + 3) * RELL + t] : 0.f;
        #pragma unroll
        for (int r = 0; r < 16; ++r) {
            const float4 xv = os4[r * 32 + kc];
            acc[r] = fmaf(xv.x, w0, acc[r]);
            acc[r] = fmaf(xv.y, w1, acc[r]);
            acc[r] = fmaf(xv.z, w2, acc[r]);
            acc[r] = fmaf(xv.w, w3, acc[r]);
        }
    }
    if (act) {
        #pragma unroll
        for (int r = 0; r < 16; ++r)
            out[(long)(b0 + r) * RELL + t] = acc[r] + bias[t];
    }
}

extern "C" void kernel_launch(void* const* d_in, const int* in_sizes, int n_in,
                              void* d_out, int out_size, void* d_ws, size_t ws_size,
                              hipStream_t stream) {
    const float* x      = (const float*)d_in[0];
    const int*   o_rows = (const int*)  d_in[1];
    const int*   o_cols = (const int*)  d_in[2];
    const float* o_vals = (const float*)d_in[3];
    const int*   s_rows = (const int*)  d_in[4];
    const int*   s_cols = (const int*)  d_in[5];
    const float* s_vals = (const float*)d_in[6];
    const int*   idx    = (const int*)  d_in[7];
    const float* W_ogc1  = (const float*)d_in[8];   const float* b_ogc1  = (const float*)d_in[9];
    const float* W_sgc1o = (const float*)d_in[10];  const float* b_sgc1o = (const float*)d_in[11];
    const float* W_sgc1  = (const float*)d_in[12];  const float* b_sgc1  = (const float*)d_in[13];
    const float* W_ogc1s = (const float*)d_in[14];  const float* b_ogc1s = (const float*)d_in[15];
    const float* W_ogc2  = (const float*)d_in[16];  const float* b_ogc2  = (const float*)d_in[17];
    const float* W_sgc2o = (const float*)d_in[18];  const float* b_sgc2o = (const float*)d_in[19];
    const float* W_dec1  = (const float*)d_in[20];  const float* b_dec1  = (const float*)d_in[21];
    const float* W_dec2  = (const float*)d_in[22];  const float* b_dec2  = (const float*)d_in[23];

    const int N = in_sizes[0] / NFEAT;   // 100000
    const int E = in_sizes[1];           // 1600000
    const int B = in_sizes[7] / 2;       // 16384
    const int* idx0 = idx;
    const int* idx1 = idx + B;

    float* ws = (float*)d_ws;
    const size_t NB = (size_t)N * NHID;

    float* nodeA = ws;                                   // o_x, later h  [N,128] fp32
    float* nodeB = ws + NB;                              // s_x           [N,128] fp32
    unsigned short* tabO = (unsigned short*)(ws + 2 * NB);   // o-graph operand [N,128] bf16
    unsigned short* tabS = tabO + NB;                        // s-graph operand [N,128] bf16
    float* o1buf = (float*)(tabS + NB);                  // dec1 out [B,128] fp32
    unsigned short* wt1 = (unsigned short*)(o1buf + (size_t)B * 128);
    unsigned short* wt2 = wt1 + 128 * 256;
    unsigned short* wt3 = wt2 + 128 * 256;
    unsigned short* wt4 = wt3 + 128 * 256;               // [128,128]
    unsigned short* wt5 = wt4 + 128 * 128;
    unsigned short* wt6 = wt5 + 128 * 128;
    int* rp_o  = (int*)(wt6 + 128 * 128);                // [N+1]
    int* cur_o = rp_o + (N + 1);                         // [N] counts->cursor
    int* sc_o  = cur_o + N;                              // [E]
    float* sv_o = (float*)(sc_o + E);                    // [E]
    int* rp_s  = (int*)(sv_o + E);
    int* cur_s = rp_s + (N + 1);
    int* sc_s  = cur_s + N;
    float* sv_s = (float*)(sc_s + E);

    const int gM = (N + 127) / 128;       // 782
    const int gE = (E + 255) / 256;       // 6250
    const int gR = (N + 3) / 4;           // 25000
    const int gB = B / 16;                // 1024

    // ---- CSR build for both graphs
    hipMemsetAsync(cur_o, 0, (size_t)N * sizeof(int), stream);
    hipMemsetAsync(cur_s, 0, (size_t)N * sizeof(int), stream);
    hist_kernel<<<gE, 256, 0, stream>>>(o_rows, cur_o, E);
    hist_kernel<<<gE, 256, 0, stream>>>(s_rows, cur_s, E);
    scan_kernel<<<1, 1024, 0, stream>>>(cur_o, rp_o, N);
    scan_kernel<<<1, 1024, 0, stream>>>(cur_s, rp_s, N);
    scatter_kernel<<<gE, 256, 0, stream>>>(o_rows, o_cols, o_vals, cur_o, sc_o, sv_o, E);
    scatter_kernel<<<gE, 256, 0, stream>>>(s_rows, s_cols, s_vals, cur_s, sc_s, sv_s, E);

    // ---- weight prep (bf16 transpose)
    wt_prep<<<(NFEAT * 128 + 255) / 256, 256, 0, stream>>>(W_ogc1, wt1, NFEAT);
    wt_prep<<<(NFEAT * 128 + 255) / 256, 256, 0, stream>>>(W_sgc1o, wt2, NFEAT);
    wt_prep<<<(NFEAT * 128 + 255) / 256, 256, 0, stream>>>(W_sgc1, wt3, NFEAT);
    wt_prep<<<(NHID * 128 + 255) / 256, 256, 0, stream>>>(W_ogc1s, wt4, NHID);
    wt_prep<<<(NHID * 128 + 255) / 256, 256, 0, stream>>>(W_ogc2, wt5, NHID);
    wt_prep<<<(NHID * 128 + 255) / 256, 256, 0, stream>>>(W_sgc2o, wt6, NHID);

    // ---- Layer 1: o_x = relu(spmm_o(x@W_ogc1) + spmm_s(x@W_sgc1o) + b)
    gemm_mfma<NFEAT><<<gM, 256, 0, stream>>>(x, wt1, tabO, N);
    gemm_mfma<NFEAT><<<gM, 256, 0, stream>>>(x, wt2, tabS, N);
    spmm2_csr<<<gR, 256, 0, stream>>>(rp_o, sc_o, sv_o, tabO, rp_s, sc_s, sv_s, tabS,
                                      b_ogc1, b_sgc1o, nodeA, N, 1);   // o_x

    // ---- Layer 2: s_x = relu(spmm_s(x@W_sgc1) + spmm_o(o_x@W_ogc1s) + b)
    gemm_mfma<NFEAT><<<gM, 256, 0, stream>>>(x, wt3, tabS, N);
    gemm_mfma<NHID><<<gM, 256, 0, stream>>>(nodeA, wt4, tabO, N);
    spmm2_csr<<<gR, 256, 0, stream>>>(rp_o, sc_o, sv_o, tabO, rp_s, sc_s, sv_s, tabS,
                                      b_ogc1s, b_sgc1, nodeB, N, 1);   // s_x

    // ---- Layer 3: h = spmm_o(o_x@W_ogc2) + spmm_s(s_x@W_sgc2o) + b
    gemm_mfma<NHID><<<gM, 256, 0, stream>>>(nodeA, wt5, tabO, N);
    gemm_mfma<NHID><<<gM, 256, 0, stream>>>(nodeB, wt6, tabS, N);
    spmm2_csr<<<gR, 256, 0, stream>>>(rp_o, sc_o, sv_o, tabO, rp_s, sc_s, sv_s, tabS,
                                      b_ogc2, b_sgc2o, nodeA, N, 0);   // h (o_x dead)

    // ---- Decoder
    dec1_kernel<<<gB, 128, 0, stream>>>(nodeA, idx0, idx1, W_dec1, b_dec1, o1buf, B);
    dec2_kernel<<<gB, 128, 0, stream>>>(o1buf, W_dec2, b_dec2, (float*)d_out, B);
}

// Round 4
// 1276.251 us; speedup vs baseline: 3.9844x; 1.3414x over previous
//
#include <hip/hip_runtime.h>
#include <hip/hip_bf16.h>

#define NFEAT 256
#define NHID 128
#define RELL 86
#define SCAN_CHUNK 512

typedef __attribute__((ext_vector_type(8))) short short8v;
typedef __attribute__((ext_vector_type(4))) float float4v;

static __device__ __forceinline__ unsigned short f2bf(float f) {
    union { float f; unsigned int u; } v; v.f = f;
    unsigned int r = v.u + 0x7FFF + ((v.u >> 16) & 1);   // RNE
    return (unsigned short)(r >> 16);
}
static __device__ __forceinline__ float asf(unsigned int u) {
    union { unsigned int u; float f; } v; v.u = u; return v.f;
}

// ---------------------------------------------------------------------------
// Weight prep: Wt[col][k] = bf16(W[k][col]).  W: [K,128] fp32 -> Wt: [128,K] bf16
// ---------------------------------------------------------------------------
__global__ __launch_bounds__(256) void wt_prep(
    const float* __restrict__ W, unsigned short* __restrict__ Wt, int K)
{
    int i = blockIdx.x * 256 + threadIdx.x;
    if (i < K * 128) {
        int col = i & 127, k = i >> 7;
        Wt[col * K + k] = f2bf(W[i]);
    }
}

// ---------------------------------------------------------------------------
// CSR build: histogram -> 3-phase hierarchical scan -> scatter
// ---------------------------------------------------------------------------
__global__ __launch_bounds__(256) void hist_kernel(
    const int* __restrict__ rows, int* __restrict__ cnt, int E)
{
    int e = blockIdx.x * 256 + threadIdx.x;
    if (e < E) atomicAdd(&cnt[rows[e]], 1);
}

// Phase A: part[b] = sum of cnt[b*512 .. b*512+512)
__global__ __launch_bounds__(256) void scan_partial(
    const int* __restrict__ cnt, int* __restrict__ part, int N)
{
    __shared__ int red[256];
    const int b = blockIdx.x, t = threadIdx.x;
    const int i = b * SCAN_CHUNK + 2 * t;
    int s = 0;
    if (i < N) s += cnt[i];
    if (i + 1 < N) s += cnt[i + 1];
    red[t] = s;
    __syncthreads();
    #pragma unroll
    for (int off = 128; off > 0; off >>= 1) {
        if (t < off) red[t] += red[t + off];
        __syncthreads();
    }
    if (t == 0) part[b] = red[0];
}

// Phase B: in-place exclusive scan of part[0..nblk), nblk <= 1024
__global__ __launch_bounds__(1024) void scan_blocks(
    int* __restrict__ part, int nblk)
{
    __shared__ int sh[1024];
    const int t = threadIdx.x;
    const int v = (t < nblk) ? part[t] : 0;
    sh[t] = v;
    __syncthreads();
    for (int off = 1; off < 1024; off <<= 1) {
        int u = (t >= off) ? sh[t - off] : 0;
        __syncthreads();
        sh[t] += u;
        __syncthreads();
    }
    if (t < nblk) part[t] = sh[t] - v;   // exclusive
}

// Phase C: block-local exclusive scan + block offset -> rp & cursor.
// cnt may alias cursor (reads complete before writes within each block's chunk).
__global__ __launch_bounds__(256) void scan_final(
    const int* __restrict__ cnt, const int* __restrict__ part,
    int* __restrict__ rp, int* __restrict__ cursor, int N, int E)
{
    __shared__ int sh[256];
    const int b = blockIdx.x, t = threadIdx.x;
    const int i = b * SCAN_CHUNK + 2 * t;
    const int c0 = (i < N) ? cnt[i] : 0;
    const int c1 = (i + 1 < N) ? cnt[i + 1] : 0;
    const int s = c0 + c1;
    sh[t] = s;
    __syncthreads();
    for (int off = 1; off < 256; off <<= 1) {
        int u = (t >= off) ? sh[t - off] : 0;
        __syncthreads();
        sh[t] += u;
        __syncthreads();
    }
    const int base = part[b] + sh[t] - s;
    if (i < N)     { rp[i] = base;          cursor[i] = base; }
    if (i + 1 < N) { rp[i + 1] = base + c0; cursor[i + 1] = base + c0; }
    if (b == 0 && t == 0) rp[N] = E;
}

__global__ __launch_bounds__(256) void scatter_kernel(
    const int* __restrict__ rows, const int* __restrict__ cols,
    const float* __restrict__ vals, int* __restrict__ cursor,
    int* __restrict__ sc, float* __restrict__ sv, int E)
{
    int e = blockIdx.x * 256 + threadIdx.x;
    if (e < E) {
        int r = rows[e];
        int p = atomicAdd(&cursor[r], 1);
        sc[p] = cols[e];
        sv[p] = vals[e];
    }
}

// ---------------------------------------------------------------------------
// MFMA GEMM: S = X @ W, X:[Nrows,K] fp32, Wt:[128,K] bf16 (pre-transposed),
// S:[Nrows,128] bf16.  Block 256 thr (4 waves), tile 128x128, BK=64.
// ---------------------------------------------------------------------------
template <int K>
__global__ __launch_bounds__(256) void gemm_mfma(
    const float* __restrict__ X, const unsigned short* __restrict__ Wt,
    unsigned short* __restrict__ S, int Nrows)
{
    __shared__ unsigned short As[128 * 72];
    __shared__ unsigned short Bs[128 * 72];

    const int t = threadIdx.x;
    const int l = t & 63;
    const int w = t >> 6;
    const int row_in = l & 15;
    const int kgrp = l >> 4;        // 0..3
    const int wr0 = w * 32;
    const int row0 = blockIdx.x * 128;

    float4v acc[2][8];
    #pragma unroll
    for (int m = 0; m < 2; ++m)
        #pragma unroll
        for (int n = 0; n < 8; ++n)
            acc[m][n] = (float4v)(0.f);

    for (int kt = 0; kt < K / 64; ++kt) {
        if (kt > 0) __syncthreads();
        #pragma unroll
        for (int it = 0; it < 8; ++it) {
            int i = t + it * 256;           // 0..2047
            int r = i >> 4, c4 = i & 15;
            int gr = row0 + r;
            float4 v = make_float4(0.f, 0.f, 0.f, 0.f);
            if (gr < Nrows)
                v = *(const float4*)(X + (size_t)gr * K + kt * 64 + c4 * 4);
            ushort4 b4;
            b4.x = f2bf(v.x); b4.y = f2bf(v.y); b4.z = f2bf(v.z); b4.w = f2bf(v.w);
            *(ushort4*)&As[r * 72 + c4 * 4] = b4;
        }
        #pragma unroll
        for (int it = 0; it < 8; ++it) {
            int i = t + it * 256;
            int r = i >> 4, c4 = i & 15;
            *(ushort4*)&Bs[r * 72 + c4 * 4] =
                *(const ushort4*)(Wt + (size_t)r * K + kt * 64 + c4 * 4);
        }
        __syncthreads();

        #pragma unroll
        for (int kc = 0; kc < 2; ++kc) {
            short8v a[2], b[8];
            #pragma unroll
            for (int m = 0; m < 2; ++m) {
                const unsigned short* p =
                    &As[(wr0 + m * 16 + row_in) * 72 + kc * 32 + kgrp * 8];
                ((uint2*)&a[m])[0] = *(const uint2*)p;
                ((uint2*)&a[m])[1] = *(const uint2*)(p + 4);
            }
            #pragma unroll
            for (int n = 0; n < 8; ++n) {
                const unsigned short* p =
                    &Bs[(n * 16 + row_in) * 72 + kc * 32 + kgrp * 8];
                ((uint2*)&b[n])[0] = *(const uint2*)p;
                ((uint2*)&b[n])[1] = *(const uint2*)(p + 4);
            }
            #pragma unroll
            for (int m = 0; m < 2; ++m)
                #pragma unroll
                for (int n = 0; n < 8; ++n)
                    acc[m][n] = __builtin_amdgcn_mfma_f32_16x16x32_bf16(
                        a[m], b[n], acc[m][n], 0, 0, 0);
        }
    }

    // epilogue: C/D layout col=lane&15, row=(lane>>4)*4+reg; write bf16
    #pragma unroll
    for (int m = 0; m < 2; ++m)
        #pragma unroll
        for (int n = 0; n < 8; ++n)
            #pragma unroll
            for (int r = 0; r < 4; ++r) {
                int gr = row0 + wr0 + m * 16 + kgrp * 4 + r;
                int gc = n * 16 + row_in;
                if (gr < Nrows) S[(size_t)gr * 128 + gc] = f2bf(acc[m][n][r]);
            }
}

// ---------------------------------------------------------------------------
// Fused dual-graph CSR SpMM: out[row] = maybe_relu(b1+b2 + sum_A + sum_B)
// One wave per row; lane l owns features 2l, 2l+1. Tables are bf16.
// ---------------------------------------------------------------------------
__global__ __launch_bounds__(256) void spmm2_csr(
    const int* __restrict__ rp_a, const int* __restrict__ cs_a,
    const float* __restrict__ vs_a, const unsigned short* __restrict__ Sa,
    const int* __restrict__ rp_b, const int* __restrict__ cs_b,
    const float* __restrict__ vs_b, const unsigned short* __restrict__ Sb,
    const float* __restrict__ b1, const float* __restrict__ b2,
    float* __restrict__ out, int N, int do_relu)
{
    const int row = blockIdx.x * 4 + (threadIdx.x >> 6);
    if (row >= N) return;
    const int l = threadIdx.x & 63;

    float2 bv1 = *(const float2*)(b1 + 2 * l);
    float2 bv2 = *(const float2*)(b2 + 2 * l);
    float ax = bv1.x + bv2.x;
    float ay = bv1.y + bv2.y;

    // graph A
    {
        int e0 = rp_a[row], e1 = rp_a[row + 1];
        int c = 0; float v = 0.f;
        if (e0 < e1) { c = cs_a[e0]; v = vs_a[e0]; }
        for (int e = e0; e < e1; ++e) {
            int cc = c; float vv = v;
            if (e + 1 < e1) { c = cs_a[e + 1]; v = vs_a[e + 1]; }
            unsigned int u = *(const unsigned int*)(Sa + ((size_t)cc << 7) + (l << 1));
            ax = fmaf(vv, asf(u << 16), ax);
            ay = fmaf(vv, asf(u & 0xffff0000u), ay);
        }
    }
    // graph B
    {
        int e0 = rp_b[row], e1 = rp_b[row + 1];
        int c = 0; float v = 0.f;
        if (e0 < e1) { c = cs_b[e0]; v = vs_b[e0]; }
        for (int e = e0; e < e1; ++e) {
            int cc = c; float vv = v;
            if (e + 1 < e1) { c = cs_b[e + 1]; v = vs_b[e + 1]; }
            unsigned int u = *(const unsigned int*)(Sb + ((size_t)cc << 7) + (l << 1));
            ax = fmaf(vv, asf(u << 16), ax);
            ay = fmaf(vv, asf(u & 0xffff0000u), ay);
        }
    }
    if (do_relu) { ax = fmaxf(ax, 0.f); ay = fmaxf(ay, 0.f); }
    float2 o; o.x = ax; o.y = ay;
    *(float2*)(out + ((size_t)row << 7) + (l << 1)) = o;
}

// ---------------------------------------------------------------------------
// Decoder stage 1: out[b] = concat(h[idx0[b]], h[idx1[b]]) @ W + bias -> [B,128]
// ---------------------------------------------------------------------------
__global__ __launch_bounds__(128) void dec1_kernel(
    const float* __restrict__ h,
    const int* __restrict__ idx0, const int* __restrict__ idx1,
    const float* __restrict__ W, const float* __restrict__ bias,
    float* __restrict__ out, int B)
{
    __shared__ __align__(16) float fs[16 * 256];
    const int t = threadIdx.x;
    const int b0 = blockIdx.x * 16;
    #pragma unroll
    for (int r = 0; r < 16; ++r) {
        const int b = b0 + r;
        fs[r * 256 + t]       = h[(long)idx0[b] * 128 + t];
        fs[r * 256 + 128 + t] = h[(long)idx1[b] * 128 + t];
    }
    __syncthreads();

    const float4* fs4 = (const float4*)fs;
    float acc[16];
    #pragma unroll
    for (int r = 0; r < 16; ++r) acc[r] = 0.f;
    for (int kc = 0; kc < 64; ++kc) {
        const float w0 = W[(kc * 4 + 0) * 128 + t];
        const float w1 = W[(kc * 4 + 1) * 128 + t];
        const float w2 = W[(kc * 4 + 2) * 128 + t];
        const float w3 = W[(kc * 4 + 3) * 128 + t];
        #pragma unroll
        for (int r = 0; r < 16; ++r) {
            const float4 xv = fs4[r * 64 + kc];
            acc[r] = fmaf(xv.x, w0, acc[r]);
            acc[r] = fmaf(xv.y, w1, acc[r]);
            acc[r] = fmaf(xv.z, w2, acc[r]);
            acc[r] = fmaf(xv.w, w3, acc[r]);
        }
    }
    #pragma unroll
    for (int r = 0; r < 16; ++r)
        out[(long)(b0 + r) * 128 + t] = acc[r] + bias[t];
}

// ---------------------------------------------------------------------------
// Decoder stage 2: out[b] = o1[b] @ W + bias -> [B, 86]
// ---------------------------------------------------------------------------
__global__ __launch_bounds__(128) void dec2_kernel(
    const float* __restrict__ o1,
    const float* __restrict__ W, const float* __restrict__ bias,
    float* __restrict__ out, int B)
{
    __shared__ __align__(16) float os[16 * 128];
    const int t = threadIdx.x;
    const int b0 = blockIdx.x * 16;
    #pragma unroll
    for (int r = 0; r < 16; ++r)
        os[r * 128 + t] = o1[(long)(b0 + r) * 128 + t];
    __syncthreads();

    const float4* os4 = (const float4*)os;
    float acc[16];
    #pragma unroll
    for (int r = 0; r < 16; ++r) acc[r] = 0.f;
    const bool act = (t < RELL);
    for (int kc = 0; kc < 32; ++kc) {
        const float w0 = act ? W[(kc * 4 + 0) * RELL + t] : 0.f;
        const float w1 = act ? W[(kc * 4 + 1) * RELL + t] : 0.f;
        const float w2 = act ? W[(kc * 4 + 2) * RELL + t] : 0.f;
        const float w3 = act ? W[(kc * 4 + 3) * RELL + t] : 0.f;
        #pragma unroll
        for (int r = 0; r < 16; ++r) {
            const float4 xv = os4[r * 32 + kc];
            acc[r] = fmaf(xv.x, w0, acc[r]);
            acc[r] = fmaf(xv.y, w1, acc[r]);
            acc[r] = fmaf(xv.z, w2, acc[r]);
            acc[r] = fmaf(xv.w, w3, acc[r]);
        }
    }
    if (act) {
        #pragma unroll
        for (int r = 0; r < 16; ++r)
            out[(long)(b0 + r) * RELL + t] = acc[r] + bias[t];
    }
}

extern "C" void kernel_launch(void* const* d_in, const int* in_sizes, int n_in,
                              void* d_out, int out_size, void* d_ws, size_t ws_size,
                              hipStream_t stream) {
    const float* x      = (const float*)d_in[0];
    const int*   o_rows = (const int*)  d_in[1];
    const int*   o_cols = (const int*)  d_in[2];
    const float* o_vals = (const float*)d_in[3];
    const int*   s_rows = (const int*)  d_in[4];
    const int*   s_cols = (const int*)  d_in[5];
    const float* s_vals = (const float*)d_in[6];
    const int*   idx    = (const int*)  d_in[7];
    const float* W_ogc1  = (const float*)d_in[8];   const float* b_ogc1  = (const float*)d_in[9];
    const float* W_sgc1o = (const float*)d_in[10];  const float* b_sgc1o = (const float*)d_in[11];
    const float* W_sgc1  = (const float*)d_in[12];  const float* b_sgc1  = (const float*)d_in[13];
    const float* W_ogc1s = (const float*)d_in[14];  const float* b_ogc1s = (const float*)d_in[15];
    const float* W_ogc2  = (const float*)d_in[16];  const float* b_ogc2  = (const float*)d_in[17];
    const float* W_sgc2o = (const float*)d_in[18];  const float* b_sgc2o = (const float*)d_in[19];
    const float* W_dec1  = (const float*)d_in[20];  const float* b_dec1  = (const float*)d_in[21];
    const float* W_dec2  = (const float*)d_in[22];  const float* b_dec2  = (const float*)d_in[23];

    const int N = in_sizes[0] / NFEAT;   // 100000
    const int E = in_sizes[1];           // 1600000
    const int B = in_sizes[7] / 2;       // 16384
    const int* idx0 = idx;
    const int* idx1 = idx + B;

    float* ws = (float*)d_ws;
    const size_t NB = (size_t)N * NHID;

    float* nodeA = ws;                                   // o_x, later h  [N,128] fp32
    float* nodeB = ws + NB;                              // s_x           [N,128] fp32
    unsigned short* tabO = (unsigned short*)(ws + 2 * NB);   // o-graph operand [N,128] bf16
    unsigned short* tabS = tabO + NB;                        // s-graph operand [N,128] bf16
    float* o1buf = (float*)(tabS + NB);                  // dec1 out [B,128] fp32
    unsigned short* wt1 = (unsigned short*)(o1buf + (size_t)B * 128);
    unsigned short* wt2 = wt1 + 128 * 256;
    unsigned short* wt3 = wt2 + 128 * 256;
    unsigned short* wt4 = wt3 + 128 * 256;               // [128,128]
    unsigned short* wt5 = wt4 + 128 * 128;
    unsigned short* wt6 = wt5 + 128 * 128;
    int* rp_o  = (int*)(wt6 + 128 * 128);                // [N+1]
    int* cur_o = rp_o + (N + 1);                         // [N] counts->cursor
    int* sc_o  = cur_o + N;                              // [E]
    float* sv_o = (float*)(sc_o + E);                    // [E]
    int* rp_s  = (int*)(sv_o + E);
    int* cur_s = rp_s + (N + 1);
    int* sc_s  = cur_s + N;
    float* sv_s = (float*)(sc_s + E);
    int* part_o = (int*)(sv_s + E);                      // [1024] scan partials
    int* part_s = part_o + 1024;

    const int gM = (N + 127) / 128;       // 782
    const int gE = (E + 255) / 256;       // 6250
    const int gR = (N + 3) / 4;           // 25000
    const int gB = B / 16;                // 1024
    const int gScan = (N + SCAN_CHUNK - 1) / SCAN_CHUNK;  // 196

    // ---- CSR build for both graphs
    hipMemsetAsync(cur_o, 0, (size_t)N * sizeof(int), stream);
    hipMemsetAsync(cur_s, 0, (size_t)N * sizeof(int), stream);
    hist_kernel<<<gE, 256, 0, stream>>>(o_rows, cur_o, E);
    hist_kernel<<<gE, 256, 0, stream>>>(s_rows, cur_s, E);
    scan_partial<<<gScan, 256, 0, stream>>>(cur_o, part_o, N);
    scan_partial<<<gScan, 256, 0, stream>>>(cur_s, part_s, N);
    scan_blocks<<<1, 1024, 0, stream>>>(part_o, gScan);
    scan_blocks<<<1, 1024, 0, stream>>>(part_s, gScan);
    scan_final<<<gScan, 256, 0, stream>>>(cur_o, part_o, rp_o, cur_o, N, E);
    scan_final<<<gScan, 256, 0, stream>>>(cur_s, part_s, rp_s, cur_s, N, E);
    scatter_kernel<<<gE, 256, 0, stream>>>(o_rows, o_cols, o_vals, cur_o, sc_o, sv_o, E);
    scatter_kernel<<<gE, 256, 0, stream>>>(s_rows, s_cols, s_vals, cur_s, sc_s, sv_s, E);

    // ---- weight prep (bf16 transpose)
    wt_prep<<<(NFEAT * 128 + 255) / 256, 256, 0, stream>>>(W_ogc1, wt1, NFEAT);
    wt_prep<<<(NFEAT * 128 + 255) / 256, 256, 0, stream>>>(W_sgc1o, wt2, NFEAT);
    wt_prep<<<(NFEAT * 128 + 255) / 256, 256, 0, stream>>>(W_sgc1, wt3, NFEAT);
    wt_prep<<<(NHID * 128 + 255) / 256, 256, 0, stream>>>(W_ogc1s, wt4, NHID);
    wt_prep<<<(NHID * 128 + 255) / 256, 256, 0, stream>>>(W_ogc2, wt5, NHID);
    wt_prep<<<(NHID * 128 + 255) / 256, 256, 0, stream>>>(W_sgc2o, wt6, NHID);

    // ---- Layer 1: o_x = relu(spmm_o(x@W_ogc1) + spmm_s(x@W_sgc1o) + b)
    gemm_mfma<NFEAT><<<gM, 256, 0, stream>>>(x, wt1, tabO, N);
    gemm_mfma<NFEAT><<<gM, 256, 0, stream>>>(x, wt2, tabS, N);
    spmm2_csr<<<gR, 256, 0, stream>>>(rp_o, sc_o, sv_o, tabO, rp_s, sc_s, sv_s, tabS,
                                      b_ogc1, b_sgc1o, nodeA, N, 1);   // o_x

    // ---- Layer 2: s_x = relu(spmm_s(x@W_sgc1) + spmm_o(o_x@W_ogc1s) + b)
    gemm_mfma<NFEAT><<<gM, 256, 0, stream>>>(x, wt3, tabS, N);
    gemm_mfma<NHID><<<gM, 256, 0, stream>>>(nodeA, wt4, tabO, N);
    spmm2_csr<<<gR, 256, 0, stream>>>(rp_o, sc_o, sv_o, tabO, rp_s, sc_s, sv_s, tabS,
                                      b_ogc1s, b_sgc1, nodeB, N, 1);   // s_x

    // ---- Layer 3: h = spmm_o(o_x@W_ogc2) + spmm_s(s_x@W_sgc2o) + b
    gemm_mfma<NHID><<<gM, 256, 0, stream>>>(nodeA, wt5, tabO, N);
    gemm_mfma<NHID><<<gM, 256, 0, stream>>>(nodeB, wt6, tabS, N);
    spmm2_csr<<<gR, 256, 0, stream>>>(rp_o, sc_o, sv_o, tabO, rp_s, sc_s, sv_s, tabS,
                                      b_ogc2, b_sgc2o, nodeA, N, 0);   // h (o_x dead)

    // ---- Decoder
    dec1_kernel<<<gB, 128, 0, stream>>>(nodeA, idx0, idx1, W_dec1, b_dec1, o1buf, B);
    dec2_kernel<<<gB, 128, 0, stream>>>(o1buf, W_dec2, b_dec2, (float*)d_out, B);
}

// Round 5
// 1082.716 us; speedup vs baseline: 4.6966x; 1.1787x over previous
//
#include <hip/hip_runtime.h>
#include <hip/hip_bf16.h>

#define NFEAT 256
#define NHID 128
#define RELL 86
#define SCAN_CHUNK 512

typedef __attribute__((ext_vector_type(8))) short short8v;
typedef __attribute__((ext_vector_type(4))) float float4v;

static __device__ __forceinline__ unsigned short f2bf(float f) {
    union { float f; unsigned int u; } v; v.f = f;
    unsigned int r = v.u + 0x7FFF + ((v.u >> 16) & 1);   // RNE
    return (unsigned short)(r >> 16);
}
static __device__ __forceinline__ float asf(unsigned int u) {
    union { unsigned int u; float f; } v; v.u = u; return v.f;
}

// ---------------------------------------------------------------------------
// Weight prep: Wt[col][k] = bf16(W[k][col]).  W: [K,128] fp32 -> Wt: [128,K] bf16
// ---------------------------------------------------------------------------
__global__ __launch_bounds__(256) void wt_prep(
    const float* __restrict__ W, unsigned short* __restrict__ Wt, int K)
{
    int i = blockIdx.x * 256 + threadIdx.x;
    if (i < K * 128) {
        int col = i & 127, k = i >> 7;
        Wt[col * K + k] = f2bf(W[i]);
    }
}

// ---------------------------------------------------------------------------
// CSR build: histogram -> 3-phase hierarchical scan -> scatter
// ---------------------------------------------------------------------------
__global__ __launch_bounds__(256) void hist_kernel(
    const int* __restrict__ rows, int* __restrict__ cnt, int E)
{
    int e = blockIdx.x * 256 + threadIdx.x;
    if (e < E) atomicAdd(&cnt[rows[e]], 1);
}

// Phase A: part[b] = sum of cnt[b*512 .. b*512+512)
__global__ __launch_bounds__(256) void scan_partial(
    const int* __restrict__ cnt, int* __restrict__ part, int N)
{
    __shared__ int red[256];
    const int b = blockIdx.x, t = threadIdx.x;
    const int i = b * SCAN_CHUNK + 2 * t;
    int s = 0;
    if (i < N) s += cnt[i];
    if (i + 1 < N) s += cnt[i + 1];
    red[t] = s;
    __syncthreads();
    #pragma unroll
    for (int off = 128; off > 0; off >>= 1) {
        if (t < off) red[t] += red[t + off];
        __syncthreads();
    }
    if (t == 0) part[b] = red[0];
}

// Phase B: in-place exclusive scan of part[0..nblk), nblk <= 1024
__global__ __launch_bounds__(1024) void scan_blocks(
    int* __restrict__ part, int nblk)
{
    __shared__ int sh[1024];
    const int t = threadIdx.x;
    const int v = (t < nblk) ? part[t] : 0;
    sh[t] = v;
    __syncthreads();
    for (int off = 1; off < 1024; off <<= 1) {
        int u = (t >= off) ? sh[t - off] : 0;
        __syncthreads();
        sh[t] += u;
        __syncthreads();
    }
    if (t < nblk) part[t] = sh[t] - v;   // exclusive
}

// Phase C: block-local exclusive scan + block offset -> rp & cursor.
// cnt may alias cursor (reads complete before writes within each block's chunk).
__global__ __launch_bounds__(256) void scan_final(
    const int* __restrict__ cnt, const int* __restrict__ part,
    int* __restrict__ rp, int* __restrict__ cursor, int N, int E)
{
    __shared__ int sh[256];
    const int b = blockIdx.x, t = threadIdx.x;
    const int i = b * SCAN_CHUNK + 2 * t;
    const int c0 = (i < N) ? cnt[i] : 0;
    const int c1 = (i + 1 < N) ? cnt[i + 1] : 0;
    const int s = c0 + c1;
    sh[t] = s;
    __syncthreads();
    for (int off = 1; off < 256; off <<= 1) {
        int u = (t >= off) ? sh[t - off] : 0;
        __syncthreads();
        sh[t] += u;
        __syncthreads();
    }
    const int base = part[b] + sh[t] - s;
    if (i < N)     { rp[i] = base;          cursor[i] = base; }
    if (i + 1 < N) { rp[i + 1] = base + c0; cursor[i + 1] = base + c0; }
    if (b == 0 && t == 0) rp[N] = E;
}

// Scatter into packed (col, val_bits) int2 array
__global__ __launch_bounds__(256) void scatter_kernel(
    const int* __restrict__ rows, const int* __restrict__ cols,
    const float* __restrict__ vals, int* __restrict__ cursor,
    int2* __restrict__ ev, int E)
{
    int e = blockIdx.x * 256 + threadIdx.x;
    if (e < E) {
        int r = rows[e];
        int p = atomicAdd(&cursor[r], 1);
        int2 pk;
        pk.x = cols[e];
        pk.y = __float_as_int(vals[e]);
        ev[p] = pk;
    }
}

// ---------------------------------------------------------------------------
// MFMA GEMM: S = X @ W, X:[Nrows,K] fp32, Wt:[128,K] bf16 (pre-transposed),
// S:[Nrows,128] bf16.  Block 256 thr (4 waves), tile 128x128, BK=64.
// ---------------------------------------------------------------------------
template <int K>
__global__ __launch_bounds__(256) void gemm_mfma(
    const float* __restrict__ X, const unsigned short* __restrict__ Wt,
    unsigned short* __restrict__ S, int Nrows)
{
    __shared__ unsigned short As[128 * 72];
    __shared__ unsigned short Bs[128 * 72];

    const int t = threadIdx.x;
    const int l = t & 63;
    const int w = t >> 6;
    const int row_in = l & 15;
    const int kgrp = l >> 4;        // 0..3
    const int wr0 = w * 32;
    const int row0 = blockIdx.x * 128;

    float4v acc[2][8];
    #pragma unroll
    for (int m = 0; m < 2; ++m)
        #pragma unroll
        for (int n = 0; n < 8; ++n)
            acc[m][n] = (float4v)(0.f);

    for (int kt = 0; kt < K / 64; ++kt) {
        if (kt > 0) __syncthreads();
        #pragma unroll
        for (int it = 0; it < 8; ++it) {
            int i = t + it * 256;           // 0..2047
            int r = i >> 4, c4 = i & 15;
            int gr = row0 + r;
            float4 v = make_float4(0.f, 0.f, 0.f, 0.f);
            if (gr < Nrows)
                v = *(const float4*)(X + (size_t)gr * K + kt * 64 + c4 * 4);
            ushort4 b4;
            b4.x = f2bf(v.x); b4.y = f2bf(v.y); b4.z = f2bf(v.z); b4.w = f2bf(v.w);
            *(ushort4*)&As[r * 72 + c4 * 4] = b4;
        }
        #pragma unroll
        for (int it = 0; it < 8; ++it) {
            int i = t + it * 256;
            int r = i >> 4, c4 = i & 15;
            *(ushort4*)&Bs[r * 72 + c4 * 4] =
                *(const ushort4*)(Wt + (size_t)r * K + kt * 64 + c4 * 4);
        }
        __syncthreads();

        #pragma unroll
        for (int kc = 0; kc < 2; ++kc) {
            short8v a[2], b[8];
            #pragma unroll
            for (int m = 0; m < 2; ++m) {
                const unsigned short* p =
                    &As[(wr0 + m * 16 + row_in) * 72 + kc * 32 + kgrp * 8];
                ((uint2*)&a[m])[0] = *(const uint2*)p;
                ((uint2*)&a[m])[1] = *(const uint2*)(p + 4);
            }
            #pragma unroll
            for (int n = 0; n < 8; ++n) {
                const unsigned short* p =
                    &Bs[(n * 16 + row_in) * 72 + kc * 32 + kgrp * 8];
                ((uint2*)&b[n])[0] = *(const uint2*)p;
                ((uint2*)&b[n])[1] = *(const uint2*)(p + 4);
            }
            #pragma unroll
            for (int m = 0; m < 2; ++m)
                #pragma unroll
                for (int n = 0; n < 8; ++n)
                    acc[m][n] = __builtin_amdgcn_mfma_f32_16x16x32_bf16(
                        a[m], b[n], acc[m][n], 0, 0, 0);
        }
    }

    // epilogue: C/D layout col=lane&15, row=(lane>>4)*4+reg; write bf16
    #pragma unroll
    for (int m = 0; m < 2; ++m)
        #pragma unroll
        for (int n = 0; n < 8; ++n)
            #pragma unroll
            for (int r = 0; r < 4; ++r) {
                int gr = row0 + wr0 + m * 16 + kgrp * 4 + r;
                int gc = n * 16 + row_in;
                if (gr < Nrows) S[(size_t)gr * 128 + gc] = f2bf(acc[m][n][r]);
            }
}

// ---------------------------------------------------------------------------
// Fused dual-graph CSR SpMM: out[row] = maybe_relu(b1+b2 + sum_A + sum_B)
// One wave per row; lane l owns features 2l, 2l+1. Tables are bf16.
// 4-way edge unroll: 4 independent table gathers in flight per wave.
// ---------------------------------------------------------------------------
__global__ __launch_bounds__(256) void spmm2_csr(
    const int* __restrict__ rp_a, const int2* __restrict__ ev_a,
    const unsigned short* __restrict__ Sa,
    const int* __restrict__ rp_b, const int2* __restrict__ ev_b,
    const unsigned short* __restrict__ Sb,
    const float* __restrict__ b1, const float* __restrict__ b2,
    float* __restrict__ out, int N, int do_relu)
{
    const int row = blockIdx.x * 4 + (threadIdx.x >> 6);
    if (row >= N) return;
    const int l2 = (threadIdx.x & 63) << 1;

    float2 bv1 = *(const float2*)(b1 + l2);
    float2 bv2 = *(const float2*)(b2 + l2);
    float ax = bv1.x + bv2.x;
    float ay = bv1.y + bv2.y;

    #pragma unroll
    for (int g = 0; g < 2; ++g) {
        const int* __restrict__ rp = g ? rp_b : rp_a;
        const int2* __restrict__ ev = g ? ev_b : ev_a;
        const unsigned short* __restrict__ S = g ? Sb : Sa;

        int e = rp[row];
        const int e1 = rp[row + 1];
        for (; e + 4 <= e1; e += 4) {
            const int2 p0 = ev[e];
            const int2 p1 = ev[e + 1];
            const int2 p2 = ev[e + 2];
            const int2 p3 = ev[e + 3];
            const unsigned u0 = *(const unsigned*)(S + ((size_t)p0.x << 7) + l2);
            const unsigned u1 = *(const unsigned*)(S + ((size_t)p1.x << 7) + l2);
            const unsigned u2 = *(const unsigned*)(S + ((size_t)p2.x << 7) + l2);
            const unsigned u3 = *(const unsigned*)(S + ((size_t)p3.x << 7) + l2);
            const float v0 = __int_as_float(p0.y);
            const float v1 = __int_as_float(p1.y);
            const float v2 = __int_as_float(p2.y);
            const float v3 = __int_as_float(p3.y);
            ax = fmaf(v0, asf(u0 << 16), ax); ay = fmaf(v0, asf(u0 & 0xffff0000u), ay);
            ax = fmaf(v1, asf(u1 << 16), ax); ay = fmaf(v1, asf(u1 & 0xffff0000u), ay);
            ax = fmaf(v2, asf(u2 << 16), ax); ay = fmaf(v2, asf(u2 & 0xffff0000u), ay);
            ax = fmaf(v3, asf(u3 << 16), ax); ay = fmaf(v3, asf(u3 & 0xffff0000u), ay);
        }
        for (; e < e1; ++e) {
            const int2 p = ev[e];
            const unsigned u = *(const unsigned*)(S + ((size_t)p.x << 7) + l2);
            const float v = __int_as_float(p.y);
            ax = fmaf(v, asf(u << 16), ax);
            ay = fmaf(v, asf(u & 0xffff0000u), ay);
        }
    }
    if (do_relu) { ax = fmaxf(ax, 0.f); ay = fmaxf(ay, 0.f); }
    float2 o; o.x = ax; o.y = ay;
    *(float2*)(out + ((size_t)row << 7) + l2) = o;
}

// ---------------------------------------------------------------------------
// Decoder stage 1: out[b] = concat(h[idx0[b]], h[idx1[b]]) @ W + bias -> [B,128]
// ---------------------------------------------------------------------------
__global__ __launch_bounds__(128) void dec1_kernel(
    const float* __restrict__ h,
    const int* __restrict__ idx0, const int* __restrict__ idx1,
    const float* __restrict__ W, const float* __restrict__ bias,
    float* __restrict__ out, int B)
{
    __shared__ __align__(16) float fs[16 * 256];
    const int t = threadIdx.x;
    const int b0 = blockIdx.x * 16;
    #pragma unroll
    for (int r = 0; r < 16; ++r) {
        const int b = b0 + r;
        fs[r * 256 + t]       = h[(long)idx0[b] * 128 + t];
        fs[r * 256 + 128 + t] = h[(long)idx1[b] * 128 + t];
    }
    __syncthreads();

    const float4* fs4 = (const float4*)fs;
    float acc[16];
    #pragma unroll
    for (int r = 0; r < 16; ++r) acc[r] = 0.f;
    for (int kc = 0; kc < 64; ++kc) {
        const float w0 = W[(kc * 4 + 0) * 128 + t];
        const float w1 = W[(kc * 4 + 1) * 128 + t];
        const float w2 = W[(kc * 4 + 2) * 128 + t];
        const float w3 = W[(kc * 4 + 3) * 128 + t];
        #pragma unroll
        for (int r = 0; r < 16; ++r) {
            const float4 xv = fs4[r * 64 + kc];
            acc[r] = fmaf(xv.x, w0, acc[r]);
            acc[r] = fmaf(xv.y, w1, acc[r]);
            acc[r] = fmaf(xv.z, w2, acc[r]);
            acc[r] = fmaf(xv.w, w3, acc[r]);
        }
    }
    #pragma unroll
    for (int r = 0; r < 16; ++r)
        out[(long)(b0 + r) * 128 + t] = acc[r] + bias[t];
}

// ---------------------------------------------------------------------------
// Decoder stage 2: out[b] = o1[b] @ W + bias -> [B, 86]
// ---------------------------------------------------------------------------
__global__ __launch_bounds__(128) void dec2_kernel(
    const float* __restrict__ o1,
    const float* __restrict__ W, const float* __restrict__ bias,
    float* __restrict__ out, int B)
{
    __shared__ __align__(16) float os[16 * 128];
    const int t = threadIdx.x;
    const int b0 = blockIdx.x * 16;
    #pragma unroll
    for (int r = 0; r < 16; ++r)
        os[r * 128 + t] = o1[(long)(b0 + r) * 128 + t];
    __syncthreads();

    const float4* os4 = (const float4*)os;
    float acc[16];
    #pragma unroll
    for (int r = 0; r < 16; ++r) acc[r] = 0.f;
    const bool act = (t < RELL);
    for (int kc = 0; kc < 32; ++kc) {
        const float w0 = act ? W[(kc * 4 + 0) * RELL + t] : 0.f;
        const float w1 = act ? W[(kc * 4 + 1) * RELL + t] : 0.f;
        const float w2 = act ? W[(kc * 4 + 2) * RELL + t] : 0.f;
        const float w3 = act ? W[(kc * 4 + 3) * RELL + t] : 0.f;
        #pragma unroll
        for (int r = 0; r < 16; ++r) {
            const float4 xv = os4[r * 32 + kc];
            acc[r] = fmaf(xv.x, w0, acc[r]);
            acc[r] = fmaf(xv.y, w1, acc[r]);
            acc[r] = fmaf(xv.z, w2, acc[r]);
            acc[r] = fmaf(xv.w, w3, acc[r]);
        }
    }
    if (act) {
        #pragma unroll
        for (int r = 0; r < 16; ++r)
            out[(long)(b0 + r) * RELL + t] = acc[r] + bias[t];
    }
}

extern "C" void kernel_launch(void* const* d_in, const int* in_sizes, int n_in,
                              void* d_out, int out_size, void* d_ws, size_t ws_size,
                              hipStream_t stream) {
    const float* x      = (const float*)d_in[0];
    const int*   o_rows = (const int*)  d_in[1];
    const int*   o_cols = (const int*)  d_in[2];
    const float* o_vals = (const float*)d_in[3];
    const int*   s_rows = (const int*)  d_in[4];
    const int*   s_cols = (const int*)  d_in[5];
    const float* s_vals = (const float*)d_in[6];
    const int*   idx    = (const int*)  d_in[7];
    const float* W_ogc1  = (const float*)d_in[8];   const float* b_ogc1  = (const float*)d_in[9];
    const float* W_sgc1o = (const float*)d_in[10];  const float* b_sgc1o = (const float*)d_in[11];
    const float* W_sgc1  = (const float*)d_in[12];  const float* b_sgc1  = (const float*)d_in[13];
    const float* W_ogc1s = (const float*)d_in[14];  const float* b_ogc1s = (const float*)d_in[15];
    const float* W_ogc2  = (const float*)d_in[16];  const float* b_ogc2  = (const float*)d_in[17];
    const float* W_sgc2o = (const float*)d_in[18];  const float* b_sgc2o = (const float*)d_in[19];
    const float* W_dec1  = (const float*)d_in[20];  const float* b_dec1  = (const float*)d_in[21];
    const float* W_dec2  = (const float*)d_in[22];  const float* b_dec2  = (const float*)d_in[23];

    const int N = in_sizes[0] / NFEAT;   // 100000
    const int E = in_sizes[1];           // 1600000
    const int B = in_sizes[7] / 2;       // 16384
    const int* idx0 = idx;
    const int* idx1 = idx + B;

    float* ws = (float*)d_ws;
    const size_t NB = (size_t)N * NHID;

    float* nodeA = ws;                                   // o_x, later h  [N,128] fp32
    float* nodeB = ws + NB;                              // s_x           [N,128] fp32
    unsigned short* tabO = (unsigned short*)(ws + 2 * NB);   // o-graph operand [N,128] bf16
    unsigned short* tabS = tabO + NB;                        // s-graph operand [N,128] bf16
    float* o1buf = (float*)(tabS + NB);                  // dec1 out [B,128] fp32
    unsigned short* wt1 = (unsigned short*)(o1buf + (size_t)B * 128);
    unsigned short* wt2 = wt1 + 128 * 256;
    unsigned short* wt3 = wt2 + 128 * 256;
    unsigned short* wt4 = wt3 + 128 * 256;               // [128,128]
    unsigned short* wt5 = wt4 + 128 * 128;
    unsigned short* wt6 = wt5 + 128 * 128;
    int* rp_o  = (int*)(wt6 + 128 * 128);                // [N+1]
    int* cur_o = rp_o + (N + 1);                         // [N] counts->cursor
    int2* ev_o = (int2*)(cur_o + N + 1);                 // [E] packed (col, val)
    int* rp_s  = (int*)(ev_o + E);
    int* cur_s = rp_s + (N + 1);
    int2* ev_s = (int2*)(cur_s + N + 1);                 // [E]
    int* part_o = (int*)(ev_s + E);                      // [1024] scan partials
    int* part_s = part_o + 1024;

    const int gM = (N + 127) / 128;       // 782
    const int gE = (E + 255) / 256;       // 6250
    const int gR = (N + 3) / 4;           // 25000
    const int gB = B / 16;                // 1024
    const int gScan = (N + SCAN_CHUNK - 1) / SCAN_CHUNK;  // 196

    // ---- CSR build for both graphs
    hipMemsetAsync(cur_o, 0, (size_t)N * sizeof(int), stream);
    hipMemsetAsync(cur_s, 0, (size_t)N * sizeof(int), stream);
    hist_kernel<<<gE, 256, 0, stream>>>(o_rows, cur_o, E);
    hist_kernel<<<gE, 256, 0, stream>>>(s_rows, cur_s, E);
    scan_partial<<<gScan, 256, 0, stream>>>(cur_o, part_o, N);
    scan_partial<<<gScan, 256, 0, stream>>>(cur_s, part_s, N);
    scan_blocks<<<1, 1024, 0, stream>>>(part_o, gScan);
    scan_blocks<<<1, 1024, 0, stream>>>(part_s, gScan);
    scan_final<<<gScan, 256, 0, stream>>>(cur_o, part_o, rp_o, cur_o, N, E);
    scan_final<<<gScan, 256, 0, stream>>>(cur_s, part_s, rp_s, cur_s, N, E);
    scatter_kernel<<<gE, 256, 0, stream>>>(o_rows, o_cols, o_vals, cur_o, ev_o, E);
    scatter_kernel<<<gE, 256, 0, stream>>>(s_rows, s_cols, s_vals, cur_s, ev_s, E);

    // ---- weight prep (bf16 transpose)
    wt_prep<<<(NFEAT * 128 + 255) / 256, 256, 0, stream>>>(W_ogc1, wt1, NFEAT);
    wt_prep<<<(NFEAT * 128 + 255) / 256, 256, 0, stream>>>(W_sgc1o, wt2, NFEAT);
    wt_prep<<<(NFEAT * 128 + 255) / 256, 256, 0, stream>>>(W_sgc1, wt3, NFEAT);
    wt_prep<<<(NHID * 128 + 255) / 256, 256, 0, stream>>>(W_ogc1s, wt4, NHID);
    wt_prep<<<(NHID * 128 + 255) / 256, 256, 0, stream>>>(W_ogc2, wt5, NHID);
    wt_prep<<<(NHID * 128 + 255) / 256, 256, 0, stream>>>(W_sgc2o, wt6, NHID);

    // ---- Layer 1: o_x = relu(spmm_o(x@W_ogc1) + spmm_s(x@W_sgc1o) + b)
    gemm_mfma<NFEAT><<<gM, 256, 0, stream>>>(x, wt1, tabO, N);
    gemm_mfma<NFEAT><<<gM, 256, 0, stream>>>(x, wt2, tabS, N);
    spmm2_csr<<<gR, 256, 0, stream>>>(rp_o, ev_o, tabO, rp_s, ev_s, tabS,
                                      b_ogc1, b_sgc1o, nodeA, N, 1);   // o_x

    // ---- Layer 2: s_x = relu(spmm_s(x@W_sgc1) + spmm_o(o_x@W_ogc1s) + b)
    gemm_mfma<NFEAT><<<gM, 256, 0, stream>>>(x, wt3, tabS, N);
    gemm_mfma<NHID><<<gM, 256, 0, stream>>>(nodeA, wt4, tabO, N);
    spmm2_csr<<<gR, 256, 0, stream>>>(rp_o, ev_o, tabO, rp_s, ev_s, tabS,
                                      b_ogc1s, b_sgc1, nodeB, N, 1);   // s_x

    // ---- Layer 3: h = spmm_o(o_x@W_ogc2) + spmm_s(s_x@W_sgc2o) + b
    gemm_mfma<NHID><<<gM, 256, 0, stream>>>(nodeA, wt5, tabO, N);
    gemm_mfma<NHID><<<gM, 256, 0, stream>>>(nodeB, wt6, tabS, N);
    spmm2_csr<<<gR, 256, 0, stream>>>(rp_o, ev_o, tabO, rp_s, ev_s, tabS,
                                      b_ogc2, b_sgc2o, nodeA, N, 0);   // h (o_x dead)

    // ---- Decoder
    dec1_kernel<<<gB, 128, 0, stream>>>(nodeA, idx0, idx1, W_dec1, b_dec1, o1buf, B);
    dec2_kernel<<<gB, 128, 0, stream>>>(o1buf, W_dec2, b_dec2, (float*)d_out, B);
}

// Round 6
// 900.284 us; speedup vs baseline: 5.6483x; 1.2026x over previous
//
#include <hip/hip_runtime.h>
#include <hip/hip_bf16.h>

#define NFEAT 256
#define NHID 128
#define RELL 86
#define SCAN_CHUNK 512

typedef __attribute__((ext_vector_type(8))) short short8v;
typedef __attribute__((ext_vector_type(4))) float float4v;

static __device__ __forceinline__ unsigned short f2bf(float f) {
    union { float f; unsigned int u; } v; v.f = f;
    unsigned int r = v.u + 0x7FFF + ((v.u >> 16) & 1);   // RNE
    return (unsigned short)(r >> 16);
}
static __device__ __forceinline__ float asf(unsigned int u) {
    union { unsigned int u; float f; } v; v.u = u; return v.f;
}

// ---------------------------------------------------------------------------
// Weight prep: 3 matrices per launch via blockIdx.y. Wt[col][k] = bf16(W[k][col])
// ---------------------------------------------------------------------------
template <int K>
__global__ __launch_bounds__(256) void wt_prep3(
    const float* __restrict__ W0, const float* __restrict__ W1,
    const float* __restrict__ W2,
    unsigned short* __restrict__ T0, unsigned short* __restrict__ T1,
    unsigned short* __restrict__ T2)
{
    const float* W = (blockIdx.y == 0) ? W0 : ((blockIdx.y == 1) ? W1 : W2);
    unsigned short* T = (blockIdx.y == 0) ? T0 : ((blockIdx.y == 1) ? T1 : T2);
    int i = blockIdx.x * 256 + threadIdx.x;
    if (i < K * 128) {
        int col = i & 127, k = i >> 7;
        T[col * K + k] = f2bf(W[i]);
    }
}

// ---------------------------------------------------------------------------
// CSR build (both graphs per launch via blockIdx.y)
// cnt/cursor is a [2][N] slab; ev is packed (col, val_bits)
// ---------------------------------------------------------------------------
__global__ __launch_bounds__(256) void hist2(
    const int* __restrict__ rows_o, const int* __restrict__ rows_s,
    int* __restrict__ cnt, int N, int E)
{
    const int* rows = blockIdx.y ? rows_s : rows_o;
    int* c = cnt + (size_t)blockIdx.y * N;
    int e = blockIdx.x * 256 + threadIdx.x;
    if (e < E) atomicAdd(&c[rows[e]], 1);
}

__global__ __launch_bounds__(256) void scan_partial2(
    const int* __restrict__ cnt, int* __restrict__ part, int N)
{
    __shared__ int red[256];
    const int* c = cnt + (size_t)blockIdx.y * N;
    int* p = part + blockIdx.y * 1024;
    const int b = blockIdx.x, t = threadIdx.x;
    const int i = b * SCAN_CHUNK + 2 * t;
    int s = 0;
    if (i < N) s += c[i];
    if (i + 1 < N) s += c[i + 1];
    red[t] = s;
    __syncthreads();
    #pragma unroll
    for (int off = 128; off > 0; off >>= 1) {
        if (t < off) red[t] += red[t + off];
        __syncthreads();
    }
    if (t == 0) p[b] = red[0];
}

__global__ __launch_bounds__(1024) void scan_blocks2(
    int* __restrict__ part, int nblk)
{
    __shared__ int sh[1024];
    int* p = part + blockIdx.y * 1024;
    const int t = threadIdx.x;
    const int v = (t < nblk) ? p[t] : 0;
    sh[t] = v;
    __syncthreads();
    for (int off = 1; off < 1024; off <<= 1) {
        int u = (t >= off) ? sh[t - off] : 0;
        __syncthreads();
        sh[t] += u;
        __syncthreads();
    }
    if (t < nblk) p[t] = sh[t] - v;   // exclusive
}

// cnt aliases cursor (same slab): block-local reads complete before writes.
__global__ __launch_bounds__(256) void scan_final2(
    const int* __restrict__ cnt, const int* __restrict__ part,
    int* __restrict__ rp_o, int* __restrict__ rp_s,
    int* __restrict__ cursor, int N, int E)
{
    __shared__ int sh[256];
    const int y = blockIdx.y;
    const int* c = cnt + (size_t)y * N;
    const int* p = part + y * 1024;
    int* rp = y ? rp_s : rp_o;
    int* cur = cursor + (size_t)y * N;
    const int b = blockIdx.x, t = threadIdx.x;
    const int i = b * SCAN_CHUNK + 2 * t;
    const int c0 = (i < N) ? c[i] : 0;
    const int c1 = (i + 1 < N) ? c[i + 1] : 0;
    const int s = c0 + c1;
    sh[t] = s;
    __syncthreads();
    for (int off = 1; off < 256; off <<= 1) {
        int u = (t >= off) ? sh[t - off] : 0;
        __syncthreads();
        sh[t] += u;
        __syncthreads();
    }
    const int base = p[b] + sh[t] - s;
    if (i < N)     { rp[i] = base;          cur[i] = base; }
    if (i + 1 < N) { rp[i + 1] = base + c0; cur[i + 1] = base + c0; }
    if (b == 0 && t == 0) rp[N] = E;
}

__global__ __launch_bounds__(256) void scatter2(
    const int* __restrict__ ro, const int* __restrict__ co,
    const float* __restrict__ vo,
    const int* __restrict__ rs, const int* __restrict__ cs,
    const float* __restrict__ vs,
    int* __restrict__ cursor, int2* __restrict__ ev_o,
    int2* __restrict__ ev_s, int N, int E)
{
    const int y = blockIdx.y;
    const int* rows = y ? rs : ro;
    const int* cols = y ? cs : co;
    const float* vals = y ? vs : vo;
    int* cur = cursor + (size_t)y * N;
    int2* ev = y ? ev_s : ev_o;
    int e = blockIdx.x * 256 + threadIdx.x;
    if (e < E) {
        int r = rows[e];
        int pz = atomicAdd(&cur[r], 1);
        ev[pz] = make_int2(cols[e], __float_as_int(vals[e]));
    }
}

// ---------------------------------------------------------------------------
// Fused MFMA GEMM: S_m = X @ W_m for NM matrices, X staged ONCE (full K) in LDS.
// X: [Nrows,K] fp32 (XBF=false) or bf16 (XBF=true). Wt: [128,K] bf16.
// S: [Nrows,128] bf16. Block 256 thr (4 waves), tile BM=64, wave owns 16 rows.
// LDS: As 64 x (K+8), Bs 128 x 72 (both 2-way bank aliasing = free).
// ---------------------------------------------------------------------------
template <int K, int NM, bool XBF>
__global__ __launch_bounds__(256) void gemm_fused(
    const void* __restrict__ Xv,
    const unsigned short* __restrict__ Wt0, unsigned short* __restrict__ S0,
    const unsigned short* __restrict__ Wt1, unsigned short* __restrict__ S1,
    const unsigned short* __restrict__ Wt2, unsigned short* __restrict__ S2,
    int Nrows)
{
    constexpr int AST = K + 8;
    __shared__ unsigned short As[64 * AST];
    __shared__ unsigned short Bs[128 * 72];

    const int t = threadIdx.x;
    const int l = t & 63;
    const int w = t >> 6;
    const int row_in = l & 15;
    const int kgrp = l >> 4;        // 0..3
    const int row0 = blockIdx.x * 64;

    // stage A: 64 rows x K, once
    {
        constexpr int QPR = K / 4;                  // quads per row
        #pragma unroll
        for (int it = 0; it < 64 * QPR / 256; ++it) {
            int i = t + it * 256;
            int r = i / QPR, c4 = i % QPR;
            int gr = row0 + r;
            if (XBF) {
                ushort4 v = make_ushort4(0, 0, 0, 0);
                if (gr < Nrows)
                    v = *(const ushort4*)((const unsigned short*)Xv + (size_t)gr * K + c4 * 4);
                *(ushort4*)&As[r * AST + c4 * 4] = v;
            } else {
                float4 v = make_float4(0.f, 0.f, 0.f, 0.f);
                if (gr < Nrows)
                    v = *(const float4*)((const float*)Xv + (size_t)gr * K + c4 * 4);
                ushort4 b4;
                b4.x = f2bf(v.x); b4.y = f2bf(v.y); b4.z = f2bf(v.z); b4.w = f2bf(v.w);
                *(ushort4*)&As[r * AST + c4 * 4] = b4;
            }
        }
    }

    #pragma unroll
    for (int m = 0; m < NM; ++m) {
        const unsigned short* Wt = (m == 0) ? Wt0 : ((m == 1) ? Wt1 : Wt2);
        unsigned short* S = (m == 0) ? S0 : ((m == 1) ? S1 : S2);
        float4v acc[8];
        #pragma unroll
        for (int n = 0; n < 8; ++n) acc[n] = (float4v)(0.f);

        for (int kt = 0; kt < K / 64; ++kt) {
            __syncthreads();    // A visible (1st iter); prior Bs reads done
            #pragma unroll
            for (int it = 0; it < 8; ++it) {
                int i = t + it * 256;
                int r = i >> 4, c4 = i & 15;
                *(ushort4*)&Bs[r * 72 + c4 * 4] =
                    *(const ushort4*)(Wt + (size_t)r * K + kt * 64 + c4 * 4);
            }
            __syncthreads();
            #pragma unroll
            for (int kc = 0; kc < 2; ++kc) {
                short8v a, b[8];
                const unsigned short* pa =
                    &As[(w * 16 + row_in) * AST + kt * 64 + kc * 32 + kgrp * 8];
                ((uint2*)&a)[0] = *(const uint2*)pa;
                ((uint2*)&a)[1] = *(const uint2*)(pa + 4);
                #pragma unroll
                for (int n = 0; n < 8; ++n) {
                    const unsigned short* pb =
                        &Bs[(n * 16 + row_in) * 72 + kc * 32 + kgrp * 8];
                    ((uint2*)&b[n])[0] = *(const uint2*)pb;
                    ((uint2*)&b[n])[1] = *(const uint2*)(pb + 4);
                }
                #pragma unroll
                for (int n = 0; n < 8; ++n)
                    acc[n] = __builtin_amdgcn_mfma_f32_16x16x32_bf16(
                        a, b[n], acc[n], 0, 0, 0);
            }
        }
        // epilogue: col=lane&15, row=kgrp*4+reg
        #pragma unroll
        for (int n = 0; n < 8; ++n)
            #pragma unroll
            for (int r = 0; r < 4; ++r) {
                int gr = row0 + w * 16 + kgrp * 4 + r;
                int gc = n * 16 + row_in;
                if (gr < Nrows) S[(size_t)gr * 128 + gc] = f2bf(acc[n][r]);
            }
    }
}

// ---------------------------------------------------------------------------
// Fused dual-graph CSR SpMM: out[row] = maybe_relu(b1+b2 + sum_A + sum_B)
// One wave per row; lane l owns features 2l, 2l+1. Tables bf16.
// 8-way edge unroll for MLP. Output bf16 (OBF) or fp32.
// ---------------------------------------------------------------------------
template <bool OBF>
__global__ __launch_bounds__(256) void spmm2_csr(
    const int* __restrict__ rp_a, const int2* __restrict__ ev_a,
    const unsigned short* __restrict__ Sa,
    const int* __restrict__ rp_b, const int2* __restrict__ ev_b,
    const unsigned short* __restrict__ Sb,
    const float* __restrict__ b1, const float* __restrict__ b2,
    void* __restrict__ outv, int N, int do_relu)
{
    const int row = blockIdx.x * 4 + (threadIdx.x >> 6);
    if (row >= N) return;
    const int l2 = (threadIdx.x & 63) << 1;

    float2 bv1 = *(const float2*)(b1 + l2);
    float2 bv2 = *(const float2*)(b2 + l2);
    float ax = bv1.x + bv2.x;
    float ay = bv1.y + bv2.y;

    #pragma unroll
    for (int g = 0; g < 2; ++g) {
        const int* __restrict__ rp = g ? rp_b : rp_a;
        const int2* __restrict__ ev = g ? ev_b : ev_a;
        const unsigned short* __restrict__ S = g ? Sb : Sa;

        int e = rp[row];
        const int e1 = rp[row + 1];
        for (; e + 8 <= e1; e += 8) {
            int2 p0 = ev[e],     p1 = ev[e + 1], p2 = ev[e + 2], p3 = ev[e + 3];
            int2 p4 = ev[e + 4], p5 = ev[e + 5], p6 = ev[e + 6], p7 = ev[e + 7];
            unsigned u0 = *(const unsigned*)(S + ((size_t)p0.x << 7) + l2);
            unsigned u1 = *(const unsigned*)(S + ((size_t)p1.x << 7) + l2);
            unsigned u2 = *(const unsigned*)(S + ((size_t)p2.x << 7) + l2);
            unsigned u3 = *(const unsigned*)(S + ((size_t)p3.x << 7) + l2);
            unsigned u4 = *(const unsigned*)(S + ((size_t)p4.x << 7) + l2);
            unsigned u5 = *(const unsigned*)(S + ((size_t)p5.x << 7) + l2);
            unsigned u6 = *(const unsigned*)(S + ((size_t)p6.x << 7) + l2);
            unsigned u7 = *(const unsigned*)(S + ((size_t)p7.x << 7) + l2);
            float v0 = __int_as_float(p0.y), v1 = __int_as_float(p1.y);
            float v2 = __int_as_float(p2.y), v3 = __int_as_float(p3.y);
            float v4 = __int_as_float(p4.y), v5 = __int_as_float(p5.y);
            float v6 = __int_as_float(p6.y), v7 = __int_as_float(p7.y);
            ax = fmaf(v0, asf(u0 << 16), ax); ay = fmaf(v0, asf(u0 & 0xffff0000u), ay);
            ax = fmaf(v1, asf(u1 << 16), ax); ay = fmaf(v1, asf(u1 & 0xffff0000u), ay);
            ax = fmaf(v2, asf(u2 << 16), ax); ay = fmaf(v2, asf(u2 & 0xffff0000u), ay);
            ax = fmaf(v3, asf(u3 << 16), ax); ay = fmaf(v3, asf(u3 & 0xffff0000u), ay);
            ax = fmaf(v4, asf(u4 << 16), ax); ay = fmaf(v4, asf(u4 & 0xffff0000u), ay);
            ax = fmaf(v5, asf(u5 << 16), ax); ay = fmaf(v5, asf(u5 & 0xffff0000u), ay);
            ax = fmaf(v6, asf(u6 << 16), ax); ay = fmaf(v6, asf(u6 & 0xffff0000u), ay);
            ax = fmaf(v7, asf(u7 << 16), ax); ay = fmaf(v7, asf(u7 & 0xffff0000u), ay);
        }
        for (; e + 4 <= e1; e += 4) {
            int2 p0 = ev[e], p1 = ev[e + 1], p2 = ev[e + 2], p3 = ev[e + 3];
            unsigned u0 = *(const unsigned*)(S + ((size_t)p0.x << 7) + l2);
            unsigned u1 = *(const unsigned*)(S + ((size_t)p1.x << 7) + l2);
            unsigned u2 = *(const unsigned*)(S + ((size_t)p2.x << 7) + l2);
            unsigned u3 = *(const unsigned*)(S + ((size_t)p3.x << 7) + l2);
            float v0 = __int_as_float(p0.y), v1 = __int_as_float(p1.y);
            float v2 = __int_as_float(p2.y), v3 = __int_as_float(p3.y);
            ax = fmaf(v0, asf(u0 << 16), ax); ay = fmaf(v0, asf(u0 & 0xffff0000u), ay);
            ax = fmaf(v1, asf(u1 << 16), ax); ay = fmaf(v1, asf(u1 & 0xffff0000u), ay);
            ax = fmaf(v2, asf(u2 << 16), ax); ay = fmaf(v2, asf(u2 & 0xffff0000u), ay);
            ax = fmaf(v3, asf(u3 << 16), ax); ay = fmaf(v3, asf(u3 & 0xffff0000u), ay);
        }
        for (; e < e1; ++e) {
            int2 p = ev[e];
            unsigned u = *(const unsigned*)(S + ((size_t)p.x << 7) + l2);
            float v = __int_as_float(p.y);
            ax = fmaf(v, asf(u << 16), ax);
            ay = fmaf(v, asf(u & 0xffff0000u), ay);
        }
    }
    if (do_relu) { ax = fmaxf(ax, 0.f); ay = fmaxf(ay, 0.f); }
    if (OBF) {
        unsigned pk = (unsigned)f2bf(ax) | ((unsigned)f2bf(ay) << 16);
        ((unsigned*)outv)[((size_t)row << 6) + (l2 >> 1)] = pk;
    } else {
        float2 o; o.x = ax; o.y = ay;
        *(float2*)((float*)outv + ((size_t)row << 7) + l2) = o;
    }
}

// ---------------------------------------------------------------------------
// Decoder stage 1: out[b] = concat(h[idx0[b]], h[idx1[b]]) @ W + bias -> [B,128]
// ---------------------------------------------------------------------------
__global__ __launch_bounds__(128) void dec1_kernel(
    const float* __restrict__ h,
    const int* __restrict__ idx0, const int* __restrict__ idx1,
    const float* __restrict__ W, const float* __restrict__ bias,
    float* __restrict__ out, int B)
{
    __shared__ __align__(16) float fs[16 * 256];
    const int t = threadIdx.x;
    const int b0 = blockIdx.x * 16;
    #pragma unroll
    for (int r = 0; r < 16; ++r) {
        const int b = b0 + r;
        fs[r * 256 + t]       = h[(long)idx0[b] * 128 + t];
        fs[r * 256 + 128 + t] = h[(long)idx1[b] * 128 + t];
    }
    __syncthreads();

    const float4* fs4 = (const float4*)fs;
    float acc[16];
    #pragma unroll
    for (int r = 0; r < 16; ++r) acc[r] = 0.f;
    for (int kc = 0; kc < 64; ++kc) {
        const float w0 = W[(kc * 4 + 0) * 128 + t];
        const float w1 = W[(kc * 4 + 1) * 128 + t];
        const float w2 = W[(kc * 4 + 2) * 128 + t];
        const float w3 = W[(kc * 4 + 3) * 128 + t];
        #pragma unroll
        for (int r = 0; r < 16; ++r) {
            const float4 xv = fs4[r * 64 + kc];
            acc[r] = fmaf(xv.x, w0, acc[r]);
            acc[r] = fmaf(xv.y, w1, acc[r]);
            acc[r] = fmaf(xv.z, w2, acc[r]);
            acc[r] = fmaf(xv.w, w3, acc[r]);
        }
    }
    #pragma unroll
    for (int r = 0; r < 16; ++r)
        out[(long)(b0 + r) * 128 + t] = acc[r] + bias[t];
}

// ---------------------------------------------------------------------------
// Decoder stage 2: out[b] = o1[b] @ W + bias -> [B, 86]
// ---------------------------------------------------------------------------
__global__ __launch_bounds__(128) void dec2_kernel(
    const float* __restrict__ o1,
    const float* __restrict__ W, const float* __restrict__ bias,
    float* __restrict__ out, int B)
{
    __shared__ __align__(16) float os[16 * 128];
    const int t = threadIdx.x;
    const int b0 = blockIdx.x * 16;
    #pragma unroll
    for (int r = 0; r < 16; ++r)
        os[r * 128 + t] = o1[(long)(b0 + r) * 128 + t];
    __syncthreads();

    const float4* os4 = (const float4*)os;
    float acc[16];
    #pragma unroll
    for (int r = 0; r < 16; ++r) acc[r] = 0.f;
    const bool act = (t < RELL);
    for (int kc = 0; kc < 32; ++kc) {
        const float w0 = act ? W[(kc * 4 + 0) * RELL + t] : 0.f;
        const float w1 = act ? W[(kc * 4 + 1) * RELL + t] : 0.f;
        const float w2 = act ? W[(kc * 4 + 2) * RELL + t] : 0.f;
        const float w3 = act ? W[(kc * 4 + 3) * RELL + t] : 0.f;
        #pragma unroll
        for (int r = 0; r < 16; ++r) {
            const float4 xv = os4[r * 32 + kc];
            acc[r] = fmaf(xv.x, w0, acc[r]);
            acc[r] = fmaf(xv.y, w1, acc[r]);
            acc[r] = fmaf(xv.z, w2, acc[r]);
            acc[r] = fmaf(xv.w, w3, acc[r]);
        }
    }
    if (act) {
        #pragma unroll
        for (int r = 0; r < 16; ++r)
            out[(long)(b0 + r) * RELL + t] = acc[r] + bias[t];
    }
}

extern "C" void kernel_launch(void* const* d_in, const int* in_sizes, int n_in,
                              void* d_out, int out_size, void* d_ws, size_t ws_size,
                              hipStream_t stream) {
    const float* x      = (const float*)d_in[0];
    const int*   o_rows = (const int*)  d_in[1];
    const int*   o_cols = (const int*)  d_in[2];
    const float* o_vals = (const float*)d_in[3];
    const int*   s_rows = (const int*)  d_in[4];
    const int*   s_cols = (const int*)  d_in[5];
    const float* s_vals = (const float*)d_in[6];
    const int*   idx    = (const int*)  d_in[7];
    const float* W_ogc1  = (const float*)d_in[8];   const float* b_ogc1  = (const float*)d_in[9];
    const float* W_sgc1o = (const float*)d_in[10];  const float* b_sgc1o = (const float*)d_in[11];
    const float* W_sgc1  = (const float*)d_in[12];  const float* b_sgc1  = (const float*)d_in[13];
    const float* W_ogc1s = (const float*)d_in[14];  const float* b_ogc1s = (const float*)d_in[15];
    const float* W_ogc2  = (const float*)d_in[16];  const float* b_ogc2  = (const float*)d_in[17];
    const float* W_sgc2o = (const float*)d_in[18];  const float* b_sgc2o = (const float*)d_in[19];
    const float* W_dec1  = (const float*)d_in[20];  const float* b_dec1  = (const float*)d_in[21];
    const float* W_dec2  = (const float*)d_in[22];  const float* b_dec2  = (const float*)d_in[23];

    const int N = in_sizes[0] / NFEAT;   // 100000
    const int E = in_sizes[1];           // 1600000
    const int B = in_sizes[7] / 2;       // 16384
    const int* idx0 = idx;
    const int* idx1 = idx + B;

    // ---- workspace layout (float units; all offsets even -> 8B aligned) ----
    float* p = (float*)d_ws;
    const size_t N64 = (size_t)N * 64;    // one bf16 [N,128] table in float units
    float* h    = p;  p += (size_t)N * 128;          // fp32 [N,128]
    unsigned short* oxb  = (unsigned short*)p; p += N64;   // o_x bf16
    unsigned short* sxb  = (unsigned short*)p; p += N64;   // s_x bf16
    unsigned short* tabA = (unsigned short*)p; p += N64;
    unsigned short* tabB = (unsigned short*)p; p += N64;
    unsigned short* tabC = (unsigned short*)p; p += N64;
    unsigned short* tabD = (unsigned short*)p; p += N64;
    float* o1buf = p; p += (size_t)B * 128;
    unsigned short* wt1 = (unsigned short*)p; p += 16384;   // [128,256] bf16
    unsigned short* wt2 = (unsigned short*)p; p += 16384;
    unsigned short* wt3 = (unsigned short*)p; p += 16384;
    unsigned short* wt4 = (unsigned short*)p; p += 8192;    // [128,128] bf16
    unsigned short* wt5 = (unsigned short*)p; p += 8192;
    unsigned short* wt6 = (unsigned short*)p; p += 8192;
    int* rp_o = (int*)p; p += (size_t)N + 2;
    int* rp_s = (int*)p; p += (size_t)N + 2;
    int* cur  = (int*)p; p += 2 * (size_t)N;         // [2][N] counts->cursor
    int2* ev_o = (int2*)p; p += 2 * (size_t)E;
    int2* ev_s = (int2*)p; p += 2 * (size_t)E;
    int* part  = (int*)p; p += 2048;                 // [2][1024]

    const int gM64 = (N + 63) / 64;       // 1563
    const int gE = (E + 255) / 256;       // 6250
    const int gR = (N + 3) / 4;           // 25000
    const int gB = B / 16;                // 1024
    const int gScan = (N + SCAN_CHUNK - 1) / SCAN_CHUNK;  // 196

    // ---- CSR build (both graphs via y-grid)
    hipMemsetAsync(cur, 0, 2 * (size_t)N * sizeof(int), stream);
    hist2<<<dim3(gE, 2), 256, 0, stream>>>(o_rows, s_rows, cur, N, E);
    scan_partial2<<<dim3(gScan, 2), 256, 0, stream>>>(cur, part, N);
    scan_blocks2<<<dim3(1, 2), 1024, 0, stream>>>(part, gScan);
    scan_final2<<<dim3(gScan, 2), 256, 0, stream>>>(cur, part, rp_o, rp_s, cur, N, E);
    scatter2<<<dim3(gE, 2), 256, 0, stream>>>(o_rows, o_cols, o_vals,
                                              s_rows, s_cols, s_vals,
                                              cur, ev_o, ev_s, N, E);

    // ---- weight prep
    wt_prep3<NFEAT><<<dim3(128, 3), 256, 0, stream>>>(W_ogc1, W_sgc1o, W_sgc1,
                                                      wt1, wt2, wt3);
    wt_prep3<NHID><<<dim3(64, 3), 256, 0, stream>>>(W_ogc1s, W_ogc2, W_sgc2o,
                                                    wt4, wt5, wt6);

    // ---- Layer 1 GEMMs (x read once): tabA=x@W_ogc1, tabB=x@W_sgc1o, tabC=x@W_sgc1
    gemm_fused<NFEAT, 3, false><<<gM64, 256, 0, stream>>>(
        x, wt1, tabA, wt2, tabB, wt3, tabC, N);
    // o_x = relu(spmm_o(tabA) + spmm_s(tabB) + b)  -> bf16
    spmm2_csr<true><<<gR, 256, 0, stream>>>(rp_o, ev_o, tabA, rp_s, ev_s, tabB,
                                            b_ogc1, b_sgc1o, oxb, N, 1);

    // ---- Layer 2: tabD = o_x@W_ogc1s;  s_x = relu(spmm_o(tabD) + spmm_s(tabC) + b) -> bf16
    gemm_fused<NHID, 1, true><<<gM64, 256, 0, stream>>>(
        oxb, wt4, tabD, nullptr, nullptr, nullptr, nullptr, N);
    spmm2_csr<true><<<gR, 256, 0, stream>>>(rp_o, ev_o, tabD, rp_s, ev_s, tabC,
                                            b_ogc1s, b_sgc1, sxb, N, 1);

    // ---- Layer 3: tabA = o_x@W_ogc2; tabB = s_x@W_sgc2o; h = spmm sum (fp32)
    gemm_fused<NHID, 1, true><<<gM64, 256, 0, stream>>>(
        oxb, wt5, tabA, nullptr, nullptr, nullptr, nullptr, N);
    gemm_fused<NHID, 1, true><<<gM64, 256, 0, stream>>>(
        sxb, wt6, tabB, nullptr, nullptr, nullptr, nullptr, N);
    spmm2_csr<false><<<gR, 256, 0, stream>>>(rp_o, ev_o, tabA, rp_s, ev_s, tabB,
                                             b_ogc2, b_sgc2o, h, N, 0);

    // ---- Decoder
    dec1_kernel<<<gB, 128, 0, stream>>>(h, idx0, idx1, W_dec1, b_dec1, o1buf, B);
    dec2_kernel<<<gB, 128, 0, stream>>>(o1buf, W_dec2, b_dec2, (float*)d_out, B);
}

// Round 7
// 799.665 us; speedup vs baseline: 6.3590x; 1.1258x over previous
//
#include <hip/hip_runtime.h>
#include <hip/hip_bf16.h>

#define NFEAT 256
#define NHID 128
#define RELL 86
#define SCAN_CHUNK 512
#define BSHIFT 9                 // bucket = row >> 9 (512 rows)
#define SCAT_TILE 4096           // edges per binscat1 block (16/thread)

typedef __attribute__((ext_vector_type(8))) short short8v;
typedef __attribute__((ext_vector_type(4))) float float4v;

static __device__ __forceinline__ unsigned short f2bf(float f) {
    union { float f; unsigned int u; } v; v.f = f;
    unsigned int r = v.u + 0x7FFF + ((v.u >> 16) & 1);   // RNE
    return (unsigned short)(r >> 16);
}
static __device__ __forceinline__ float asf(unsigned int u) {
    union { unsigned int u; float f; } v; v.u = u; return v.f;
}

// ---------------------------------------------------------------------------
// Weight prep: 3 matrices per launch via blockIdx.y. Wt[col][k] = bf16(W[k][col])
// ---------------------------------------------------------------------------
template <int K>
__global__ __launch_bounds__(256) void wt_prep3(
    const float* __restrict__ W0, const float* __restrict__ W1,
    const float* __restrict__ W2,
    unsigned short* __restrict__ T0, unsigned short* __restrict__ T1,
    unsigned short* __restrict__ T2)
{
    const float* W = (blockIdx.y == 0) ? W0 : ((blockIdx.y == 1) ? W1 : W2);
    unsigned short* T = (blockIdx.y == 0) ? T0 : ((blockIdx.y == 1) ? T1 : T2);
    int i = blockIdx.x * 256 + threadIdx.x;
    if (i < K * 128) {
        int col = i & 127, k = i >> 7;
        T[col * K + k] = f2bf(W[i]);
    }
}

// ---------------------------------------------------------------------------
// CSR build: histogram -> hierarchical scan -> binned two-phase scatter
// ---------------------------------------------------------------------------
__global__ __launch_bounds__(256) void hist2(
    const int* __restrict__ rows_o, const int* __restrict__ rows_s,
    int* __restrict__ cnt, int N, int E)
{
    const int* rows = blockIdx.y ? rows_s : rows_o;
    int* c = cnt + (size_t)blockIdx.y * N;
    int e = blockIdx.x * 256 + threadIdx.x;
    if (e < E) atomicAdd(&c[rows[e]], 1);
}

__global__ __launch_bounds__(256) void scan_partial2(
    const int* __restrict__ cnt, int* __restrict__ part, int N)
{
    __shared__ int red[256];
    const int* c = cnt + (size_t)blockIdx.y * N;
    int* p = part + blockIdx.y * 1024;
    const int b = blockIdx.x, t = threadIdx.x;
    const int i = b * SCAN_CHUNK + 2 * t;
    int s = 0;
    if (i < N) s += c[i];
    if (i + 1 < N) s += c[i + 1];
    red[t] = s;
    __syncthreads();
    #pragma unroll
    for (int off = 128; off > 0; off >>= 1) {
        if (t < off) red[t] += red[t + off];
        __syncthreads();
    }
    if (t == 0) p[b] = red[0];
}

__global__ __launch_bounds__(1024) void scan_blocks2(
    int* __restrict__ part, int nblk)
{
    __shared__ int sh[1024];
    int* p = part + blockIdx.y * 1024;
    const int t = threadIdx.x;
    const int v = (t < nblk) ? p[t] : 0;
    sh[t] = v;
    __syncthreads();
    for (int off = 1; off < 1024; off <<= 1) {
        int u = (t >= off) ? sh[t - off] : 0;
        __syncthreads();
        sh[t] += u;
        __syncthreads();
    }
    if (t < nblk) p[t] = sh[t] - v;   // exclusive
}

__global__ __launch_bounds__(256) void scan_final2(
    const int* __restrict__ cnt, const int* __restrict__ part,
    int* __restrict__ rp_o, int* __restrict__ rp_s, int N, int E)
{
    __shared__ int sh[256];
    const int y = blockIdx.y;
    const int* c = cnt + (size_t)y * N;
    const int* p = part + y * 1024;
    int* rp = y ? rp_s : rp_o;
    const int b = blockIdx.x, t = threadIdx.x;
    const int i = b * SCAN_CHUNK + 2 * t;
    const int c0 = (i < N) ? c[i] : 0;
    const int c1 = (i + 1 < N) ? c[i + 1] : 0;
    const int s = c0 + c1;
    sh[t] = s;
    __syncthreads();
    for (int off = 1; off < 256; off <<= 1) {
        int u = (t >= off) ? sh[t - off] : 0;
        __syncthreads();
        sh[t] += u;
        __syncthreads();
    }
    const int base = p[b] + sh[t] - s;
    if (i < N)     rp[i] = base;
    if (i + 1 < N) rp[i + 1] = base + c0;
    if (b == 0 && t == 0) rp[N] = E;
}

// bucket cursors seeded with rp[b*512]
__global__ __launch_bounds__(512) void binit(
    const int* __restrict__ rp_o, const int* __restrict__ rp_s,
    int* __restrict__ bcur, int N)
{
    const int t = threadIdx.x;          // [0,512)
    const int g = t >> 8, b = t & 255;
    const int* rp = g ? rp_s : rp_o;
    int r = b << BSHIFT;
    bcur[t] = rp[(r < N) ? r : N];
}

// Phase 1: bin edges by row>>9 into temp, packed (row&511 | col<<9, val_bits).
// Per-block LDS histogram -> one global reserve per bucket -> chunked writes.
__global__ __launch_bounds__(256) void binscat1(
    const int* __restrict__ ro, const int* __restrict__ co,
    const float* __restrict__ vo,
    const int* __restrict__ rs, const int* __restrict__ cs,
    const float* __restrict__ vs,
    int* __restrict__ bcur, int2* __restrict__ temp_o,
    int2* __restrict__ temp_s, int E)
{
    const int g = blockIdx.y;
    const int* rows = g ? rs : ro;
    const int* cols = g ? cs : co;
    const float* vals = g ? vs : vo;
    int* bc = bcur + g * 256;
    int2* temp = g ? temp_s : temp_o;

    __shared__ int hist[256];
    __shared__ int base[256];
    const int t = threadIdx.x;
    hist[t] = 0;
    __syncthreads();

    const int e0 = blockIdx.x * SCAT_TILE;
    int myrow[16];
    #pragma unroll
    for (int i = 0; i < 16; ++i) {
        int e = e0 + i * 256 + t;
        int r = (e < E) ? rows[e] : -1;
        myrow[i] = r;
        if (r >= 0) atomicAdd(&hist[r >> BSHIFT], 1);
    }
    __syncthreads();
    const int h = hist[t];
    if (h > 0) base[t] = atomicAdd(&bc[t], h);
    __syncthreads();
    hist[t] = (h > 0) ? base[t] : 0;     // reuse hist as within-block cursor
    __syncthreads();
    #pragma unroll
    for (int i = 0; i < 16; ++i) {
        const int r = myrow[i];
        if (r >= 0) {
            int e = e0 + i * 256 + t;
            int off = atomicAdd(&hist[r >> BSHIFT], 1);
            temp[off] = make_int2((r & 511) | (cols[e] << BSHIFT),
                                  __float_as_int(vals[e]));
        }
    }
}

// Phase 2: per-bucket block; LDS row cursors from rp; contiguous read of the
// bucket's temp region; writes confined to the bucket's CSR region.
__global__ __launch_bounds__(256) void binscat2(
    const int* __restrict__ rp_o, const int* __restrict__ rp_s,
    const int2* __restrict__ temp_o, const int2* __restrict__ temp_s,
    int2* __restrict__ ev_o, int2* __restrict__ ev_s, int N)
{
    const int g = blockIdx.y;
    const int* rp = g ? rp_s : rp_o;
    const int2* temp = g ? temp_s : temp_o;
    int2* ev = g ? ev_s : ev_o;

    __shared__ int lcur[512];
    const int b = blockIdx.x;
    const int r0 = b << BSHIFT;
    const int t = threadIdx.x;
    #pragma unroll
    for (int i = 0; i < 2; ++i) {
        int r = r0 + t + i * 256;
        lcur[t + i * 256] = (r < N) ? rp[r] : 0;
    }
    __syncthreads();
    const int e0 = rp[r0];
    const int rend = r0 + 512;
    const int e1 = rp[(rend < N) ? rend : N];

    int e = e0 + t;
    for (; e + 768 < e1; e += 1024) {
        int2 p0 = temp[e];
        int2 p1 = temp[e + 256];
        int2 p2 = temp[e + 512];
        int2 p3 = temp[e + 768];
        int q0 = atomicAdd(&lcur[p0.x & 511], 1);
        int q1 = atomicAdd(&lcur[p1.x & 511], 1);
        int q2 = atomicAdd(&lcur[p2.x & 511], 1);
        int q3 = atomicAdd(&lcur[p3.x & 511], 1);
        ev[q0] = make_int2(p0.x >> BSHIFT, p0.y);
        ev[q1] = make_int2(p1.x >> BSHIFT, p1.y);
        ev[q2] = make_int2(p2.x >> BSHIFT, p2.y);
        ev[q3] = make_int2(p3.x >> BSHIFT, p3.y);
    }
    for (; e < e1; e += 256) {
        int2 pk = temp[e];
        int q = atomicAdd(&lcur[pk.x & 511], 1);
        ev[q] = make_int2(pk.x >> BSHIFT, pk.y);
    }
}

// ---------------------------------------------------------------------------
// Fused MFMA GEMM: S_m = X @ W_m for NM matrices, X staged ONCE (full K) in LDS.
// ---------------------------------------------------------------------------
template <int K, int NM, bool XBF>
__global__ __launch_bounds__(256) void gemm_fused(
    const void* __restrict__ Xv,
    const unsigned short* __restrict__ Wt0, unsigned short* __restrict__ S0,
    const unsigned short* __restrict__ Wt1, unsigned short* __restrict__ S1,
    const unsigned short* __restrict__ Wt2, unsigned short* __restrict__ S2,
    int Nrows)
{
    constexpr int AST = K + 8;
    __shared__ unsigned short As[64 * AST];
    __shared__ unsigned short Bs[128 * 72];

    const int t = threadIdx.x;
    const int l = t & 63;
    const int w = t >> 6;
    const int row_in = l & 15;
    const int kgrp = l >> 4;        // 0..3
    const int row0 = blockIdx.x * 64;

    {
        constexpr int QPR = K / 4;
        #pragma unroll
        for (int it = 0; it < 64 * QPR / 256; ++it) {
            int i = t + it * 256;
            int r = i / QPR, c4 = i % QPR;
            int gr = row0 + r;
            if (XBF) {
                ushort4 v = make_ushort4(0, 0, 0, 0);
                if (gr < Nrows)
                    v = *(const ushort4*)((const unsigned short*)Xv + (size_t)gr * K + c4 * 4);
                *(ushort4*)&As[r * AST + c4 * 4] = v;
            } else {
                float4 v = make_float4(0.f, 0.f, 0.f, 0.f);
                if (gr < Nrows)
                    v = *(const float4*)((const float*)Xv + (size_t)gr * K + c4 * 4);
                ushort4 b4;
                b4.x = f2bf(v.x); b4.y = f2bf(v.y); b4.z = f2bf(v.z); b4.w = f2bf(v.w);
                *(ushort4*)&As[r * AST + c4 * 4] = b4;
            }
        }
    }

    #pragma unroll
    for (int m = 0; m < NM; ++m) {
        const unsigned short* Wt = (m == 0) ? Wt0 : ((m == 1) ? Wt1 : Wt2);
        unsigned short* S = (m == 0) ? S0 : ((m == 1) ? S1 : S2);
        float4v acc[8];
        #pragma unroll
        for (int n = 0; n < 8; ++n) acc[n] = (float4v)(0.f);

        for (int kt = 0; kt < K / 64; ++kt) {
            __syncthreads();
            #pragma unroll
            for (int it = 0; it < 8; ++it) {
                int i = t + it * 256;
                int r = i >> 4, c4 = i & 15;
                *(ushort4*)&Bs[r * 72 + c4 * 4] =
                    *(const ushort4*)(Wt + (size_t)r * K + kt * 64 + c4 * 4);
            }
            __syncthreads();
            #pragma unroll
            for (int kc = 0; kc < 2; ++kc) {
                short8v a, b[8];
                const unsigned short* pa =
                    &As[(w * 16 + row_in) * AST + kt * 64 + kc * 32 + kgrp * 8];
                ((uint2*)&a)[0] = *(const uint2*)pa;
                ((uint2*)&a)[1] = *(const uint2*)(pa + 4);
                #pragma unroll
                for (int n = 0; n < 8; ++n) {
                    const unsigned short* pb =
                        &Bs[(n * 16 + row_in) * 72 + kc * 32 + kgrp * 8];
                    ((uint2*)&b[n])[0] = *(const uint2*)pb;
                    ((uint2*)&b[n])[1] = *(const uint2*)(pb + 4);
                }
                #pragma unroll
                for (int n = 0; n < 8; ++n)
                    acc[n] = __builtin_amdgcn_mfma_f32_16x16x32_bf16(
                        a, b[n], acc[n], 0, 0, 0);
            }
        }
        #pragma unroll
        for (int n = 0; n < 8; ++n)
            #pragma unroll
            for (int r = 0; r < 4; ++r) {
                int gr = row0 + w * 16 + kgrp * 4 + r;
                int gc = n * 16 + row_in;
                if (gr < Nrows) S[(size_t)gr * 128 + gc] = f2bf(acc[n][r]);
            }
    }
}

// ---------------------------------------------------------------------------
// Fused dual-graph CSR SpMM (8-way MLP unroll), bf16 tables, bf16/fp32 out.
// ---------------------------------------------------------------------------
template <bool OBF>
__global__ __launch_bounds__(256) void spmm2_csr(
    const int* __restrict__ rp_a, const int2* __restrict__ ev_a,
    const unsigned short* __restrict__ Sa,
    const int* __restrict__ rp_b, const int2* __restrict__ ev_b,
    const unsigned short* __restrict__ Sb,
    const float* __restrict__ b1, const float* __restrict__ b2,
    void* __restrict__ outv, int N, int do_relu)
{
    const int row = blockIdx.x * 4 + (threadIdx.x >> 6);
    if (row >= N) return;
    const int l2 = (threadIdx.x & 63) << 1;

    float2 bv1 = *(const float2*)(b1 + l2);
    float2 bv2 = *(const float2*)(b2 + l2);
    float ax = bv1.x + bv2.x;
    float ay = bv1.y + bv2.y;

    #pragma unroll
    for (int g = 0; g < 2; ++g) {
        const int* __restrict__ rp = g ? rp_b : rp_a;
        const int2* __restrict__ ev = g ? ev_b : ev_a;
        const unsigned short* __restrict__ S = g ? Sb : Sa;

        int e = rp[row];
        const int e1 = rp[row + 1];
        for (; e + 8 <= e1; e += 8) {
            int2 p0 = ev[e],     p1 = ev[e + 1], p2 = ev[e + 2], p3 = ev[e + 3];
            int2 p4 = ev[e + 4], p5 = ev[e + 5], p6 = ev[e + 6], p7 = ev[e + 7];
            unsigned u0 = *(const unsigned*)(S + ((size_t)p0.x << 7) + l2);
            unsigned u1 = *(const unsigned*)(S + ((size_t)p1.x << 7) + l2);
            unsigned u2 = *(const unsigned*)(S + ((size_t)p2.x << 7) + l2);
            unsigned u3 = *(const unsigned*)(S + ((size_t)p3.x << 7) + l2);
            unsigned u4 = *(const unsigned*)(S + ((size_t)p4.x << 7) + l2);
            unsigned u5 = *(const unsigned*)(S + ((size_t)p5.x << 7) + l2);
            unsigned u6 = *(const unsigned*)(S + ((size_t)p6.x << 7) + l2);
            unsigned u7 = *(const unsigned*)(S + ((size_t)p7.x << 7) + l2);
            float v0 = __int_as_float(p0.y), v1 = __int_as_float(p1.y);
            float v2 = __int_as_float(p2.y), v3 = __int_as_float(p3.y);
            float v4 = __int_as_float(p4.y), v5 = __int_as_float(p5.y);
            float v6 = __int_as_float(p6.y), v7 = __int_as_float(p7.y);
            ax = fmaf(v0, asf(u0 << 16), ax); ay = fmaf(v0, asf(u0 & 0xffff0000u), ay);
            ax = fmaf(v1, asf(u1 << 16), ax); ay = fmaf(v1, asf(u1 & 0xffff0000u), ay);
            ax = fmaf(v2, asf(u2 << 16), ax); ay = fmaf(v2, asf(u2 & 0xffff0000u), ay);
            ax = fmaf(v3, asf(u3 << 16), ax); ay = fmaf(v3, asf(u3 & 0xffff0000u), ay);
            ax = fmaf(v4, asf(u4 << 16), ax); ay = fmaf(v4, asf(u4 & 0xffff0000u), ay);
            ax = fmaf(v5, asf(u5 << 16), ax); ay = fmaf(v5, asf(u5 & 0xffff0000u), ay);
            ax = fmaf(v6, asf(u6 << 16), ax); ay = fmaf(v6, asf(u6 & 0xffff0000u), ay);
            ax = fmaf(v7, asf(u7 << 16), ax); ay = fmaf(v7, asf(u7 & 0xffff0000u), ay);
        }
        for (; e + 4 <= e1; e += 4) {
            int2 p0 = ev[e], p1 = ev[e + 1], p2 = ev[e + 2], p3 = ev[e + 3];
            unsigned u0 = *(const unsigned*)(S + ((size_t)p0.x << 7) + l2);
            unsigned u1 = *(const unsigned*)(S + ((size_t)p1.x << 7) + l2);
            unsigned u2 = *(const unsigned*)(S + ((size_t)p2.x << 7) + l2);
            unsigned u3 = *(const unsigned*)(S + ((size_t)p3.x << 7) + l2);
            float v0 = __int_as_float(p0.y), v1 = __int_as_float(p1.y);
            float v2 = __int_as_float(p2.y), v3 = __int_as_float(p3.y);
            ax = fmaf(v0, asf(u0 << 16), ax); ay = fmaf(v0, asf(u0 & 0xffff0000u), ay);
            ax = fmaf(v1, asf(u1 << 16), ax); ay = fmaf(v1, asf(u1 & 0xffff0000u), ay);
            ax = fmaf(v2, asf(u2 << 16), ax); ay = fmaf(v2, asf(u2 & 0xffff0000u), ay);
            ax = fmaf(v3, asf(u3 << 16), ax); ay = fmaf(v3, asf(u3 & 0xffff0000u), ay);
        }
        for (; e < e1; ++e) {
            int2 p = ev[e];
            unsigned u = *(const unsigned*)(S + ((size_t)p.x << 7) + l2);
            float v = __int_as_float(p.y);
            ax = fmaf(v, asf(u << 16), ax);
            ay = fmaf(v, asf(u & 0xffff0000u), ay);
        }
    }
    if (do_relu) { ax = fmaxf(ax, 0.f); ay = fmaxf(ay, 0.f); }
    if (OBF) {
        unsigned pk = (unsigned)f2bf(ax) | ((unsigned)f2bf(ay) << 16);
        ((unsigned*)outv)[((size_t)row << 6) + (l2 >> 1)] = pk;
    } else {
        float2 o; o.x = ax; o.y = ay;
        *(float2*)((float*)outv + ((size_t)row << 7) + l2) = o;
    }
}

// ---------------------------------------------------------------------------
// Decoder stage 1: out[b] = concat(h[idx0[b]], h[idx1[b]]) @ W + bias -> [B,128]
// ---------------------------------------------------------------------------
__global__ __launch_bounds__(128) void dec1_kernel(
    const float* __restrict__ h,
    const int* __restrict__ idx0, const int* __restrict__ idx1,
    const float* __restrict__ W, const float* __restrict__ bias,
    float* __restrict__ out, int B)
{
    __shared__ __align__(16) float fs[16 * 256];
    const int t = threadIdx.x;
    const int b0 = blockIdx.x * 16;
    #pragma unroll
    for (int r = 0; r < 16; ++r) {
        const int b = b0 + r;
        fs[r * 256 + t]       = h[(long)idx0[b] * 128 + t];
        fs[r * 256 + 128 + t] = h[(long)idx1[b] * 128 + t];
    }
    __syncthreads();

    const float4* fs4 = (const float4*)fs;
    float acc[16];
    #pragma unroll
    for (int r = 0; r < 16; ++r) acc[r] = 0.f;
    for (int kc = 0; kc < 64; ++kc) {
        const float w0 = W[(kc * 4 + 0) * 128 + t];
        const float w1 = W[(kc * 4 + 1) * 128 + t];
        const float w2 = W[(kc * 4 + 2) * 128 + t];
        const float w3 = W[(kc * 4 + 3) * 128 + t];
        #pragma unroll
        for (int r = 0; r < 16; ++r) {
            const float4 xv = fs4[r * 64 + kc];
            acc[r] = fmaf(xv.x, w0, acc[r]);
            acc[r] = fmaf(xv.y, w1, acc[r]);
            acc[r] = fmaf(xv.z, w2, acc[r]);
            acc[r] = fmaf(xv.w, w3, acc[r]);
        }
    }
    #pragma unroll
    for (int r = 0; r < 16; ++r)
        out[(long)(b0 + r) * 128 + t] = acc[r] + bias[t];
}

// ---------------------------------------------------------------------------
// Decoder stage 2: out[b] = o1[b] @ W + bias -> [B, 86]
// ---------------------------------------------------------------------------
__global__ __launch_bounds__(128) void dec2_kernel(
    const float* __restrict__ o1,
    const float* __restrict__ W, const float* __restrict__ bias,
    float* __restrict__ out, int B)
{
    __shared__ __align__(16) float os[16 * 128];
    const int t = threadIdx.x;
    const int b0 = blockIdx.x * 16;
    #pragma unroll
    for (int r = 0; r < 16; ++r)
        os[r * 128 + t] = o1[(long)(b0 + r) * 128 + t];
    __syncthreads();

    const float4* os4 = (const float4*)os;
    float acc[16];
    #pragma unroll
    for (int r = 0; r < 16; ++r) acc[r] = 0.f;
    const bool act = (t < RELL);
    for (int kc = 0; kc < 32; ++kc) {
        const float w0 = act ? W[(kc * 4 + 0) * RELL + t] : 0.f;
        const float w1 = act ? W[(kc * 4 + 1) * RELL + t] : 0.f;
        const float w2 = act ? W[(kc * 4 + 2) * RELL + t] : 0.f;
        const float w3 = act ? W[(kc * 4 + 3) * RELL + t] : 0.f;
        #pragma unroll
        for (int r = 0; r < 16; ++r) {
            const float4 xv = os4[r * 32 + kc];
            acc[r] = fmaf(xv.x, w0, acc[r]);
            acc[r] = fmaf(xv.y, w1, acc[r]);
            acc[r] = fmaf(xv.z, w2, acc[r]);
            acc[r] = fmaf(xv.w, w3, acc[r]);
        }
    }
    if (act) {
        #pragma unroll
        for (int r = 0; r < 16; ++r)
            out[(long)(b0 + r) * RELL + t] = acc[r] + bias[t];
    }
}

extern "C" void kernel_launch(void* const* d_in, const int* in_sizes, int n_in,
                              void* d_out, int out_size, void* d_ws, size_t ws_size,
                              hipStream_t stream) {
    const float* x      = (const float*)d_in[0];
    const int*   o_rows = (const int*)  d_in[1];
    const int*   o_cols = (const int*)  d_in[2];
    const float* o_vals = (const float*)d_in[3];
    const int*   s_rows = (const int*)  d_in[4];
    const int*   s_cols = (const int*)  d_in[5];
    const float* s_vals = (const float*)d_in[6];
    const int*   idx    = (const int*)  d_in[7];
    const float* W_ogc1  = (const float*)d_in[8];   const float* b_ogc1  = (const float*)d_in[9];
    const float* W_sgc1o = (const float*)d_in[10];  const float* b_sgc1o = (const float*)d_in[11];
    const float* W_sgc1  = (const float*)d_in[12];  const float* b_sgc1  = (const float*)d_in[13];
    const float* W_ogc1s = (const float*)d_in[14];  const float* b_ogc1s = (const float*)d_in[15];
    const float* W_ogc2  = (const float*)d_in[16];  const float* b_ogc2  = (const float*)d_in[17];
    const float* W_sgc2o = (const float*)d_in[18];  const float* b_sgc2o = (const float*)d_in[19];
    const float* W_dec1  = (const float*)d_in[20];  const float* b_dec1  = (const float*)d_in[21];
    const float* W_dec2  = (const float*)d_in[22];  const float* b_dec2  = (const float*)d_in[23];

    const int N = in_sizes[0] / NFEAT;   // 100000
    const int E = in_sizes[1];           // 1600000
    const int B = in_sizes[7] / 2;       // 16384
    const int* idx0 = idx;
    const int* idx1 = idx + B;

    // ---- workspace layout (float units) ----
    float* p = (float*)d_ws;
    const size_t N64 = (size_t)N * 64;    // one bf16 [N,128] table in float units
    float* h    = p;  p += (size_t)N * 128;          // fp32 [N,128]
    unsigned short* oxb  = (unsigned short*)p; p += N64;   // o_x bf16
    unsigned short* sxb  = (unsigned short*)p; p += N64;   // s_x bf16
    unsigned short* tabA = (unsigned short*)p; p += N64;
    unsigned short* tabB = (unsigned short*)p; p += N64;
    unsigned short* tabC = (unsigned short*)p; p += N64;
    unsigned short* tabD = (unsigned short*)p; p += N64;
    float* o1buf = p; p += (size_t)B * 128;
    unsigned short* wt1 = (unsigned short*)p; p += 16384;   // [128,256] bf16
    unsigned short* wt2 = (unsigned short*)p; p += 16384;
    unsigned short* wt3 = (unsigned short*)p; p += 16384;
    unsigned short* wt4 = (unsigned short*)p; p += 8192;    // [128,128] bf16
    unsigned short* wt5 = (unsigned short*)p; p += 8192;
    unsigned short* wt6 = (unsigned short*)p; p += 8192;
    int* rp_o = (int*)p; p += (size_t)N + 2;
    int* rp_s = (int*)p; p += (size_t)N + 2;
    int* cnt  = (int*)p; p += 2 * (size_t)N;         // [2][N] histogram counts
    int2* ev_o = (int2*)p; p += 2 * (size_t)E;
    int2* ev_s = (int2*)p; p += 2 * (size_t)E;
    int* part  = (int*)p; p += 2048;                 // [2][1024]
    int* bcur  = (int*)p; p += 512;                  // [2][256] bucket cursors
    // temp binning buffers alias tabA/tabB region (dead until first GEMM)
    int2* temp_o = (int2*)tabA;                      // E int2 = 12.8 MB
    int2* temp_s = temp_o + E;                       // spills into tabB region

    const int gM64 = (N + 63) / 64;       // 1563
    const int gE = (E + 255) / 256;       // 6250
    const int gR = (N + 3) / 4;           // 25000
    const int gB = B / 16;                // 1024
    const int gScan = (N + SCAN_CHUNK - 1) / SCAN_CHUNK;              // 196
    const int gT = (E + SCAT_TILE - 1) / SCAT_TILE;                   // 391
    const int gBuck = (N + (1 << BSHIFT) - 1) >> BSHIFT;              // 196

    // ---- CSR build (both graphs via y-grid)
    hipMemsetAsync(cnt, 0, 2 * (size_t)N * sizeof(int), stream);
    hist2<<<dim3(gE, 2), 256, 0, stream>>>(o_rows, s_rows, cnt, N, E);
    scan_partial2<<<dim3(gScan, 2), 256, 0, stream>>>(cnt, part, N);
    scan_blocks2<<<dim3(1, 2), 1024, 0, stream>>>(part, gScan);
    scan_final2<<<dim3(gScan, 2), 256, 0, stream>>>(cnt, part, rp_o, rp_s, N, E);
    binit<<<1, 512, 0, stream>>>(rp_o, rp_s, bcur, N);
    binscat1<<<dim3(gT, 2), 256, 0, stream>>>(o_rows, o_cols, o_vals,
                                              s_rows, s_cols, s_vals,
                                              bcur, temp_o, temp_s, E);
    binscat2<<<dim3(gBuck, 2), 256, 0, stream>>>(rp_o, rp_s, temp_o, temp_s,
                                                 ev_o, ev_s, N);

    // ---- weight prep
    wt_prep3<NFEAT><<<dim3(128, 3), 256, 0, stream>>>(W_ogc1, W_sgc1o, W_sgc1,
                                                      wt1, wt2, wt3);
    wt_prep3<NHID><<<dim3(64, 3), 256, 0, stream>>>(W_ogc1s, W_ogc2, W_sgc2o,
                                                    wt4, wt5, wt6);

    // ---- Layer 1 GEMMs (x read once): tabA=x@W_ogc1, tabB=x@W_sgc1o, tabC=x@W_sgc1
    gemm_fused<NFEAT, 3, false><<<gM64, 256, 0, stream>>>(
        x, wt1, tabA, wt2, tabB, wt3, tabC, N);
    // o_x = relu(spmm_o(tabA) + spmm_s(tabB) + b)  -> bf16
    spmm2_csr<true><<<gR, 256, 0, stream>>>(rp_o, ev_o, tabA, rp_s, ev_s, tabB,
                                            b_ogc1, b_sgc1o, oxb, N, 1);

    // ---- Layer 2: tabD = o_x@W_ogc1s;  s_x = relu(spmm_o(tabD) + spmm_s(tabC) + b) -> bf16
    gemm_fused<NHID, 1, true><<<gM64, 256, 0, stream>>>(
        oxb, wt4, tabD, nullptr, nullptr, nullptr, nullptr, N);
    spmm2_csr<true><<<gR, 256, 0, stream>>>(rp_o, ev_o, tabD, rp_s, ev_s, tabC,
                                            b_ogc1s, b_sgc1, sxb, N, 1);

    // ---- Layer 3: tabA = o_x@W_ogc2; tabB = s_x@W_sgc2o; h = spmm sum (fp32)
    gemm_fused<NHID, 1, true><<<gM64, 256, 0, stream>>>(
        oxb, wt5, tabA, nullptr, nullptr, nullptr, nullptr, N);
    gemm_fused<NHID, 1, true><<<gM64, 256, 0, stream>>>(
        sxb, wt6, tabB, nullptr, nullptr, nullptr, nullptr, N);
    spmm2_csr<false><<<gR, 256, 0, stream>>>(rp_o, ev_o, tabA, rp_s, ev_s, tabB,
                                             b_ogc2, b_sgc2o, h, N, 0);

    // ---- Decoder
    dec1_kernel<<<gB, 128, 0, stream>>>(h, idx0, idx1, W_dec1, b_dec1, o1buf, B);
    dec2_kernel<<<gB, 128, 0, stream>>>(o1buf, W_dec2, b_dec2, (float*)d_out, B);
}

// Round 8
// 686.712 us; speedup vs baseline: 7.4050x; 1.1645x over previous
//
#include <hip/hip_runtime.h>
#include <hip/hip_bf16.h>

#define NFEAT 256
#define NHID 128
#define RELL 86
#define BSHIFT 9                 // bucket = row >> 9 (512 rows)
#define SCAT_TILE 4096           // edges per binscat block (16/thread)

typedef __attribute__((ext_vector_type(8))) short short8v;
typedef __attribute__((ext_vector_type(4))) float float4v;

static __device__ __forceinline__ unsigned short f2bf(float f) {
    union { float f; unsigned int u; } v; v.f = f;
    unsigned int r = v.u + 0x7FFF + ((v.u >> 16) & 1);   // RNE
    return (unsigned short)(r >> 16);
}
static __device__ __forceinline__ float asf(unsigned int u) {
    union { unsigned int u; float f; } v; v.u = u; return v.f;
}

// ---------------------------------------------------------------------------
// Weight prep: 3 matrices per launch via blockIdx.y. Wt[col][k] = bf16(W[k][col])
// ---------------------------------------------------------------------------
template <int K>
__global__ __launch_bounds__(256) void wt_prep3(
    const float* __restrict__ W0, const float* __restrict__ W1,
    const float* __restrict__ W2,
    unsigned short* __restrict__ T0, unsigned short* __restrict__ T1,
    unsigned short* __restrict__ T2)
{
    const float* W = (blockIdx.y == 0) ? W0 : ((blockIdx.y == 1) ? W1 : W2);
    unsigned short* T = (blockIdx.y == 0) ? T0 : ((blockIdx.y == 1) ? T1 : T2);
    int i = blockIdx.x * 256 + threadIdx.x;
    if (i < K * 128) {
        int col = i & 127, k = i >> 7;
        T[col * K + k] = f2bf(W[i]);
    }
}

// ---------------------------------------------------------------------------
// CSR build: bucket counts -> bucket scan -> binned scatter -> per-bucket
// local counting-sort (derives rp locally; no per-row global histogram).
// ---------------------------------------------------------------------------

// Per-block LDS bucket histogram -> few global atomics on 256-entry counters.
__global__ __launch_bounds__(256) void bucket_count(
    const int* __restrict__ ro, const int* __restrict__ rs,
    int* __restrict__ bcnt, int E)
{
    const int g = blockIdx.y;
    const int* rows = g ? rs : ro;
    int* bc = bcnt + g * 256;
    __shared__ int hist[256];
    const int t = threadIdx.x;
    hist[t] = 0;
    __syncthreads();
    const int e0 = blockIdx.x * SCAT_TILE;
    #pragma unroll
    for (int i = 0; i < 16; ++i) {
        int e = e0 + i * 256 + t;
        if (e < E) atomicAdd(&hist[rows[e] >> BSHIFT], 1);
    }
    __syncthreads();
    if (hist[t] > 0) atomicAdd(&bc[t], hist[t]);
}

// One block: exclusive scan of 256 bucket counts per graph -> bases + cursors.
__global__ __launch_bounds__(256) void bucket_scan(
    const int* __restrict__ bcnt, int* __restrict__ bbase,
    int* __restrict__ bcur, int E)
{
    __shared__ int sh[256];
    const int t = threadIdx.x;
    for (int g = 0; g < 2; ++g) {
        const int v = bcnt[g * 256 + t];
        sh[t] = v;
        __syncthreads();
        for (int off = 1; off < 256; off <<= 1) {
            int u = (t >= off) ? sh[t - off] : 0;
            __syncthreads();
            sh[t] += u;
            __syncthreads();
        }
        const int ex = sh[t] - v;
        bbase[g * 257 + t] = ex;
        bcur[g * 256 + t] = ex;
        if (t == 255) bbase[g * 257 + 256] = E;
        __syncthreads();
    }
}

// Phase 1: bin edges by row>>9 into bucket-contiguous temp regions,
// packed (row&511 | col<<9, val_bits).
__global__ __launch_bounds__(256) void binscat1(
    const int* __restrict__ ro, const int* __restrict__ co,
    const float* __restrict__ vo,
    const int* __restrict__ rs, const int* __restrict__ cs,
    const float* __restrict__ vs,
    int* __restrict__ bcur, int2* __restrict__ temp_o,
    int2* __restrict__ temp_s, int E)
{
    const int g = blockIdx.y;
    const int* rows = g ? rs : ro;
    const int* cols = g ? cs : co;
    const float* vals = g ? vs : vo;
    int* bc = bcur + g * 256;
    int2* temp = g ? temp_s : temp_o;

    __shared__ int hist[256];
    __shared__ int base[256];
    const int t = threadIdx.x;
    hist[t] = 0;
    __syncthreads();

    const int e0 = blockIdx.x * SCAT_TILE;
    int myrow[16];
    #pragma unroll
    for (int i = 0; i < 16; ++i) {
        int e = e0 + i * 256 + t;
        int r = (e < E) ? rows[e] : -1;
        myrow[i] = r;
        if (r >= 0) atomicAdd(&hist[r >> BSHIFT], 1);
    }
    __syncthreads();
    const int h = hist[t];
    if (h > 0) base[t] = atomicAdd(&bc[t], h);
    __syncthreads();
    hist[t] = (h > 0) ? base[t] : 0;     // reuse hist as within-block cursor
    __syncthreads();
    #pragma unroll
    for (int i = 0; i < 16; ++i) {
        const int r = myrow[i];
        if (r >= 0) {
            int e = e0 + i * 256 + t;
            int off = atomicAdd(&hist[r >> BSHIFT], 1);
            temp[off] = make_int2((r & 511) | (cols[e] << BSHIFT),
                                  __float_as_int(vals[e]));
        }
    }
}

// Phase 2: per-bucket local counting sort. Counts rows in LDS, scans, writes
// rp for this bucket's row range, then scatters edges to final CSR order.
__global__ __launch_bounds__(512) void binscat2(
    const int* __restrict__ bbase,
    const int2* __restrict__ temp_o, const int2* __restrict__ temp_s,
    int* __restrict__ rp_o, int* __restrict__ rp_s,
    int2* __restrict__ ev_o, int2* __restrict__ ev_s, int N)
{
    const int g = blockIdx.y;
    const int2* temp = g ? temp_s : temp_o;
    int2* ev = g ? ev_s : ev_o;
    int* rp = g ? rp_s : rp_o;
    const int* bb = bbase + g * 257;

    __shared__ int lcnt[512];
    __shared__ int lpre[512];
    const int b = blockIdx.x;
    const int r0 = b << BSHIFT;
    const int t = threadIdx.x;
    const int e0 = bb[b], e1 = bb[b + 1];

    lcnt[t] = 0;
    __syncthreads();
    for (int e = e0 + t; e < e1; e += 512)
        atomicAdd(&lcnt[temp[e].x & 511], 1);
    __syncthreads();
    const int v = lcnt[t];
    lpre[t] = v;
    __syncthreads();
    for (int off = 1; off < 512; off <<= 1) {
        int u = (t >= off) ? lpre[t - off] : 0;
        __syncthreads();
        lpre[t] += u;
        __syncthreads();
    }
    const int base = e0 + lpre[t] - v;   // exclusive -> row start offset
    const int r = r0 + t;
    if (r <= N) rp[r] = base;            // last bucket's r==N lands rp[N]=E
    __syncthreads();
    lcnt[t] = base;                      // row cursors
    __syncthreads();
    for (int e = e0 + t; e < e1; e += 512) {
        int2 pk = temp[e];
        int q = atomicAdd(&lcnt[pk.x & 511], 1);
        ev[q] = make_int2(pk.x >> BSHIFT, pk.y);
    }
}

// ---------------------------------------------------------------------------
// Fused MFMA GEMM: S_m = X @ W_m for NM matrices, X staged ONCE (full K) in LDS.
// ---------------------------------------------------------------------------
template <int K, int NM, bool XBF>
__global__ __launch_bounds__(256) void gemm_fused(
    const void* __restrict__ Xv,
    const unsigned short* __restrict__ Wt0, unsigned short* __restrict__ S0,
    const unsigned short* __restrict__ Wt1, unsigned short* __restrict__ S1,
    const unsigned short* __restrict__ Wt2, unsigned short* __restrict__ S2,
    int Nrows)
{
    constexpr int AST = K + 8;
    __shared__ unsigned short As[64 * AST];
    __shared__ unsigned short Bs[128 * 72];

    const int t = threadIdx.x;
    const int l = t & 63;
    const int w = t >> 6;
    const int row_in = l & 15;
    const int kgrp = l >> 4;        // 0..3
    const int row0 = blockIdx.x * 64;

    {
        constexpr int QPR = K / 4;
        #pragma unroll
        for (int it = 0; it < 64 * QPR / 256; ++it) {
            int i = t + it * 256;
            int r = i / QPR, c4 = i % QPR;
            int gr = row0 + r;
            if (XBF) {
                ushort4 v = make_ushort4(0, 0, 0, 0);
                if (gr < Nrows)
                    v = *(const ushort4*)((const unsigned short*)Xv + (size_t)gr * K + c4 * 4);
                *(ushort4*)&As[r * AST + c4 * 4] = v;
            } else {
                float4 v = make_float4(0.f, 0.f, 0.f, 0.f);
                if (gr < Nrows)
                    v = *(const float4*)((const float*)Xv + (size_t)gr * K + c4 * 4);
                ushort4 b4;
                b4.x = f2bf(v.x); b4.y = f2bf(v.y); b4.z = f2bf(v.z); b4.w = f2bf(v.w);
                *(ushort4*)&As[r * AST + c4 * 4] = b4;
            }
        }
    }

    #pragma unroll
    for (int m = 0; m < NM; ++m) {
        const unsigned short* Wt = (m == 0) ? Wt0 : ((m == 1) ? Wt1 : Wt2);
        unsigned short* S = (m == 0) ? S0 : ((m == 1) ? S1 : S2);
        float4v acc[8];
        #pragma unroll
        for (int n = 0; n < 8; ++n) acc[n] = (float4v)(0.f);

        for (int kt = 0; kt < K / 64; ++kt) {
            __syncthreads();
            #pragma unroll
            for (int it = 0; it < 8; ++it) {
                int i = t + it * 256;
                int r = i >> 4, c4 = i & 15;
                *(ushort4*)&Bs[r * 72 + c4 * 4] =
                    *(const ushort4*)(Wt + (size_t)r * K + kt * 64 + c4 * 4);
            }
            __syncthreads();
            #pragma unroll
            for (int kc = 0; kc < 2; ++kc) {
                short8v a, b[8];
                const unsigned short* pa =
                    &As[(w * 16 + row_in) * AST + kt * 64 + kc * 32 + kgrp * 8];
                ((uint2*)&a)[0] = *(const uint2*)pa;
                ((uint2*)&a)[1] = *(const uint2*)(pa + 4);
                #pragma unroll
                for (int n = 0; n < 8; ++n) {
                    const unsigned short* pb =
                        &Bs[(n * 16 + row_in) * 72 + kc * 32 + kgrp * 8];
                    ((uint2*)&b[n])[0] = *(const uint2*)pb;
                    ((uint2*)&b[n])[1] = *(const uint2*)(pb + 4);
                }
                #pragma unroll
                for (int n = 0; n < 8; ++n)
                    acc[n] = __builtin_amdgcn_mfma_f32_16x16x32_bf16(
                        a, b[n], acc[n], 0, 0, 0);
            }
        }
        #pragma unroll
        for (int n = 0; n < 8; ++n)
            #pragma unroll
            for (int r = 0; r < 4; ++r) {
                int gr = row0 + w * 16 + kgrp * 4 + r;
                int gc = n * 16 + row_in;
                if (gr < Nrows) S[(size_t)gr * 128 + gc] = f2bf(acc[n][r]);
            }
    }
}

// ---------------------------------------------------------------------------
// Fused dual-graph CSR SpMM (8-way MLP unroll), bf16 tables, bf16/fp32 out.
// ---------------------------------------------------------------------------
template <bool OBF>
__global__ __launch_bounds__(256) void spmm2_csr(
    const int* __restrict__ rp_a, const int2* __restrict__ ev_a,
    const unsigned short* __restrict__ Sa,
    const int* __restrict__ rp_b, const int2* __restrict__ ev_b,
    const unsigned short* __restrict__ Sb,
    const float* __restrict__ b1, const float* __restrict__ b2,
    void* __restrict__ outv, int N, int do_relu)
{
    const int row = blockIdx.x * 4 + (threadIdx.x >> 6);
    if (row >= N) return;
    const int l2 = (threadIdx.x & 63) << 1;

    float2 bv1 = *(const float2*)(b1 + l2);
    float2 bv2 = *(const float2*)(b2 + l2);
    float ax = bv1.x + bv2.x;
    float ay = bv1.y + bv2.y;

    #pragma unroll
    for (int g = 0; g < 2; ++g) {
        const int* __restrict__ rp = g ? rp_b : rp_a;
        const int2* __restrict__ ev = g ? ev_b : ev_a;
        const unsigned short* __restrict__ S = g ? Sb : Sa;

        int e = rp[row];
        const int e1 = rp[row + 1];
        for (; e + 8 <= e1; e += 8) {
            int2 p0 = ev[e],     p1 = ev[e + 1], p2 = ev[e + 2], p3 = ev[e + 3];
            int2 p4 = ev[e + 4], p5 = ev[e + 5], p6 = ev[e + 6], p7 = ev[e + 7];
            unsigned u0 = *(const unsigned*)(S + ((size_t)p0.x << 7) + l2);
            unsigned u1 = *(const unsigned*)(S + ((size_t)p1.x << 7) + l2);
            unsigned u2 = *(const unsigned*)(S + ((size_t)p2.x << 7) + l2);
            unsigned u3 = *(const unsigned*)(S + ((size_t)p3.x << 7) + l2);
            unsigned u4 = *(const unsigned*)(S + ((size_t)p4.x << 7) + l2);
            unsigned u5 = *(const unsigned*)(S + ((size_t)p5.x << 7) + l2);
            unsigned u6 = *(const unsigned*)(S + ((size_t)p6.x << 7) + l2);
            unsigned u7 = *(const unsigned*)(S + ((size_t)p7.x << 7) + l2);
            float v0 = __int_as_float(p0.y), v1 = __int_as_float(p1.y);
            float v2 = __int_as_float(p2.y), v3 = __int_as_float(p3.y);
            float v4 = __int_as_float(p4.y), v5 = __int_as_float(p5.y);
            float v6 = __int_as_float(p6.y), v7 = __int_as_float(p7.y);
            ax = fmaf(v0, asf(u0 << 16), ax); ay = fmaf(v0, asf(u0 & 0xffff0000u), ay);
            ax = fmaf(v1, asf(u1 << 16), ax); ay = fmaf(v1, asf(u1 & 0xffff0000u), ay);
            ax = fmaf(v2, asf(u2 << 16), ax); ay = fmaf(v2, asf(u2 & 0xffff0000u), ay);
            ax = fmaf(v3, asf(u3 << 16), ax); ay = fmaf(v3, asf(u3 & 0xffff0000u), ay);
            ax = fmaf(v4, asf(u4 << 16), ax); ay = fmaf(v4, asf(u4 & 0xffff0000u), ay);
            ax = fmaf(v5, asf(u5 << 16), ax); ay = fmaf(v5, asf(u5 & 0xffff0000u), ay);
            ax = fmaf(v6, asf(u6 << 16), ax); ay = fmaf(v6, asf(u6 & 0xffff0000u), ay);
            ax = fmaf(v7, asf(u7 << 16), ax); ay = fmaf(v7, asf(u7 & 0xffff0000u), ay);
        }
        for (; e + 4 <= e1; e += 4) {
            int2 p0 = ev[e], p1 = ev[e + 1], p2 = ev[e + 2], p3 = ev[e + 3];
            unsigned u0 = *(const unsigned*)(S + ((size_t)p0.x << 7) + l2);
            unsigned u1 = *(const unsigned*)(S + ((size_t)p1.x << 7) + l2);
            unsigned u2 = *(const unsigned*)(S + ((size_t)p2.x << 7) + l2);
            unsigned u3 = *(const unsigned*)(S + ((size_t)p3.x << 7) + l2);
            float v0 = __int_as_float(p0.y), v1 = __int_as_float(p1.y);
            float v2 = __int_as_float(p2.y), v3 = __int_as_float(p3.y);
            ax = fmaf(v0, asf(u0 << 16), ax); ay = fmaf(v0, asf(u0 & 0xffff0000u), ay);
            ax = fmaf(v1, asf(u1 << 16), ax); ay = fmaf(v1, asf(u1 & 0xffff0000u), ay);
            ax = fmaf(v2, asf(u2 << 16), ax); ay = fmaf(v2, asf(u2 & 0xffff0000u), ay);
            ax = fmaf(v3, asf(u3 << 16), ax); ay = fmaf(v3, asf(u3 & 0xffff0000u), ay);
        }
        for (; e < e1; ++e) {
            int2 p = ev[e];
            unsigned u = *(const unsigned*)(S + ((size_t)p.x << 7) + l2);
            float v = __int_as_float(p.y);
            ax = fmaf(v, asf(u << 16), ax);
            ay = fmaf(v, asf(u & 0xffff0000u), ay);
        }
    }
    if (do_relu) { ax = fmaxf(ax, 0.f); ay = fmaxf(ay, 0.f); }
    if (OBF) {
        unsigned pk = (unsigned)f2bf(ax) | ((unsigned)f2bf(ay) << 16);
        ((unsigned*)outv)[((size_t)row << 6) + (l2 >> 1)] = pk;
    } else {
        float2 o; o.x = ax; o.y = ay;
        *(float2*)((float*)outv + ((size_t)row << 7) + l2) = o;
    }
}

// ---------------------------------------------------------------------------
// Decoder stage 1: out[b] = concat(h[idx0[b]], h[idx1[b]]) @ W + bias -> [B,128]
// ---------------------------------------------------------------------------
__global__ __launch_bounds__(128) void dec1_kernel(
    const float* __restrict__ h,
    const int* __restrict__ idx0, const int* __restrict__ idx1,
    const float* __restrict__ W, const float* __restrict__ bias,
    float* __restrict__ out, int B)
{
    __shared__ __align__(16) float fs[16 * 256];
    const int t = threadIdx.x;
    const int b0 = blockIdx.x * 16;
    #pragma unroll
    for (int r = 0; r < 16; ++r) {
        const int b = b0 + r;
        fs[r * 256 + t]       = h[(long)idx0[b] * 128 + t];
        fs[r * 256 + 128 + t] = h[(long)idx1[b] * 128 + t];
    }
    __syncthreads();

    const float4* fs4 = (const float4*)fs;
    float acc[16];
    #pragma unroll
    for (int r = 0; r < 16; ++r) acc[r] = 0.f;
    for (int kc = 0; kc < 64; ++kc) {
        const float w0 = W[(kc * 4 + 0) * 128 + t];
        const float w1 = W[(kc * 4 + 1) * 128 + t];
        const float w2 = W[(kc * 4 + 2) * 128 + t];
        const float w3 = W[(kc * 4 + 3) * 128 + t];
        #pragma unroll
        for (int r = 0; r < 16; ++r) {
            const float4 xv = fs4[r * 64 + kc];
            acc[r] = fmaf(xv.x, w0, acc[r]);
            acc[r] = fmaf(xv.y, w1, acc[r]);
            acc[r] = fmaf(xv.z, w2, acc[r]);
            acc[r] = fmaf(xv.w, w3, acc[r]);
        }
    }
    #pragma unroll
    for (int r = 0; r < 16; ++r)
        out[(long)(b0 + r) * 128 + t] = acc[r] + bias[t];
}

// ---------------------------------------------------------------------------
// Decoder stage 2: out[b] = o1[b] @ W + bias -> [B, 86]
// ---------------------------------------------------------------------------
__global__ __launch_bounds__(128) void dec2_kernel(
    const float* __restrict__ o1,
    const float* __restrict__ W, const float* __restrict__ bias,
    float* __restrict__ out, int B)
{
    __shared__ __align__(16) float os[16 * 128];
    const int t = threadIdx.x;
    const int b0 = blockIdx.x * 16;
    #pragma unroll
    for (int r = 0; r < 16; ++r)
        os[r * 128 + t] = o1[(long)(b0 + r) * 128 + t];
    __syncthreads();

    const float4* os4 = (const float4*)os;
    float acc[16];
    #pragma unroll
    for (int r = 0; r < 16; ++r) acc[r] = 0.f;
    const bool act = (t < RELL);
    for (int kc = 0; kc < 32; ++kc) {
        const float w0 = act ? W[(kc * 4 + 0) * RELL + t] : 0.f;
        const float w1 = act ? W[(kc * 4 + 1) * RELL + t] : 0.f;
        const float w2 = act ? W[(kc * 4 + 2) * RELL + t] : 0.f;
        const float w3 = act ? W[(kc * 4 + 3) * RELL + t] : 0.f;
        #pragma unroll
        for (int r = 0; r < 16; ++r) {
            const float4 xv = os4[r * 32 + kc];
            acc[r] = fmaf(xv.x, w0, acc[r]);
            acc[r] = fmaf(xv.y, w1, acc[r]);
            acc[r] = fmaf(xv.z, w2, acc[r]);
            acc[r] = fmaf(xv.w, w3, acc[r]);
        }
    }
    if (act) {
        #pragma unroll
        for (int r = 0; r < 16; ++r)
            out[(long)(b0 + r) * RELL + t] = acc[r] + bias[t];
    }
}

extern "C" void kernel_launch(void* const* d_in, const int* in_sizes, int n_in,
                              void* d_out, int out_size, void* d_ws, size_t ws_size,
                              hipStream_t stream) {
    const float* x      = (const float*)d_in[0];
    const int*   o_rows = (const int*)  d_in[1];
    const int*   o_cols = (const int*)  d_in[2];
    const float* o_vals = (const float*)d_in[3];
    const int*   s_rows = (const int*)  d_in[4];
    const int*   s_cols = (const int*)  d_in[5];
    const float* s_vals = (const float*)d_in[6];
    const int*   idx    = (const int*)  d_in[7];
    const float* W_ogc1  = (const float*)d_in[8];   const float* b_ogc1  = (const float*)d_in[9];
    const float* W_sgc1o = (const float*)d_in[10];  const float* b_sgc1o = (const float*)d_in[11];
    const float* W_sgc1  = (const float*)d_in[12];  const float* b_sgc1  = (const float*)d_in[13];
    const float* W_ogc1s = (const float*)d_in[14];  const float* b_ogc1s = (const float*)d_in[15];
    const float* W_ogc2  = (const float*)d_in[16];  const float* b_ogc2  = (const float*)d_in[17];
    const float* W_sgc2o = (const float*)d_in[18];  const float* b_sgc2o = (const float*)d_in[19];
    const float* W_dec1  = (const float*)d_in[20];  const float* b_dec1  = (const float*)d_in[21];
    const float* W_dec2  = (const float*)d_in[22];  const float* b_dec2  = (const float*)d_in[23];

    const int N = in_sizes[0] / NFEAT;   // 100000
    const int E = in_sizes[1];           // 1600000
    const int B = in_sizes[7] / 2;       // 16384
    const int* idx0 = idx;
    const int* idx1 = idx + B;

    // ---- workspace layout (float units) ----
    float* p = (float*)d_ws;
    const size_t N64 = (size_t)N * 64;    // one bf16 [N,128] table in float units
    float* h    = p;  p += (size_t)N * 128;          // fp32 [N,128]
    unsigned short* oxb  = (unsigned short*)p; p += N64;   // o_x bf16
    unsigned short* sxb  = (unsigned short*)p; p += N64;   // s_x bf16
    unsigned short* tabA = (unsigned short*)p; p += N64;
    unsigned short* tabB = (unsigned short*)p; p += N64;
    unsigned short* tabC = (unsigned short*)p; p += N64;
    unsigned short* tabD = (unsigned short*)p; p += N64;
    float* o1buf = p; p += (size_t)B * 128;
    unsigned short* wt1 = (unsigned short*)p; p += 16384;   // [128,256] bf16
    unsigned short* wt2 = (unsigned short*)p; p += 16384;
    unsigned short* wt3 = (unsigned short*)p; p += 16384;
    unsigned short* wt4 = (unsigned short*)p; p += 8192;    // [128,128] bf16
    unsigned short* wt5 = (unsigned short*)p; p += 8192;
    unsigned short* wt6 = (unsigned short*)p; p += 8192;
    int* rp_o = (int*)p; p += (size_t)N + 2;
    int* rp_s = (int*)p; p += (size_t)N + 2;
    int2* ev_o = (int2*)p; p += 2 * (size_t)E;
    int2* ev_s = (int2*)p; p += 2 * (size_t)E;
    int* bcnt  = (int*)p; p += 512;                  // [2][256] bucket counts
    int* bbase = (int*)p; p += 516;                  // [2][257] bucket bases
    int* bcur  = (int*)p; p += 512;                  // [2][256] bucket cursors
    // temp binning buffers alias tabA/tabB region (dead until first GEMM)
    int2* temp_o = (int2*)tabA;                      // E int2 = 12.8 MB
    int2* temp_s = temp_o + E;                       // next 12.8 MB

    const int gM64 = (N + 63) / 64;       // 1563
    const int gR = (N + 3) / 4;           // 25000
    const int gB = B / 16;                // 1024
    const int gT = (E + SCAT_TILE - 1) / SCAT_TILE;                   // 391
    const int gBuck = (N + (1 << BSHIFT) - 1) >> BSHIFT;              // 196

    // ---- CSR build (both graphs via y-grid), no per-row global histogram
    hipMemsetAsync(bcnt, 0, 512 * sizeof(int), stream);
    bucket_count<<<dim3(gT, 2), 256, 0, stream>>>(o_rows, s_rows, bcnt, E);
    bucket_scan<<<1, 256, 0, stream>>>(bcnt, bbase, bcur, E);
    binscat1<<<dim3(gT, 2), 256, 0, stream>>>(o_rows, o_cols, o_vals,
                                              s_rows, s_cols, s_vals,
                                              bcur, temp_o, temp_s, E);
    binscat2<<<dim3(gBuck, 2), 512, 0, stream>>>(bbase, temp_o, temp_s,
                                                 rp_o, rp_s, ev_o, ev_s, N);

    // ---- weight prep
    wt_prep3<NFEAT><<<dim3(128, 3), 256, 0, stream>>>(W_ogc1, W_sgc1o, W_sgc1,
                                                      wt1, wt2, wt3);
    wt_prep3<NHID><<<dim3(64, 3), 256, 0, stream>>>(W_ogc1s, W_ogc2, W_sgc2o,
                                                    wt4, wt5, wt6);

    // ---- Layer 1 GEMMs (x read once): tabA=x@W_ogc1, tabB=x@W_sgc1o, tabC=x@W_sgc1
    gemm_fused<NFEAT, 3, false><<<gM64, 256, 0, stream>>>(
        x, wt1, tabA, wt2, tabB, wt3, tabC, N);
    // o_x = relu(spmm_o(tabA) + spmm_s(tabB) + b)  -> bf16
    spmm2_csr<true><<<gR, 256, 0, stream>>>(rp_o, ev_o, tabA, rp_s, ev_s, tabB,
                                            b_ogc1, b_sgc1o, oxb, N, 1);

    // ---- Layer 2: tabD = o_x@W_ogc1s;  s_x = relu(spmm_o(tabD) + spmm_s(tabC) + b) -> bf16
    gemm_fused<NHID, 1, true><<<gM64, 256, 0, stream>>>(
        oxb, wt4, tabD, nullptr, nullptr, nullptr, nullptr, N);
    spmm2_csr<true><<<gR, 256, 0, stream>>>(rp_o, ev_o, tabD, rp_s, ev_s, tabC,
                                            b_ogc1s, b_sgc1, sxb, N, 1);

    // ---- Layer 3: tabA = o_x@W_ogc2; tabB = s_x@W_sgc2o; h = spmm sum (fp32)
    gemm_fused<NHID, 1, true><<<gM64, 256, 0, stream>>>(
        oxb, wt5, tabA, nullptr, nullptr, nullptr, nullptr, N);
    gemm_fused<NHID, 1, true><<<gM64, 256, 0, stream>>>(
        sxb, wt6, tabB, nullptr, nullptr, nullptr, nullptr, N);
    spmm2_csr<false><<<gR, 256, 0, stream>>>(rp_o, ev_o, tabA, rp_s, ev_s, tabB,
                                             b_ogc2, b_sgc2o, h, N, 0);

    // ---- Decoder
    dec1_kernel<<<gB, 128, 0, stream>>>(h, idx0, idx1, W_dec1, b_dec1, o1buf, B);
    dec2_kernel<<<gB, 128, 0, stream>>>(o1buf, W_dec2, b_dec2, (float*)d_out, B);
}

// Round 9
// 637.187 us; speedup vs baseline: 7.9806x; 1.0777x over previous
//
#include <hip/hip_runtime.h>
#include <hip/hip_bf16.h>

#define NFEAT 256
#define NHID 128
#define RELL 86
#define BSHIFT 9                 // bucket = row >> 9 (512 rows)
#define SCAT_TILE 4096           // edges per binscat block (16/thread)

typedef __attribute__((ext_vector_type(8))) short short8v;
typedef __attribute__((ext_vector_type(4))) float float4v;

static __device__ __forceinline__ unsigned short f2bf(float f) {
    union { float f; unsigned int u; } v; v.f = f;
    unsigned int r = v.u + 0x7FFF + ((v.u >> 16) & 1);   // RNE
    return (unsigned short)(r >> 16);
}
static __device__ __forceinline__ float asf(unsigned int u) {
    union { unsigned int u; float f; } v; v.u = u; return v.f;
}

// ---------------------------------------------------------------------------
// Weight prep: 3 matrices per launch via blockIdx.y. Wt[col][k] = bf16(W[k][col])
// ---------------------------------------------------------------------------
template <int K>
__global__ __launch_bounds__(256) void wt_prep3(
    const float* __restrict__ W0, const float* __restrict__ W1,
    const float* __restrict__ W2,
    unsigned short* __restrict__ T0, unsigned short* __restrict__ T1,
    unsigned short* __restrict__ T2)
{
    const float* W = (blockIdx.y == 0) ? W0 : ((blockIdx.y == 1) ? W1 : W2);
    unsigned short* T = (blockIdx.y == 0) ? T0 : ((blockIdx.y == 1) ? T1 : T2);
    int i = blockIdx.x * 256 + threadIdx.x;
    if (i < K * 128) {
        int col = i & 127, k = i >> 7;
        T[col * K + k] = f2bf(W[i]);
    }
}

// ---------------------------------------------------------------------------
// CSR build: bucket counts -> bucket scan -> binned scatter -> per-bucket
// local counting-sort (derives rp locally; no per-row global histogram).
// ---------------------------------------------------------------------------
__global__ __launch_bounds__(256) void bucket_count(
    const int* __restrict__ ro, const int* __restrict__ rs,
    int* __restrict__ bcnt, int E)
{
    const int g = blockIdx.y;
    const int* rows = g ? rs : ro;
    int* bc = bcnt + g * 256;
    __shared__ int hist[256];
    const int t = threadIdx.x;
    hist[t] = 0;
    __syncthreads();
    const int e0 = blockIdx.x * SCAT_TILE;
    #pragma unroll
    for (int i = 0; i < 16; ++i) {
        int e = e0 + i * 256 + t;
        if (e < E) atomicAdd(&hist[rows[e] >> BSHIFT], 1);
    }
    __syncthreads();
    if (hist[t] > 0) atomicAdd(&bc[t], hist[t]);
}

__global__ __launch_bounds__(256) void bucket_scan(
    const int* __restrict__ bcnt, int* __restrict__ bbase,
    int* __restrict__ bcur, int E)
{
    __shared__ int sh[256];
    const int t = threadIdx.x;
    for (int g = 0; g < 2; ++g) {
        const int v = bcnt[g * 256 + t];
        sh[t] = v;
        __syncthreads();
        for (int off = 1; off < 256; off <<= 1) {
            int u = (t >= off) ? sh[t - off] : 0;
            __syncthreads();
            sh[t] += u;
            __syncthreads();
        }
        const int ex = sh[t] - v;
        bbase[g * 257 + t] = ex;
        bcur[g * 256 + t] = ex;
        if (t == 255) bbase[g * 257 + 256] = E;
        __syncthreads();
    }
}

__global__ __launch_bounds__(256) void binscat1(
    const int* __restrict__ ro, const int* __restrict__ co,
    const float* __restrict__ vo,
    const int* __restrict__ rs, const int* __restrict__ cs,
    const float* __restrict__ vs,
    int* __restrict__ bcur, int2* __restrict__ temp_o,
    int2* __restrict__ temp_s, int E)
{
    const int g = blockIdx.y;
    const int* rows = g ? rs : ro;
    const int* cols = g ? cs : co;
    const float* vals = g ? vs : vo;
    int* bc = bcur + g * 256;
    int2* temp = g ? temp_s : temp_o;

    __shared__ int hist[256];
    __shared__ int base[256];
    const int t = threadIdx.x;
    hist[t] = 0;
    __syncthreads();

    const int e0 = blockIdx.x * SCAT_TILE;
    int myrow[16];
    #pragma unroll
    for (int i = 0; i < 16; ++i) {
        int e = e0 + i * 256 + t;
        int r = (e < E) ? rows[e] : -1;
        myrow[i] = r;
        if (r >= 0) atomicAdd(&hist[r >> BSHIFT], 1);
    }
    __syncthreads();
    const int h = hist[t];
    if (h > 0) base[t] = atomicAdd(&bc[t], h);
    __syncthreads();
    hist[t] = (h > 0) ? base[t] : 0;     // reuse hist as within-block cursor
    __syncthreads();
    #pragma unroll
    for (int i = 0; i < 16; ++i) {
        const int r = myrow[i];
        if (r >= 0) {
            int e = e0 + i * 256 + t;
            int off = atomicAdd(&hist[r >> BSHIFT], 1);
            temp[off] = make_int2((r & 511) | (cols[e] << BSHIFT),
                                  __float_as_int(vals[e]));
        }
    }
}

__global__ __launch_bounds__(512) void binscat2(
    const int* __restrict__ bbase,
    const int2* __restrict__ temp_o, const int2* __restrict__ temp_s,
    int* __restrict__ rp_o, int* __restrict__ rp_s,
    int2* __restrict__ ev_o, int2* __restrict__ ev_s, int N)
{
    const int g = blockIdx.y;
    const int2* temp = g ? temp_s : temp_o;
    int2* ev = g ? ev_s : ev_o;
    int* rp = g ? rp_s : rp_o;
    const int* bb = bbase + g * 257;

    __shared__ int lcnt[512];
    __shared__ int lpre[512];
    const int b = blockIdx.x;
    const int r0 = b << BSHIFT;
    const int t = threadIdx.x;
    const int e0 = bb[b], e1 = bb[b + 1];

    lcnt[t] = 0;
    __syncthreads();
    for (int e = e0 + t; e < e1; e += 512)
        atomicAdd(&lcnt[temp[e].x & 511], 1);
    __syncthreads();
    const int v = lcnt[t];
    lpre[t] = v;
    __syncthreads();
    for (int off = 1; off < 512; off <<= 1) {
        int u = (t >= off) ? lpre[t - off] : 0;
        __syncthreads();
        lpre[t] += u;
        __syncthreads();
    }
    const int base = e0 + lpre[t] - v;
    const int r = r0 + t;
    if (r <= N) rp[r] = base;
    __syncthreads();
    lcnt[t] = base;
    __syncthreads();
    for (int e = e0 + t; e < e1; e += 512) {
        int2 pk = temp[e];
        int q = atomicAdd(&lcnt[pk.x & 511], 1);
        ev[q] = make_int2(pk.x >> BSHIFT, pk.y);
    }
}

// ---------------------------------------------------------------------------
// Row-set compaction for sparse layer-3 (decoder only reads idx rows).
// Order nondeterministic, values deterministic.
// ---------------------------------------------------------------------------
__global__ __launch_bounds__(256) void mark_rows(
    const int* __restrict__ idx, int* __restrict__ flag, int n2)
{
    int i = blockIdx.x * 256 + threadIdx.x;
    if (i < n2) flag[idx[i]] = 1;
}

__global__ __launch_bounds__(256) void compact_rows(
    const int* __restrict__ flag, int* __restrict__ rlist,
    int* __restrict__ inv, int* __restrict__ ctr, int N)
{
    int r = blockIdx.x * 256 + threadIdx.x;
    if (r < N && flag[r]) {
        int i = atomicAdd(ctr, 1);
        rlist[i] = r;
        inv[r] = i;
    }
}

// ---------------------------------------------------------------------------
// Fused MFMA GEMM: S_m = X @ W_m for NM matrices, X staged ONCE (full K) in LDS.
// ---------------------------------------------------------------------------
template <int K, int NM, bool XBF>
__global__ __launch_bounds__(256) void gemm_fused(
    const void* __restrict__ Xv,
    const unsigned short* __restrict__ Wt0, unsigned short* __restrict__ S0,
    const unsigned short* __restrict__ Wt1, unsigned short* __restrict__ S1,
    const unsigned short* __restrict__ Wt2, unsigned short* __restrict__ S2,
    int Nrows)
{
    constexpr int AST = K + 8;
    __shared__ unsigned short As[64 * AST];
    __shared__ unsigned short Bs[128 * 72];

    const int t = threadIdx.x;
    const int l = t & 63;
    const int w = t >> 6;
    const int row_in = l & 15;
    const int kgrp = l >> 4;        // 0..3
    const int row0 = blockIdx.x * 64;

    {
        constexpr int QPR = K / 4;
        #pragma unroll
        for (int it = 0; it < 64 * QPR / 256; ++it) {
            int i = t + it * 256;
            int r = i / QPR, c4 = i % QPR;
            int gr = row0 + r;
            if (XBF) {
                ushort4 v = make_ushort4(0, 0, 0, 0);
                if (gr < Nrows)
                    v = *(const ushort4*)((const unsigned short*)Xv + (size_t)gr * K + c4 * 4);
                *(ushort4*)&As[r * AST + c4 * 4] = v;
            } else {
                float4 v = make_float4(0.f, 0.f, 0.f, 0.f);
                if (gr < Nrows)
                    v = *(const float4*)((const float*)Xv + (size_t)gr * K + c4 * 4);
                ushort4 b4;
                b4.x = f2bf(v.x); b4.y = f2bf(v.y); b4.z = f2bf(v.z); b4.w = f2bf(v.w);
                *(ushort4*)&As[r * AST + c4 * 4] = b4;
            }
        }
    }

    #pragma unroll
    for (int m = 0; m < NM; ++m) {
        const unsigned short* Wt = (m == 0) ? Wt0 : ((m == 1) ? Wt1 : Wt2);
        unsigned short* S = (m == 0) ? S0 : ((m == 1) ? S1 : S2);
        float4v acc[8];
        #pragma unroll
        for (int n = 0; n < 8; ++n) acc[n] = (float4v)(0.f);

        for (int kt = 0; kt < K / 64; ++kt) {
            __syncthreads();
            #pragma unroll
            for (int it = 0; it < 8; ++it) {
                int i = t + it * 256;
                int r = i >> 4, c4 = i & 15;
                *(ushort4*)&Bs[r * 72 + c4 * 4] =
                    *(const ushort4*)(Wt + (size_t)r * K + kt * 64 + c4 * 4);
            }
            __syncthreads();
            #pragma unroll
            for (int kc = 0; kc < 2; ++kc) {
                short8v a, b[8];
                const unsigned short* pa =
                    &As[(w * 16 + row_in) * AST + kt * 64 + kc * 32 + kgrp * 8];
                ((uint2*)&a)[0] = *(const uint2*)pa;
                ((uint2*)&a)[1] = *(const uint2*)(pa + 4);
                #pragma unroll
                for (int n = 0; n < 8; ++n) {
                    const unsigned short* pb =
                        &Bs[(n * 16 + row_in) * 72 + kc * 32 + kgrp * 8];
                    ((uint2*)&b[n])[0] = *(const uint2*)pb;
                    ((uint2*)&b[n])[1] = *(const uint2*)(pb + 4);
                }
                #pragma unroll
                for (int n = 0; n < 8; ++n)
                    acc[n] = __builtin_amdgcn_mfma_f32_16x16x32_bf16(
                        a, b[n], acc[n], 0, 0, 0);
            }
        }
        #pragma unroll
        for (int n = 0; n < 8; ++n)
            #pragma unroll
            for (int r = 0; r < 4; ++r) {
                int gr = row0 + w * 16 + kgrp * 4 + r;
                int gc = n * 16 + row_in;
                if (gr < Nrows) S[(size_t)gr * 128 + gc] = f2bf(acc[n][r]);
            }
    }
}

// ---------------------------------------------------------------------------
// Fused dual-graph CSR SpMM, interleaved A/B gather streams (4+4 per iter).
// One wave per row; lane l owns features 2l, 2l+1. Tables bf16.
// SPARSE: row list indirection, compact output indexing.
// ---------------------------------------------------------------------------
#define GA(pk) (*(const unsigned*)(Sa + ((size_t)(pk).x << 7) + l2))
#define GB(pk) (*(const unsigned*)(Sb + ((size_t)(pk).x << 7) + l2))
#define ACC(pk, uu) { float vv = __int_as_float((pk).y); \
    ax = fmaf(vv, asf((uu) << 16), ax); ay = fmaf(vv, asf((uu) & 0xffff0000u), ay); }

template <bool OBF, bool SPARSE>
__global__ __launch_bounds__(256) void spmm2_csr(
    const int* __restrict__ rp_a, const int2* __restrict__ ev_a,
    const unsigned short* __restrict__ Sa,
    const int* __restrict__ rp_b, const int2* __restrict__ ev_b,
    const unsigned short* __restrict__ Sb,
    const float* __restrict__ b1, const float* __restrict__ b2,
    void* __restrict__ outv, int N, int do_relu,
    const int* __restrict__ rlist, const int* __restrict__ pcnt)
{
    const int gi = blockIdx.x * 4 + (threadIdx.x >> 6);
    int row;
    if (SPARSE) {
        if (gi >= *pcnt) return;
        row = rlist[gi];
    } else {
        if (gi >= N) return;
        row = gi;
    }
    const int l2 = (threadIdx.x & 63) << 1;

    float2 bv1 = *(const float2*)(b1 + l2);
    float2 bv2 = *(const float2*)(b2 + l2);
    float ax = bv1.x + bv2.x;
    float ay = bv1.y + bv2.y;

    int eA = rp_a[row]; const int eA1 = rp_a[row + 1];
    int eB = rp_b[row]; const int eB1 = rp_b[row + 1];

    // joint interleaved loop: 4 A-gathers + 4 B-gathers in flight together
    while (eA + 4 <= eA1 && eB + 4 <= eB1) {
        const int2 a0 = ev_a[eA], a1 = ev_a[eA + 1], a2 = ev_a[eA + 2], a3 = ev_a[eA + 3];
        const int2 c0 = ev_b[eB], c1 = ev_b[eB + 1], c2 = ev_b[eB + 2], c3 = ev_b[eB + 3];
        const unsigned u0 = GA(a0), u1 = GA(a1), u2 = GA(a2), u3 = GA(a3);
        const unsigned w0 = GB(c0), w1 = GB(c1), w2 = GB(c2), w3 = GB(c3);
        ACC(a0, u0) ACC(a1, u1) ACC(a2, u2) ACC(a3, u3)
        ACC(c0, w0) ACC(c1, w1) ACC(c2, w2) ACC(c3, w3)
        eA += 4; eB += 4;
    }
    // drain A
    for (; eA + 8 <= eA1; eA += 8) {
        const int2 a0 = ev_a[eA], a1 = ev_a[eA + 1], a2 = ev_a[eA + 2], a3 = ev_a[eA + 3];
        const int2 a4 = ev_a[eA + 4], a5 = ev_a[eA + 5], a6 = ev_a[eA + 6], a7 = ev_a[eA + 7];
        const unsigned u0 = GA(a0), u1 = GA(a1), u2 = GA(a2), u3 = GA(a3);
        const unsigned u4 = GA(a4), u5 = GA(a5), u6 = GA(a6), u7 = GA(a7);
        ACC(a0, u0) ACC(a1, u1) ACC(a2, u2) ACC(a3, u3)
        ACC(a4, u4) ACC(a5, u5) ACC(a6, u6) ACC(a7, u7)
    }
    for (; eA + 4 <= eA1; eA += 4) {
        const int2 a0 = ev_a[eA], a1 = ev_a[eA + 1], a2 = ev_a[eA + 2], a3 = ev_a[eA + 3];
        const unsigned u0 = GA(a0), u1 = GA(a1), u2 = GA(a2), u3 = GA(a3);
        ACC(a0, u0) ACC(a1, u1) ACC(a2, u2) ACC(a3, u3)
    }
    for (; eA < eA1; ++eA) {
        const int2 a0 = ev_a[eA];
        const unsigned u0 = GA(a0);
        ACC(a0, u0)
    }
    // drain B
    for (; eB + 8 <= eB1; eB += 8) {
        const int2 c0 = ev_b[eB], c1 = ev_b[eB + 1], c2 = ev_b[eB + 2], c3 = ev_b[eB + 3];
        const int2 c4 = ev_b[eB + 4], c5 = ev_b[eB + 5], c6 = ev_b[eB + 6], c7 = ev_b[eB + 7];
        const unsigned w0 = GB(c0), w1 = GB(c1), w2 = GB(c2), w3 = GB(c3);
        const unsigned w4 = GB(c4), w5 = GB(c5), w6 = GB(c6), w7 = GB(c7);
        ACC(c0, w0) ACC(c1, w1) ACC(c2, w2) ACC(c3, w3)
        ACC(c4, w4) ACC(c5, w5) ACC(c6, w6) ACC(c7, w7)
    }
    for (; eB + 4 <= eB1; eB += 4) {
        const int2 c0 = ev_b[eB], c1 = ev_b[eB + 1], c2 = ev_b[eB + 2], c3 = ev_b[eB + 3];
        const unsigned w0 = GB(c0), w1 = GB(c1), w2 = GB(c2), w3 = GB(c3);
        ACC(c0, w0) ACC(c1, w1) ACC(c2, w2) ACC(c3, w3)
    }
    for (; eB < eB1; ++eB) {
        const int2 c0 = ev_b[eB];
        const unsigned w0 = GB(c0);
        ACC(c0, w0)
    }

    if (do_relu) { ax = fmaxf(ax, 0.f); ay = fmaxf(ay, 0.f); }
    const size_t oidx = SPARSE ? (size_t)gi : (size_t)row;
    if (OBF) {
        unsigned pk = (unsigned)f2bf(ax) | ((unsigned)f2bf(ay) << 16);
        ((unsigned*)outv)[(oidx << 6) + (l2 >> 1)] = pk;
    } else {
        float2 o; o.x = ax; o.y = ay;
        *(float2*)((float*)outv + (oidx << 7) + l2) = o;
    }
}
#undef GA
#undef GB
#undef ACC

// ---------------------------------------------------------------------------
// Decoder stage 1: out[b] = concat(h[inv[idx0[b]]], h[inv[idx1[b]]]) @ W + bias
// h is the COMPACT layer-3 output; inv maps node id -> compact index.
// ---------------------------------------------------------------------------
__global__ __launch_bounds__(128) void dec1_kernel(
    const float* __restrict__ h, const int* __restrict__ inv,
    const int* __restrict__ idx0, const int* __restrict__ idx1,
    const float* __restrict__ W, const float* __restrict__ bias,
    float* __restrict__ out, int B)
{
    __shared__ __align__(16) float fs[16 * 256];
    const int t = threadIdx.x;
    const int b0 = blockIdx.x * 16;
    #pragma unroll
    for (int r = 0; r < 16; ++r) {
        const int b = b0 + r;
        fs[r * 256 + t]       = h[(long)inv[idx0[b]] * 128 + t];
        fs[r * 256 + 128 + t] = h[(long)inv[idx1[b]] * 128 + t];
    }
    __syncthreads();

    const float4* fs4 = (const float4*)fs;
    float acc[16];
    #pragma unroll
    for (int r = 0; r < 16; ++r) acc[r] = 0.f;
    for (int kc = 0; kc < 64; ++kc) {
        const float w0 = W[(kc * 4 + 0) * 128 + t];
        const float w1 = W[(kc * 4 + 1) * 128 + t];
        const float w2 = W[(kc * 4 + 2) * 128 + t];
        const float w3 = W[(kc * 4 + 3) * 128 + t];
        #pragma unroll
        for (int r = 0; r < 16; ++r) {
            const float4 xv = fs4[r * 64 + kc];
            acc[r] = fmaf(xv.x, w0, acc[r]);
            acc[r] = fmaf(xv.y, w1, acc[r]);
            acc[r] = fmaf(xv.z, w2, acc[r]);
            acc[r] = fmaf(xv.w, w3, acc[r]);
        }
    }
    #pragma unroll
    for (int r = 0; r < 16; ++r)
        out[(long)(b0 + r) * 128 + t] = acc[r] + bias[t];
}

// ---------------------------------------------------------------------------
// Decoder stage 2: out[b] = o1[b] @ W + bias -> [B, 86]
// ---------------------------------------------------------------------------
__global__ __launch_bounds__(128) void dec2_kernel(
    const float* __restrict__ o1,
    const float* __restrict__ W, const float* __restrict__ bias,
    float* __restrict__ out, int B)
{
    __shared__ __align__(16) float os[16 * 128];
    const int t = threadIdx.x;
    const int b0 = blockIdx.x * 16;
    #pragma unroll
    for (int r = 0; r < 16; ++r)
        os[r * 128 + t] = o1[(long)(b0 + r) * 128 + t];
    __syncthreads();

    const float4* os4 = (const float4*)os;
    float acc[16];
    #pragma unroll
    for (int r = 0; r < 16; ++r) acc[r] = 0.f;
    const bool act = (t < RELL);
    for (int kc = 0; kc < 32; ++kc) {
        const float w0 = act ? W[(kc * 4 + 0) * RELL + t] : 0.f;
        const float w1 = act ? W[(kc * 4 + 1) * RELL + t] : 0.f;
        const float w2 = act ? W[(kc * 4 + 2) * RELL + t] : 0.f;
        const float w3 = act ? W[(kc * 4 + 3) * RELL + t] : 0.f;
        #pragma unroll
        for (int r = 0; r < 16; ++r) {
            const float4 xv = os4[r * 32 + kc];
            acc[r] = fmaf(xv.x, w0, acc[r]);
            acc[r] = fmaf(xv.y, w1, acc[r]);
            acc[r] = fmaf(xv.z, w2, acc[r]);
            acc[r] = fmaf(xv.w, w3, acc[r]);
        }
    }
    if (act) {
        #pragma unroll
        for (int r = 0; r < 16; ++r)
            out[(long)(b0 + r) * RELL + t] = acc[r] + bias[t];
    }
}

extern "C" void kernel_launch(void* const* d_in, const int* in_sizes, int n_in,
                              void* d_out, int out_size, void* d_ws, size_t ws_size,
                              hipStream_t stream) {
    const float* x      = (const float*)d_in[0];
    const int*   o_rows = (const int*)  d_in[1];
    const int*   o_cols = (const int*)  d_in[2];
    const float* o_vals = (const float*)d_in[3];
    const int*   s_rows = (const int*)  d_in[4];
    const int*   s_cols = (const int*)  d_in[5];
    const float* s_vals = (const float*)d_in[6];
    const int*   idx    = (const int*)  d_in[7];
    const float* W_ogc1  = (const float*)d_in[8];   const float* b_ogc1  = (const float*)d_in[9];
    const float* W_sgc1o = (const float*)d_in[10];  const float* b_sgc1o = (const float*)d_in[11];
    const float* W_sgc1  = (const float*)d_in[12];  const float* b_sgc1  = (const float*)d_in[13];
    const float* W_ogc1s = (const float*)d_in[14];  const float* b_ogc1s = (const float*)d_in[15];
    const float* W_ogc2  = (const float*)d_in[16];  const float* b_ogc2  = (const float*)d_in[17];
    const float* W_sgc2o = (const float*)d_in[18];  const float* b_sgc2o = (const float*)d_in[19];
    const float* W_dec1  = (const float*)d_in[20];  const float* b_dec1  = (const float*)d_in[21];
    const float* W_dec2  = (const float*)d_in[22];  const float* b_dec2  = (const float*)d_in[23];

    const int N = in_sizes[0] / NFEAT;   // 100000
    const int E = in_sizes[1];           // 1600000
    const int B = in_sizes[7] / 2;       // 16384
    const int* idx0 = idx;
    const int* idx1 = idx + B;

    // ---- workspace layout (float units) ----
    float* p = (float*)d_ws;
    const size_t N64 = (size_t)N * 64;    // one bf16 [N,128] table in float units
    float* h    = p;  p += (size_t)N * 128;          // compact fp32 [<=N,128]
    unsigned short* oxb  = (unsigned short*)p; p += N64;   // o_x bf16
    unsigned short* sxb  = (unsigned short*)p; p += N64;   // s_x bf16
    unsigned short* tabA = (unsigned short*)p; p += N64;
    unsigned short* tabB = (unsigned short*)p; p += N64;
    unsigned short* tabC = (unsigned short*)p; p += N64;
    unsigned short* tabD = (unsigned short*)p; p += N64;
    float* o1buf = p; p += (size_t)B * 128;
    unsigned short* wt1 = (unsigned short*)p; p += 16384;   // [128,256] bf16
    unsigned short* wt2 = (unsigned short*)p; p += 16384;
    unsigned short* wt3 = (unsigned short*)p; p += 16384;
    unsigned short* wt4 = (unsigned short*)p; p += 8192;    // [128,128] bf16
    unsigned short* wt5 = (unsigned short*)p; p += 8192;
    unsigned short* wt6 = (unsigned short*)p; p += 8192;
    int* rp_o = (int*)p; p += (size_t)N + 2;
    int* rp_s = (int*)p; p += (size_t)N + 2;
    int2* ev_o = (int2*)p; p += 2 * (size_t)E;
    int2* ev_s = (int2*)p; p += 2 * (size_t)E;
    int* bcnt  = (int*)p; p += 512;                  // [2][256] bucket counts
    int* bbase = (int*)p; p += 516;                  // [2][257] bucket bases
    int* bcur  = (int*)p; p += 512;                  // [2][256] bucket cursors
    int* flag  = (int*)p; p += (size_t)N;            // needed-row flags
    int* rlist = (int*)p; p += (size_t)N;            // compact row list
    int* inv   = (int*)p; p += (size_t)N;            // node -> compact index
    int* ctr   = (int*)p; p += 2;                    // compact count
    // temp binning buffers alias tabA/tabB region (dead until first GEMM)
    int2* temp_o = (int2*)tabA;                      // E int2 = 12.8 MB
    int2* temp_s = temp_o + E;                       // next 12.8 MB

    const int gM64 = (N + 63) / 64;       // 1563
    const int gR = (N + 3) / 4;           // 25000
    const int gB = B / 16;                // 1024
    const int gT = (E + SCAT_TILE - 1) / SCAT_TILE;                   // 391
    const int gBuck = (N + (1 << BSHIFT) - 1) >> BSHIFT;              // 196

    // ---- CSR build (both graphs via y-grid)
    hipMemsetAsync(bcnt, 0, 512 * sizeof(int), stream);
    hipMemsetAsync(flag, 0, (size_t)N * sizeof(int), stream);
    hipMemsetAsync(ctr, 0, sizeof(int), stream);
    bucket_count<<<dim3(gT, 2), 256, 0, stream>>>(o_rows, s_rows, bcnt, E);
    bucket_scan<<<1, 256, 0, stream>>>(bcnt, bbase, bcur, E);
    binscat1<<<dim3(gT, 2), 256, 0, stream>>>(o_rows, o_cols, o_vals,
                                              s_rows, s_cols, s_vals,
                                              bcur, temp_o, temp_s, E);
    binscat2<<<dim3(gBuck, 2), 512, 0, stream>>>(bbase, temp_o, temp_s,
                                                 rp_o, rp_s, ev_o, ev_s, N);

    // ---- needed-row compaction for layer 3
    mark_rows<<<(2 * B + 255) / 256, 256, 0, stream>>>(idx, flag, 2 * B);
    compact_rows<<<(N + 255) / 256, 256, 0, stream>>>(flag, rlist, inv, ctr, N);

    // ---- weight prep
    wt_prep3<NFEAT><<<dim3(128, 3), 256, 0, stream>>>(W_ogc1, W_sgc1o, W_sgc1,
                                                      wt1, wt2, wt3);
    wt_prep3<NHID><<<dim3(64, 3), 256, 0, stream>>>(W_ogc1s, W_ogc2, W_sgc2o,
                                                    wt4, wt5, wt6);

    // ---- Layer 1 GEMMs (x read once): tabA=x@W_ogc1, tabB=x@W_sgc1o, tabC=x@W_sgc1
    gemm_fused<NFEAT, 3, false><<<gM64, 256, 0, stream>>>(
        x, wt1, tabA, wt2, tabB, wt3, tabC, N);
    spmm2_csr<true, false><<<gR, 256, 0, stream>>>(
        rp_o, ev_o, tabA, rp_s, ev_s, tabB,
        b_ogc1, b_sgc1o, oxb, N, 1, nullptr, nullptr);     // o_x

    // ---- Layer 2: tabD = o_x@W_ogc1s; s_x = relu(spmm_o(tabD)+spmm_s(tabC)+b)
    gemm_fused<NHID, 1, true><<<gM64, 256, 0, stream>>>(
        oxb, wt4, tabD, nullptr, nullptr, nullptr, nullptr, N);
    spmm2_csr<true, false><<<gR, 256, 0, stream>>>(
        rp_o, ev_o, tabD, rp_s, ev_s, tabC,
        b_ogc1s, b_sgc1, sxb, N, 1, nullptr, nullptr);     // s_x

    // ---- Layer 3 (sparse rows): tabA = o_x@W_ogc2; tabB = s_x@W_sgc2o
    gemm_fused<NHID, 1, true><<<gM64, 256, 0, stream>>>(
        oxb, wt5, tabA, nullptr, nullptr, nullptr, nullptr, N);
    gemm_fused<NHID, 1, true><<<gM64, 256, 0, stream>>>(
        sxb, wt6, tabB, nullptr, nullptr, nullptr, nullptr, N);
    spmm2_csr<false, true><<<gR, 256, 0, stream>>>(
        rp_o, ev_o, tabA, rp_s, ev_s, tabB,
        b_ogc2, b_sgc2o, h, N, 0, rlist, ctr);             // compact h

    // ---- Decoder (inv-indirected gather from compact h)
    dec1_kernel<<<gB, 128, 0, stream>>>(h, inv, idx0, idx1, W_dec1, b_dec1, o1buf, B);
    dec2_kernel<<<gB, 128, 0, stream>>>(o1buf, W_dec2, b_dec2, (float*)d_out, B);
}

// Round 10
// 612.829 us; speedup vs baseline: 8.2978x; 1.0397x over previous
//
#include <hip/hip_runtime.h>
#include <hip/hip_bf16.h>

#define NFEAT 256
#define NHID 128
#define RELL 86
#define BSHIFT 9                 // bucket = row >> 9 (512 rows)
#define SCAT_TILE 4096           // edges per binscat block (16/thread)
#define TEMPCAP 12288            // per-bucket temp capacity (mean 8192, sigma 90)

typedef __attribute__((ext_vector_type(8))) short short8v;
typedef __attribute__((ext_vector_type(4))) float float4v;

static __device__ __forceinline__ unsigned short f2bf(float f) {
    union { float f; unsigned int u; } v; v.f = f;
    unsigned int r = v.u + 0x7FFF + ((v.u >> 16) & 1);   // RNE
    return (unsigned short)(r >> 16);
}
static __device__ __forceinline__ float asf(unsigned int u) {
    union { unsigned int u; float f; } v; v.u = u; return v.f;
}

// ---------------------------------------------------------------------------
// Weight prep, all 6 matrices in one launch. Wt[col][k] = bf16(W[k][col])
// ---------------------------------------------------------------------------
__global__ __launch_bounds__(256) void wt_prep6(
    const float* __restrict__ W0, const float* __restrict__ W1,
    const float* __restrict__ W2, const float* __restrict__ W3,
    const float* __restrict__ W4, const float* __restrict__ W5,
    unsigned short* __restrict__ T0, unsigned short* __restrict__ T1,
    unsigned short* __restrict__ T2, unsigned short* __restrict__ T3,
    unsigned short* __restrict__ T4, unsigned short* __restrict__ T5)
{
    const int y = blockIdx.y;
    const int K = (y < 3) ? NFEAT : NHID;
    const float* W = (y == 0) ? W0 : (y == 1) ? W1 : (y == 2) ? W2
                   : (y == 3) ? W3 : (y == 4) ? W4 : W5;
    unsigned short* T = (y == 0) ? T0 : (y == 1) ? T1 : (y == 2) ? T2
                      : (y == 3) ? T3 : (y == 4) ? T4 : T5;
    int i = blockIdx.x * 256 + threadIdx.x;
    if (i < K * 128) {
        int col = i & 127, k = i >> 7;
        T[col * K + k] = f2bf(W[i]);
    }
}

// ---------------------------------------------------------------------------
// CSR build: fixed-capacity binned scatter -> bucket scan -> per-bucket
// local counting-sort. No per-row global histogram, no pre-count pass.
// ---------------------------------------------------------------------------
__global__ __launch_bounds__(512) void binit2(int* __restrict__ bcur)
{
    const int t = threadIdx.x;          // [0,512): g = t>>8, b = t&255
    bcur[t] = (t & 255) * TEMPCAP;
}

// Phase 1: bin edges by row>>9 into fixed-capacity temp slots,
// packed (row&511 | col<<9, val_bits).
__global__ __launch_bounds__(256) void binscat1(
    const int* __restrict__ ro, const int* __restrict__ co,
    const float* __restrict__ vo,
    const int* __restrict__ rs, const int* __restrict__ cs,
    const float* __restrict__ vs,
    int* __restrict__ bcur, int2* __restrict__ temp_o,
    int2* __restrict__ temp_s, int E)
{
    const int g = blockIdx.y;
    const int* rows = g ? rs : ro;
    const int* cols = g ? cs : co;
    const float* vals = g ? vs : vo;
    int* bc = bcur + g * 256;
    int2* temp = g ? temp_s : temp_o;

    __shared__ int hist[256];
    __shared__ int base[256];
    const int t = threadIdx.x;
    hist[t] = 0;
    __syncthreads();

    const int e0 = blockIdx.x * SCAT_TILE;
    int myrow[16];
    #pragma unroll
    for (int i = 0; i < 16; ++i) {
        int e = e0 + i * 256 + t;
        int r = (e < E) ? rows[e] : -1;
        myrow[i] = r;
        if (r >= 0) atomicAdd(&hist[r >> BSHIFT], 1);
    }
    __syncthreads();
    const int h = hist[t];
    if (h > 0) base[t] = atomicAdd(&bc[t], h);
    __syncthreads();
    hist[t] = (h > 0) ? base[t] : 0;     // reuse hist as within-block cursor
    __syncthreads();
    #pragma unroll
    for (int i = 0; i < 16; ++i) {
        const int r = myrow[i];
        if (r >= 0) {
            int e = e0 + i * 256 + t;
            int off = atomicAdd(&hist[r >> BSHIFT], 1);
            temp[off] = make_int2((r & 511) | (cols[e] << BSHIFT),
                                  __float_as_int(vals[e]));
        }
    }
}

// Bucket-base scan from end cursors: count[b] = bcur[b] - b*TEMPCAP.
__global__ __launch_bounds__(256) void bucket_scan2(
    const int* __restrict__ bcur, int* __restrict__ bbase, int E)
{
    __shared__ int sh[256];
    const int t = threadIdx.x;
    for (int g = 0; g < 2; ++g) {
        const int v = bcur[g * 256 + t] - t * TEMPCAP;
        sh[t] = v;
        __syncthreads();
        for (int off = 1; off < 256; off <<= 1) {
            int u = (t >= off) ? sh[t - off] : 0;
            __syncthreads();
            sh[t] += u;
            __syncthreads();
        }
        bbase[g * 257 + t] = sh[t] - v;   // exclusive
        if (t == 255) bbase[g * 257 + 256] = E;
        __syncthreads();
    }
}

// Phase 2: per-bucket local counting sort. Counts rows in LDS, scans, writes
// rp for this bucket's row range, then scatters edges to final CSR order.
__global__ __launch_bounds__(512) void binscat2(
    const int* __restrict__ bbase, const int* __restrict__ bcur,
    const int2* __restrict__ temp_o, const int2* __restrict__ temp_s,
    int* __restrict__ rp_o, int* __restrict__ rp_s,
    int2* __restrict__ ev_o, int2* __restrict__ ev_s, int N)
{
    const int g = blockIdx.y;
    const int2* temp = g ? temp_s : temp_o;
    int2* ev = g ? ev_s : ev_o;
    int* rp = g ? rp_s : rp_o;
    const int* bb = bbase + g * 257;

    __shared__ int lcnt[512];
    __shared__ int lpre[512];
    const int b = blockIdx.x;
    const int r0 = b << BSHIFT;
    const int t = threadIdx.x;
    const int e0 = bb[b];                      // final CSR base
    const int cntE = bb[b + 1] - e0;           // edges in bucket
    const int t0 = b * TEMPCAP;                // temp base

    lcnt[t] = 0;
    __syncthreads();
    for (int i = t; i < cntE; i += 512)
        atomicAdd(&lcnt[temp[t0 + i].x & 511], 1);
    __syncthreads();
    const int v = lcnt[t];
    lpre[t] = v;
    __syncthreads();
    for (int off = 1; off < 512; off <<= 1) {
        int u = (t >= off) ? lpre[t - off] : 0;
        __syncthreads();
        lpre[t] += u;
        __syncthreads();
    }
    const int base = e0 + lpre[t] - v;
    const int r = r0 + t;
    if (r <= N) rp[r] = base;
    __syncthreads();
    lcnt[t] = base;
    __syncthreads();
    for (int i = t; i < cntE; i += 512) {
        int2 pk = temp[t0 + i];
        int q = atomicAdd(&lcnt[pk.x & 511], 1);
        ev[q] = make_int2(pk.x >> BSHIFT, pk.y);
    }
}

// ---------------------------------------------------------------------------
// Row-set compaction for sparse layer-3 (decoder only reads idx rows).
// ---------------------------------------------------------------------------
__global__ __launch_bounds__(256) void mark_rows(
    const int* __restrict__ idx, int* __restrict__ flag, int n2)
{
    int i = blockIdx.x * 256 + threadIdx.x;
    if (i < n2) flag[idx[i]] = 1;
}

__global__ __launch_bounds__(256) void compact_rows(
    const int* __restrict__ flag, int* __restrict__ rlist,
    int* __restrict__ inv, int* __restrict__ ctr, int N)
{
    int r = blockIdx.x * 256 + threadIdx.x;
    if (r < N && flag[r]) {
        int i = atomicAdd(ctr, 1);
        rlist[i] = r;
        inv[r] = i;
    }
}

// ---------------------------------------------------------------------------
// Fused MFMA GEMM: S_m = X @ W_m for NM matrices, X staged ONCE (full K) in LDS.
// ---------------------------------------------------------------------------
template <int K, int NM, bool XBF>
__global__ __launch_bounds__(256) void gemm_fused(
    const void* __restrict__ Xv,
    const unsigned short* __restrict__ Wt0, unsigned short* __restrict__ S0,
    const unsigned short* __restrict__ Wt1, unsigned short* __restrict__ S1,
    const unsigned short* __restrict__ Wt2, unsigned short* __restrict__ S2,
    int Nrows)
{
    constexpr int AST = K + 8;
    __shared__ unsigned short As[64 * AST];
    __shared__ unsigned short Bs[128 * 72];

    const int t = threadIdx.x;
    const int l = t & 63;
    const int w = t >> 6;
    const int row_in = l & 15;
    const int kgrp = l >> 4;        // 0..3
    const int row0 = blockIdx.x * 64;

    {
        constexpr int QPR = K / 4;
        #pragma unroll
        for (int it = 0; it < 64 * QPR / 256; ++it) {
            int i = t + it * 256;
            int r = i / QPR, c4 = i % QPR;
            int gr = row0 + r;
            if (XBF) {
                ushort4 v = make_ushort4(0, 0, 0, 0);
                if (gr < Nrows)
                    v = *(const ushort4*)((const unsigned short*)Xv + (size_t)gr * K + c4 * 4);
                *(ushort4*)&As[r * AST + c4 * 4] = v;
            } else {
                float4 v = make_float4(0.f, 0.f, 0.f, 0.f);
                if (gr < Nrows)
                    v = *(const float4*)((const float*)Xv + (size_t)gr * K + c4 * 4);
                ushort4 b4;
                b4.x = f2bf(v.x); b4.y = f2bf(v.y); b4.z = f2bf(v.z); b4.w = f2bf(v.w);
                *(ushort4*)&As[r * AST + c4 * 4] = b4;
            }
        }
    }

    #pragma unroll
    for (int m = 0; m < NM; ++m) {
        const unsigned short* Wt = (m == 0) ? Wt0 : ((m == 1) ? Wt1 : Wt2);
        unsigned short* S = (m == 0) ? S0 : ((m == 1) ? S1 : S2);
        float4v acc[8];
        #pragma unroll
        for (int n = 0; n < 8; ++n) acc[n] = (float4v)(0.f);

        for (int kt = 0; kt < K / 64; ++kt) {
            __syncthreads();
            #pragma unroll
            for (int it = 0; it < 8; ++it) {
                int i = t + it * 256;
                int r = i >> 4, c4 = i & 15;
                *(ushort4*)&Bs[r * 72 + c4 * 4] =
                    *(const ushort4*)(Wt + (size_t)r * K + kt * 64 + c4 * 4);
            }
            __syncthreads();
            #pragma unroll
            for (int kc = 0; kc < 2; ++kc) {
                short8v a, b[8];
                const unsigned short* pa =
                    &As[(w * 16 + row_in) * AST + kt * 64 + kc * 32 + kgrp * 8];
                ((uint2*)&a)[0] = *(const uint2*)pa;
                ((uint2*)&a)[1] = *(const uint2*)(pa + 4);
                #pragma unroll
                for (int n = 0; n < 8; ++n) {
                    const unsigned short* pb =
                        &Bs[(n * 16 + row_in) * 72 + kc * 32 + kgrp * 8];
                    ((uint2*)&b[n])[0] = *(const uint2*)pb;
                    ((uint2*)&b[n])[1] = *(const uint2*)(pb + 4);
                }
                #pragma unroll
                for (int n = 0; n < 8; ++n)
                    acc[n] = __builtin_amdgcn_mfma_f32_16x16x32_bf16(
                        a, b[n], acc[n], 0, 0, 0);
            }
        }
        #pragma unroll
        for (int n = 0; n < 8; ++n)
            #pragma unroll
            for (int r = 0; r < 4; ++r) {
                int gr = row0 + w * 16 + kgrp * 4 + r;
                int gc = n * 16 + row_in;
                if (gr < Nrows) S[(size_t)gr * 128 + gc] = f2bf(acc[n][r]);
            }
    }
}

// ---------------------------------------------------------------------------
// Fused dual-graph CSR SpMM, interleaved A/B gather streams (4+4 per iter).
// One wave per row; lane l owns features 2l, 2l+1. Tables bf16.
// SPARSE: row list indirection, compact output indexing.
// ---------------------------------------------------------------------------
#define GA(pk) (*(const unsigned*)(Sa + ((size_t)(pk).x << 7) + l2))
#define GB(pk) (*(const unsigned*)(Sb + ((size_t)(pk).x << 7) + l2))
#define ACC(pk, uu) { float vv = __int_as_float((pk).y); \
    ax = fmaf(vv, asf((uu) << 16), ax); ay = fmaf(vv, asf((uu) & 0xffff0000u), ay); }

template <bool OBF, bool SPARSE>
__global__ __launch_bounds__(256) void spmm2_csr(
    const int* __restrict__ rp_a, const int2* __restrict__ ev_a,
    const unsigned short* __restrict__ Sa,
    const int* __restrict__ rp_b, const int2* __restrict__ ev_b,
    const unsigned short* __restrict__ Sb,
    const float* __restrict__ b1, const float* __restrict__ b2,
    void* __restrict__ outv, int N, int do_relu,
    const int* __restrict__ rlist, const int* __restrict__ pcnt)
{
    const int gi = blockIdx.x * 4 + (threadIdx.x >> 6);
    int row;
    if (SPARSE) {
        if (gi >= *pcnt) return;
        row = rlist[gi];
    } else {
        if (gi >= N) return;
        row = gi;
    }
    const int l2 = (threadIdx.x & 63) << 1;

    float2 bv1 = *(const float2*)(b1 + l2);
    float2 bv2 = *(const float2*)(b2 + l2);
    float ax = bv1.x + bv2.x;
    float ay = bv1.y + bv2.y;

    int eA = rp_a[row]; const int eA1 = rp_a[row + 1];
    int eB = rp_b[row]; const int eB1 = rp_b[row + 1];

    while (eA + 4 <= eA1 && eB + 4 <= eB1) {
        const int2 a0 = ev_a[eA], a1 = ev_a[eA + 1], a2 = ev_a[eA + 2], a3 = ev_a[eA + 3];
        const int2 c0 = ev_b[eB], c1 = ev_b[eB + 1], c2 = ev_b[eB + 2], c3 = ev_b[eB + 3];
        const unsigned u0 = GA(a0), u1 = GA(a1), u2 = GA(a2), u3 = GA(a3);
        const unsigned w0 = GB(c0), w1 = GB(c1), w2 = GB(c2), w3 = GB(c3);
        ACC(a0, u0) ACC(a1, u1) ACC(a2, u2) ACC(a3, u3)
        ACC(c0, w0) ACC(c1, w1) ACC(c2, w2) ACC(c3, w3)
        eA += 4; eB += 4;
    }
    for (; eA + 8 <= eA1; eA += 8) {
        const int2 a0 = ev_a[eA], a1 = ev_a[eA + 1], a2 = ev_a[eA + 2], a3 = ev_a[eA + 3];
        const int2 a4 = ev_a[eA + 4], a5 = ev_a[eA + 5], a6 = ev_a[eA + 6], a7 = ev_a[eA + 7];
        const unsigned u0 = GA(a0), u1 = GA(a1), u2 = GA(a2), u3 = GA(a3);
        const unsigned u4 = GA(a4), u5 = GA(a5), u6 = GA(a6), u7 = GA(a7);
        ACC(a0, u0) ACC(a1, u1) ACC(a2, u2) ACC(a3, u3)
        ACC(a4, u4) ACC(a5, u5) ACC(a6, u6) ACC(a7, u7)
    }
    for (; eA + 4 <= eA1; eA += 4) {
        const int2 a0 = ev_a[eA], a1 = ev_a[eA + 1], a2 = ev_a[eA + 2], a3 = ev_a[eA + 3];
        const unsigned u0 = GA(a0), u1 = GA(a1), u2 = GA(a2), u3 = GA(a3);
        ACC(a0, u0) ACC(a1, u1) ACC(a2, u2) ACC(a3, u3)
    }
    for (; eA < eA1; ++eA) {
        const int2 a0 = ev_a[eA];
        const unsigned u0 = GA(a0);
        ACC(a0, u0)
    }
    for (; eB + 8 <= eB1; eB += 8) {
        const int2 c0 = ev_b[eB], c1 = ev_b[eB + 1], c2 = ev_b[eB + 2], c3 = ev_b[eB + 3];
        const int2 c4 = ev_b[eB + 4], c5 = ev_b[eB + 5], c6 = ev_b[eB + 6], c7 = ev_b[eB + 7];
        const unsigned w0 = GB(c0), w1 = GB(c1), w2 = GB(c2), w3 = GB(c3);
        const unsigned w4 = GB(c4), w5 = GB(c5), w6 = GB(c6), w7 = GB(c7);
        ACC(c0, w0) ACC(c1, w1) ACC(c2, w2) ACC(c3, w3)
        ACC(c4, w4) ACC(c5, w5) ACC(c6, w6) ACC(c7, w7)
    }
    for (; eB + 4 <= eB1; eB += 4) {
        const int2 c0 = ev_b[eB], c1 = ev_b[eB + 1], c2 = ev_b[eB + 2], c3 = ev_b[eB + 3];
        const unsigned w0 = GB(c0), w1 = GB(c1), w2 = GB(c2), w3 = GB(c3);
        ACC(c0, w0) ACC(c1, w1) ACC(c2, w2) ACC(c3, w3)
    }
    for (; eB < eB1; ++eB) {
        const int2 c0 = ev_b[eB];
        const unsigned w0 = GB(c0);
        ACC(c0, w0)
    }

    if (do_relu) { ax = fmaxf(ax, 0.f); ay = fmaxf(ay, 0.f); }
    const size_t oidx = SPARSE ? (size_t)gi : (size_t)row;
    if (OBF) {
        unsigned pk = (unsigned)f2bf(ax) | ((unsigned)f2bf(ay) << 16);
        ((unsigned*)outv)[(oidx << 6) + (l2 >> 1)] = pk;
    } else {
        float2 o; o.x = ax; o.y = ay;
        *(float2*)((float*)outv + (oidx << 7) + l2) = o;
    }
}
#undef GA
#undef GB
#undef ACC

// ---------------------------------------------------------------------------
// Fused decoder: o1 tile stays in LDS between the two small GEMMs.
// out[b] = (concat(h[inv[i0]], h[inv[i1]]) @ Wd1 + bd1) @ Wd2 + bd2
// ---------------------------------------------------------------------------
__global__ __launch_bounds__(128) void dec_fused(
    const float* __restrict__ h, const int* __restrict__ inv,
    const int* __restrict__ idx0, const int* __restrict__ idx1,
    const float* __restrict__ Wd1, const float* __restrict__ bd1,
    const float* __restrict__ Wd2, const float* __restrict__ bd2,
    float* __restrict__ out, int B)
{
    __shared__ __align__(16) float fs[16 * 256];
    __shared__ __align__(16) float os[16 * 128];
    const int t = threadIdx.x;
    const int b0 = blockIdx.x * 16;
    #pragma unroll
    for (int r = 0; r < 16; ++r) {
        const int b = b0 + r;
        fs[r * 256 + t]       = h[(long)inv[idx0[b]] * 128 + t];
        fs[r * 256 + 128 + t] = h[(long)inv[idx1[b]] * 128 + t];
    }
    __syncthreads();

    {
        const float4* fs4 = (const float4*)fs;
        float acc[16];
        #pragma unroll
        for (int r = 0; r < 16; ++r) acc[r] = 0.f;
        for (int kc = 0; kc < 64; ++kc) {
            const float w0 = Wd1[(kc * 4 + 0) * 128 + t];
            const float w1 = Wd1[(kc * 4 + 1) * 128 + t];
            const float w2 = Wd1[(kc * 4 + 2) * 128 + t];
            const float w3 = Wd1[(kc * 4 + 3) * 128 + t];
            #pragma unroll
            for (int r = 0; r < 16; ++r) {
                const float4 xv = fs4[r * 64 + kc];
                acc[r] = fmaf(xv.x, w0, acc[r]);
                acc[r] = fmaf(xv.y, w1, acc[r]);
                acc[r] = fmaf(xv.z, w2, acc[r]);
                acc[r] = fmaf(xv.w, w3, acc[r]);
            }
        }
        #pragma unroll
        for (int r = 0; r < 16; ++r)
            os[r * 128 + t] = acc[r] + bd1[t];
    }
    __syncthreads();

    {
        const float4* os4 = (const float4*)os;
        float acc[16];
        #pragma unroll
        for (int r = 0; r < 16; ++r) acc[r] = 0.f;
        const bool act = (t < RELL);
        for (int kc = 0; kc < 32; ++kc) {
            const float w0 = act ? Wd2[(kc * 4 + 0) * RELL + t] : 0.f;
            const float w1 = act ? Wd2[(kc * 4 + 1) * RELL + t] : 0.f;
            const float w2 = act ? Wd2[(kc * 4 + 2) * RELL + t] : 0.f;
            const float w3 = act ? Wd2[(kc * 4 + 3) * RELL + t] : 0.f;
            #pragma unroll
            for (int r = 0; r < 16; ++r) {
                const float4 xv = os4[r * 32 + kc];
                acc[r] = fmaf(xv.x, w0, acc[r]);
                acc[r] = fmaf(xv.y, w1, acc[r]);
                acc[r] = fmaf(xv.z, w2, acc[r]);
                acc[r] = fmaf(xv.w, w3, acc[r]);
            }
        }
        if (act) {
            #pragma unroll
            for (int r = 0; r < 16; ++r)
                out[(long)(b0 + r) * RELL + t] = acc[r] + bd2[t];
        }
    }
}

extern "C" void kernel_launch(void* const* d_in, const int* in_sizes, int n_in,
                              void* d_out, int out_size, void* d_ws, size_t ws_size,
                              hipStream_t stream) {
    const float* x      = (const float*)d_in[0];
    const int*   o_rows = (const int*)  d_in[1];
    const int*   o_cols = (const int*)  d_in[2];
    const float* o_vals = (const float*)d_in[3];
    const int*   s_rows = (const int*)  d_in[4];
    const int*   s_cols = (const int*)  d_in[5];
    const float* s_vals = (const float*)d_in[6];
    const int*   idx    = (const int*)  d_in[7];
    const float* W_ogc1  = (const float*)d_in[8];   const float* b_ogc1  = (const float*)d_in[9];
    const float* W_sgc1o = (const float*)d_in[10];  const float* b_sgc1o = (const float*)d_in[11];
    const float* W_sgc1  = (const float*)d_in[12];  const float* b_sgc1  = (const float*)d_in[13];
    const float* W_ogc1s = (const float*)d_in[14];  const float* b_ogc1s = (const float*)d_in[15];
    const float* W_ogc2  = (const float*)d_in[16];  const float* b_ogc2  = (const float*)d_in[17];
    const float* W_sgc2o = (const float*)d_in[18];  const float* b_sgc2o = (const float*)d_in[19];
    const float* W_dec1  = (const float*)d_in[20];  const float* b_dec1  = (const float*)d_in[21];
    const float* W_dec2  = (const float*)d_in[22];  const float* b_dec2  = (const float*)d_in[23];

    const int N = in_sizes[0] / NFEAT;   // 100000
    const int E = in_sizes[1];           // 1600000
    const int B = in_sizes[7] / 2;       // 16384
    const int* idx0 = idx;
    const int* idx1 = idx + B;

    // ---- workspace layout (float units) ----
    float* p = (float*)d_ws;
    const size_t N64 = (size_t)N * 64;    // one bf16 [N,128] table in float units
    float* h    = p;  p += (size_t)N * 128;          // compact fp32 [<=2B,128]
    unsigned short* oxb  = (unsigned short*)p; p += N64;   // o_x bf16
    unsigned short* sxb  = (unsigned short*)p; p += N64;   // s_x bf16
    unsigned short* tabA = (unsigned short*)p; p += N64;
    unsigned short* tabB = (unsigned short*)p; p += N64;
    unsigned short* tabC = (unsigned short*)p; p += N64;
    unsigned short* tabD = (unsigned short*)p; p += N64;
    unsigned short* wt1 = (unsigned short*)p; p += 16384;   // [128,256] bf16
    unsigned short* wt2 = (unsigned short*)p; p += 16384;
    unsigned short* wt3 = (unsigned short*)p; p += 16384;
    unsigned short* wt4 = (unsigned short*)p; p += 8192;    // [128,128] bf16
    unsigned short* wt5 = (unsigned short*)p; p += 8192;
    unsigned short* wt6 = (unsigned short*)p; p += 8192;
    int* rp_o = (int*)p; p += (size_t)N + 2;
    int* rp_s = (int*)p; p += (size_t)N + 2;
    int2* ev_o = (int2*)p; p += 2 * (size_t)E;
    int2* ev_s = (int2*)p; p += 2 * (size_t)E;
    int* bbase = (int*)p; p += 516;                  // [2][257] bucket bases
    int* bcur  = (int*)p; p += 512;                  // [2][256] bucket cursors
    int* flag  = (int*)p; p += (size_t)N;            // needed-row flags
    int* rlist = (int*)p; p += (size_t)N;            // compact row list
    int* inv   = (int*)p; p += (size_t)N;            // node -> compact index
    int* ctr   = (int*)p; p += 2;                    // compact count
    // temp binning buffers alias tabA/tabB (dead until first GEMM)
    int2* temp_o = (int2*)tabA;                      // 256*TEMPCAP int2 = 25.2 MB
    int2* temp_s = (int2*)tabB;

    const int gM64 = (N + 63) / 64;       // 1563
    const int gR = (N + 3) / 4;           // 25000
    const int gRs = (2 * B + 3) / 4;      // 8192 (sparse rows <= 2B)
    const int gB = B / 16;                // 1024
    const int gT = (E + SCAT_TILE - 1) / SCAT_TILE;                   // 391
    const int gBuck = (N + (1 << BSHIFT) - 1) >> BSHIFT;              // 196

    // ---- CSR build (both graphs via y-grid), no pre-count pass
    hipMemsetAsync(flag, 0, (size_t)N * sizeof(int), stream);
    hipMemsetAsync(ctr, 0, sizeof(int), stream);
    binit2<<<1, 512, 0, stream>>>(bcur);
    binscat1<<<dim3(gT, 2), 256, 0, stream>>>(o_rows, o_cols, o_vals,
                                              s_rows, s_cols, s_vals,
                                              bcur, temp_o, temp_s, E);
    bucket_scan2<<<1, 256, 0, stream>>>(bcur, bbase, E);
    binscat2<<<dim3(gBuck, 2), 512, 0, stream>>>(bbase, bcur, temp_o, temp_s,
                                                 rp_o, rp_s, ev_o, ev_s, N);

    // ---- needed-row compaction for layer 3
    mark_rows<<<(2 * B + 255) / 256, 256, 0, stream>>>(idx, flag, 2 * B);
    compact_rows<<<(N + 255) / 256, 256, 0, stream>>>(flag, rlist, inv, ctr, N);

    // ---- weight prep (all 6 in one launch)
    wt_prep6<<<dim3(128, 6), 256, 0, stream>>>(W_ogc1, W_sgc1o, W_sgc1,
                                               W_ogc1s, W_ogc2, W_sgc2o,
                                               wt1, wt2, wt3, wt4, wt5, wt6);

    // ---- Layer 1 GEMMs (x read once): tabA=x@W_ogc1, tabB=x@W_sgc1o, tabC=x@W_sgc1
    gemm_fused<NFEAT, 3, false><<<gM64, 256, 0, stream>>>(
        x, wt1, tabA, wt2, tabB, wt3, tabC, N);
    spmm2_csr<true, false><<<gR, 256, 0, stream>>>(
        rp_o, ev_o, tabA, rp_s, ev_s, tabB,
        b_ogc1, b_sgc1o, oxb, N, 1, nullptr, nullptr);     // o_x

    // ---- Layer 2+3a GEMMs (oxb read once): tabD = o_x@W_ogc1s, tabA = o_x@W_ogc2
    gemm_fused<NHID, 2, true><<<gM64, 256, 0, stream>>>(
        oxb, wt4, tabD, wt5, tabA, nullptr, nullptr, N);
    spmm2_csr<true, false><<<gR, 256, 0, stream>>>(
        rp_o, ev_o, tabD, rp_s, ev_s, tabC,
        b_ogc1s, b_sgc1, sxb, N, 1, nullptr, nullptr);     // s_x

    // ---- Layer 3b GEMM: tabB = s_x@W_sgc2o; sparse spmm -> compact h
    gemm_fused<NHID, 1, true><<<gM64, 256, 0, stream>>>(
        sxb, wt6, tabB, nullptr, nullptr, nullptr, nullptr, N);
    spmm2_csr<false, true><<<gRs, 256, 0, stream>>>(
        rp_o, ev_o, tabA, rp_s, ev_s, tabB,
        b_ogc2, b_sgc2o, h, N, 0, rlist, ctr);             // compact h

    // ---- Fused decoder
    dec_fused<<<gB, 128, 0, stream>>>(h, inv, idx0, idx1,
                                      W_dec1, b_dec1, W_dec2, b_dec2,
                                      (float*)d_out, B);
}

// Round 11
// 594.900 us; speedup vs baseline: 8.5478x; 1.0301x over previous
//
#include <hip/hip_runtime.h>
#include <hip/hip_bf16.h>

#define NFEAT 256
#define NHID 128
#define RELL 86
#define BSHIFT 9                 // bucket = row >> 9 (512 rows)
#define SCAT_TILE 8192           // edges per binscat block (32/thread)
#define TEMPCAP 12288            // per-bucket temp capacity (mean 8192, sigma 90)

typedef __attribute__((ext_vector_type(8))) short short8v;
typedef __attribute__((ext_vector_type(4))) float float4v;

static __device__ __forceinline__ unsigned short f2bf(float f) {
    union { float f; unsigned int u; } v; v.f = f;
    unsigned int r = v.u + 0x7FFF + ((v.u >> 16) & 1);   // RNE
    return (unsigned short)(r >> 16);
}
static __device__ __forceinline__ float asf(unsigned int u) {
    union { unsigned int u; float f; } v; v.u = u; return v.f;
}

// ---------------------------------------------------------------------------
// Weight prep, all 6 matrices in one launch. Wt[col][k] = bf16(W[k][col])
// ---------------------------------------------------------------------------
__global__ __launch_bounds__(256) void wt_prep6(
    const float* __restrict__ W0, const float* __restrict__ W1,
    const float* __restrict__ W2, const float* __restrict__ W3,
    const float* __restrict__ W4, const float* __restrict__ W5,
    unsigned short* __restrict__ T0, unsigned short* __restrict__ T1,
    unsigned short* __restrict__ T2, unsigned short* __restrict__ T3,
    unsigned short* __restrict__ T4, unsigned short* __restrict__ T5)
{
    const int y = blockIdx.y;
    const int K = (y < 3) ? NFEAT : NHID;
    const float* W = (y == 0) ? W0 : (y == 1) ? W1 : (y == 2) ? W2
                   : (y == 3) ? W3 : (y == 4) ? W4 : W5;
    unsigned short* T = (y == 0) ? T0 : (y == 1) ? T1 : (y == 2) ? T2
                      : (y == 3) ? T3 : (y == 4) ? T4 : T5;
    int i = blockIdx.x * 256 + threadIdx.x;
    if (i < K * 128) {
        int col = i & 127, k = i >> 7;
        T[col * K + k] = f2bf(W[i]);
    }
}

// ---------------------------------------------------------------------------
// CSR build: fixed-capacity binned scatter -> bucket scan -> per-bucket
// local counting-sort. No per-row global histogram, no pre-count pass.
// ---------------------------------------------------------------------------
__global__ __launch_bounds__(512) void binit2(int* __restrict__ bcur)
{
    const int t = threadIdx.x;          // [0,512): g = t>>8, b = t&255
    bcur[t] = (t & 255) * TEMPCAP;
}

// Phase 1: bin edges by row>>9 into fixed-capacity temp slots,
// packed (row&511 | col<<9, val_bits).
__global__ __launch_bounds__(256) void binscat1(
    const int* __restrict__ ro, const int* __restrict__ co,
    const float* __restrict__ vo,
    const int* __restrict__ rs, const int* __restrict__ cs,
    const float* __restrict__ vs,
    int* __restrict__ bcur, int2* __restrict__ temp_o,
    int2* __restrict__ temp_s, int E)
{
    const int g = blockIdx.y;
    const int* rows = g ? rs : ro;
    const int* cols = g ? cs : co;
    const float* vals = g ? vs : vo;
    int* bc = bcur + g * 256;
    int2* temp = g ? temp_s : temp_o;

    __shared__ int hist[256];
    __shared__ int base[256];
    const int t = threadIdx.x;
    hist[t] = 0;
    __syncthreads();

    const int e0 = blockIdx.x * SCAT_TILE;
    int myrow[32];
    #pragma unroll
    for (int i = 0; i < 32; ++i) {
        int e = e0 + i * 256 + t;
        int r = (e < E) ? rows[e] : -1;
        myrow[i] = r;
        if (r >= 0) atomicAdd(&hist[r >> BSHIFT], 1);
    }
    __syncthreads();
    const int h = hist[t];
    if (h > 0) base[t] = atomicAdd(&bc[t], h);
    __syncthreads();
    hist[t] = (h > 0) ? base[t] : 0;     // reuse hist as within-block cursor
    __syncthreads();
    #pragma unroll
    for (int i = 0; i < 32; ++i) {
        const int r = myrow[i];
        if (r >= 0) {
            int e = e0 + i * 256 + t;
            int off = atomicAdd(&hist[r >> BSHIFT], 1);
            temp[off] = make_int2((r & 511) | (cols[e] << BSHIFT),
                                  __float_as_int(vals[e]));
        }
    }
}

// Bucket-base scan from end cursors: count[b] = bcur[b] - b*TEMPCAP.
__global__ __launch_bounds__(256) void bucket_scan2(
    const int* __restrict__ bcur, int* __restrict__ bbase, int E)
{
    __shared__ int sh[256];
    const int t = threadIdx.x;
    for (int g = 0; g < 2; ++g) {
        const int v = bcur[g * 256 + t] - t * TEMPCAP;
        sh[t] = v;
        __syncthreads();
        for (int off = 1; off < 256; off <<= 1) {
            int u = (t >= off) ? sh[t - off] : 0;
            __syncthreads();
            sh[t] += u;
            __syncthreads();
        }
        bbase[g * 257 + t] = sh[t] - v;   // exclusive
        if (t == 255) bbase[g * 257 + 256] = E;
        __syncthreads();
    }
}

// Phase 2: per-bucket local counting sort. Counts rows in LDS, scans, writes
// rp for this bucket's row range, then scatters edges to final CSR order.
__global__ __launch_bounds__(512) void binscat2(
    const int* __restrict__ bbase, const int* __restrict__ bcur,
    const int2* __restrict__ temp_o, const int2* __restrict__ temp_s,
    int* __restrict__ rp_o, int* __restrict__ rp_s,
    int2* __restrict__ ev_o, int2* __restrict__ ev_s, int N)
{
    const int g = blockIdx.y;
    const int2* temp = g ? temp_s : temp_o;
    int2* ev = g ? ev_s : ev_o;
    int* rp = g ? rp_s : rp_o;
    const int* bb = bbase + g * 257;

    __shared__ int lcnt[512];
    __shared__ int lpre[512];
    const int b = blockIdx.x;
    const int r0 = b << BSHIFT;
    const int t = threadIdx.x;
    const int e0 = bb[b];                      // final CSR base
    const int cntE = bb[b + 1] - e0;           // edges in bucket
    const int t0 = b * TEMPCAP;                // temp base

    lcnt[t] = 0;
    __syncthreads();
    for (int i = t; i < cntE; i += 512)
        atomicAdd(&lcnt[temp[t0 + i].x & 511], 1);
    __syncthreads();
    const int v = lcnt[t];
    lpre[t] = v;
    __syncthreads();
    for (int off = 1; off < 512; off <<= 1) {
        int u = (t >= off) ? lpre[t - off] : 0;
        __syncthreads();
        lpre[t] += u;
        __syncthreads();
    }
    const int base = e0 + lpre[t] - v;
    const int r = r0 + t;
    if (r <= N) rp[r] = base;
    __syncthreads();
    lcnt[t] = base;
    __syncthreads();
    for (int i = t; i < cntE; i += 512) {
        int2 pk = temp[t0 + i];
        int q = atomicAdd(&lcnt[pk.x & 511], 1);
        ev[q] = make_int2(pk.x >> BSHIFT, pk.y);
    }
}

// ---------------------------------------------------------------------------
// Row-set compaction for sparse layer-3 (decoder only reads idx rows).
// ---------------------------------------------------------------------------
__global__ __launch_bounds__(256) void mark_rows(
    const int* __restrict__ idx, int* __restrict__ flag, int n2)
{
    int i = blockIdx.x * 256 + threadIdx.x;
    if (i < n2) flag[idx[i]] = 1;
}

__global__ __launch_bounds__(256) void compact_rows(
    const int* __restrict__ flag, int* __restrict__ rlist,
    int* __restrict__ inv, int* __restrict__ ctr, int N)
{
    int r = blockIdx.x * 256 + threadIdx.x;
    if (r < N && flag[r]) {
        int i = atomicAdd(ctr, 1);
        rlist[i] = r;
        inv[r] = i;
    }
}

// ---------------------------------------------------------------------------
// Fused MFMA GEMM: S_m = X @ W_m for NM matrices, X staged ONCE (full K) in LDS.
// Block 256 thr / 4 waves over a 2x2 (row-half x col-half) wave grid:
// wave w -> rows (w&1)*32 (m=2 frags), cols (w>>1)*64 (n=4 frags).
// 6 LDS b128 reads per 8 MFMA (was 9:8) -> no longer LDS-read-bound.
// ---------------------------------------------------------------------------
template <int K, int NM, bool XBF>
__global__ __launch_bounds__(256) void gemm_fused(
    const void* __restrict__ Xv,
    const unsigned short* __restrict__ Wt0, unsigned short* __restrict__ S0,
    const unsigned short* __restrict__ Wt1, unsigned short* __restrict__ S1,
    const unsigned short* __restrict__ Wt2, unsigned short* __restrict__ S2,
    int Nrows)
{
    constexpr int AST = K + 8;
    __shared__ unsigned short As[64 * AST];
    __shared__ unsigned short Bs[128 * 72];

    const int t = threadIdx.x;
    const int l = t & 63;
    const int w = t >> 6;
    const int row_in = l & 15;
    const int kgrp = l >> 4;        // 0..3
    const int rhalf = w & 1;        // row half -> rows rhalf*32..rhalf*32+31
    const int chalf = w >> 1;       // col half -> cols chalf*64..chalf*64+63
    const int row0 = blockIdx.x * 64;

    {
        constexpr int QPR = K / 4;
        #pragma unroll
        for (int it = 0; it < 64 * QPR / 256; ++it) {
            int i = t + it * 256;
            int r = i / QPR, c4 = i % QPR;
            int gr = row0 + r;
            if (XBF) {
                ushort4 v = make_ushort4(0, 0, 0, 0);
                if (gr < Nrows)
                    v = *(const ushort4*)((const unsigned short*)Xv + (size_t)gr * K + c4 * 4);
                *(ushort4*)&As[r * AST + c4 * 4] = v;
            } else {
                float4 v = make_float4(0.f, 0.f, 0.f, 0.f);
                if (gr < Nrows)
                    v = *(const float4*)((const float*)Xv + (size_t)gr * K + c4 * 4);
                ushort4 b4;
                b4.x = f2bf(v.x); b4.y = f2bf(v.y); b4.z = f2bf(v.z); b4.w = f2bf(v.w);
                *(ushort4*)&As[r * AST + c4 * 4] = b4;
            }
        }
    }

    #pragma unroll
    for (int m = 0; m < NM; ++m) {
        const unsigned short* Wt = (m == 0) ? Wt0 : ((m == 1) ? Wt1 : Wt2);
        unsigned short* S = (m == 0) ? S0 : ((m == 1) ? S1 : S2);
        float4v acc[2][4];
        #pragma unroll
        for (int mi = 0; mi < 2; ++mi)
            #pragma unroll
            for (int n = 0; n < 4; ++n) acc[mi][n] = (float4v)(0.f);

        for (int kt = 0; kt < K / 64; ++kt) {
            __syncthreads();
            #pragma unroll
            for (int it = 0; it < 8; ++it) {
                int i = t + it * 256;
                int r = i >> 4, c4 = i & 15;
                *(ushort4*)&Bs[r * 72 + c4 * 4] =
                    *(const ushort4*)(Wt + (size_t)r * K + kt * 64 + c4 * 4);
            }
            __syncthreads();
            #pragma unroll
            for (int kc = 0; kc < 2; ++kc) {
                short8v a[2], b[4];
                #pragma unroll
                for (int mi = 0; mi < 2; ++mi) {
                    const unsigned short* pa =
                        &As[(rhalf * 32 + mi * 16 + row_in) * AST + kt * 64 + kc * 32 + kgrp * 8];
                    ((uint2*)&a[mi])[0] = *(const uint2*)pa;
                    ((uint2*)&a[mi])[1] = *(const uint2*)(pa + 4);
                }
                #pragma unroll
                for (int n = 0; n < 4; ++n) {
                    const unsigned short* pb =
                        &Bs[(chalf * 64 + n * 16 + row_in) * 72 + kc * 32 + kgrp * 8];
                    ((uint2*)&b[n])[0] = *(const uint2*)pb;
                    ((uint2*)&b[n])[1] = *(const uint2*)(pb + 4);
                }
                #pragma unroll
                for (int mi = 0; mi < 2; ++mi)
                    #pragma unroll
                    for (int n = 0; n < 4; ++n)
                        acc[mi][n] = __builtin_amdgcn_mfma_f32_16x16x32_bf16(
                            a[mi], b[n], acc[mi][n], 0, 0, 0);
            }
        }
        #pragma unroll
        for (int mi = 0; mi < 2; ++mi)
            #pragma unroll
            for (int n = 0; n < 4; ++n)
                #pragma unroll
                for (int r = 0; r < 4; ++r) {
                    int gr = row0 + rhalf * 32 + mi * 16 + kgrp * 4 + r;
                    int gc = chalf * 64 + n * 16 + row_in;
                    if (gr < Nrows) S[(size_t)gr * 128 + gc] = f2bf(acc[mi][n][r]);
                }
    }
}

// ---------------------------------------------------------------------------
// Fused dual-graph CSR SpMM, interleaved A/B gather streams (4+4 per iter).
// One wave per row; lane l owns features 2l, 2l+1. Tables bf16.
// SPARSE: row list indirection, compact output indexing.
// ---------------------------------------------------------------------------
#define GA(pk) (*(const unsigned*)(Sa + ((size_t)(pk).x << 7) + l2))
#define GB(pk) (*(const unsigned*)(Sb + ((size_t)(pk).x << 7) + l2))
#define ACC(pk, uu) { float vv = __int_as_float((pk).y); \
    ax = fmaf(vv, asf((uu) << 16), ax); ay = fmaf(vv, asf((uu) & 0xffff0000u), ay); }

template <bool OBF, bool SPARSE>
__global__ __launch_bounds__(256) void spmm2_csr(
    const int* __restrict__ rp_a, const int2* __restrict__ ev_a,
    const unsigned short* __restrict__ Sa,
    const int* __restrict__ rp_b, const int2* __restrict__ ev_b,
    const unsigned short* __restrict__ Sb,
    const float* __restrict__ b1, const float* __restrict__ b2,
    void* __restrict__ outv, int N, int do_relu,
    const int* __restrict__ rlist, const int* __restrict__ pcnt)
{
    const int gi = blockIdx.x * 4 + (threadIdx.x >> 6);
    int row;
    if (SPARSE) {
        if (gi >= *pcnt) return;
        row = rlist[gi];
    } else {
        if (gi >= N) return;
        row = gi;
    }
    const int l2 = (threadIdx.x & 63) << 1;

    float2 bv1 = *(const float2*)(b1 + l2);
    float2 bv2 = *(const float2*)(b2 + l2);
    float ax = bv1.x + bv2.x;
    float ay = bv1.y + bv2.y;

    int eA = rp_a[row]; const int eA1 = rp_a[row + 1];
    int eB = rp_b[row]; const int eB1 = rp_b[row + 1];

    while (eA + 4 <= eA1 && eB + 4 <= eB1) {
        const int2 a0 = ev_a[eA], a1 = ev_a[eA + 1], a2 = ev_a[eA + 2], a3 = ev_a[eA + 3];
        const int2 c0 = ev_b[eB], c1 = ev_b[eB + 1], c2 = ev_b[eB + 2], c3 = ev_b[eB + 3];
        const unsigned u0 = GA(a0), u1 = GA(a1), u2 = GA(a2), u3 = GA(a3);
        const unsigned w0 = GB(c0), w1 = GB(c1), w2 = GB(c2), w3 = GB(c3);
        ACC(a0, u0) ACC(a1, u1) ACC(a2, u2) ACC(a3, u3)
        ACC(c0, w0) ACC(c1, w1) ACC(c2, w2) ACC(c3, w3)
        eA += 4; eB += 4;
    }
    for (; eA + 8 <= eA1; eA += 8) {
        const int2 a0 = ev_a[eA], a1 = ev_a[eA + 1], a2 = ev_a[eA + 2], a3 = ev_a[eA + 3];
        const int2 a4 = ev_a[eA + 4], a5 = ev_a[eA + 5], a6 = ev_a[eA + 6], a7 = ev_a[eA + 7];
        const unsigned u0 = GA(a0), u1 = GA(a1), u2 = GA(a2), u3 = GA(a3);
        const unsigned u4 = GA(a4), u5 = GA(a5), u6 = GA(a6), u7 = GA(a7);
        ACC(a0, u0) ACC(a1, u1) ACC(a2, u2) ACC(a3, u3)
        ACC(a4, u4) ACC(a5, u5) ACC(a6, u6) ACC(a7, u7)
    }
    for (; eA + 4 <= eA1; eA += 4) {
        const int2 a0 = ev_a[eA], a1 = ev_a[eA + 1], a2 = ev_a[eA + 2], a3 = ev_a[eA + 3];
        const unsigned u0 = GA(a0), u1 = GA(a1), u2 = GA(a2), u3 = GA(a3);
        ACC(a0, u0) ACC(a1, u1) ACC(a2, u2) ACC(a3, u3)
    }
    for (; eA < eA1; ++eA) {
        const int2 a0 = ev_a[eA];
        const unsigned u0 = GA(a0);
        ACC(a0, u0)
    }
    for (; eB + 8 <= eB1; eB += 8) {
        const int2 c0 = ev_b[eB], c1 = ev_b[eB + 1], c2 = ev_b[eB + 2], c3 = ev_b[eB + 3];
        const int2 c4 = ev_b[eB + 4], c5 = ev_b[eB + 5], c6 = ev_b[eB + 6], c7 = ev_b[eB + 7];
        const unsigned w0 = GB(c0), w1 = GB(c1), w2 = GB(c2), w3 = GB(c3);
        const unsigned w4 = GB(c4), w5 = GB(c5), w6 = GB(c6), w7 = GB(c7);
        ACC(c0, w0) ACC(c1, w1) ACC(c2, w2) ACC(c3, w3)
        ACC(c4, w4) ACC(c5, w5) ACC(c6, w6) ACC(c7, w7)
    }
    for (; eB + 4 <= eB1; eB += 4) {
        const int2 c0 = ev_b[eB], c1 = ev_b[eB + 1], c2 = ev_b[eB + 2], c3 = ev_b[eB + 3];
        const unsigned w0 = GB(c0), w1 = GB(c1), w2 = GB(c2), w3 = GB(c3);
        ACC(c0, w0) ACC(c1, w1) ACC(c2, w2) ACC(c3, w3)
    }
    for (; eB < eB1; ++eB) {
        const int2 c0 = ev_b[eB];
        const unsigned w0 = GB(c0);
        ACC(c0, w0)
    }

    if (do_relu) { ax = fmaxf(ax, 0.f); ay = fmaxf(ay, 0.f); }
    const size_t oidx = SPARSE ? (size_t)gi : (size_t)row;
    if (OBF) {
        unsigned pk = (unsigned)f2bf(ax) | ((unsigned)f2bf(ay) << 16);
        ((unsigned*)outv)[(oidx << 6) + (l2 >> 1)] = pk;
    } else {
        float2 o; o.x = ax; o.y = ay;
        *(float2*)((float*)outv + (oidx << 7) + l2) = o;
    }
}
#undef GA
#undef GB
#undef ACC

// ---------------------------------------------------------------------------
// Fused decoder: o1 tile stays in LDS between the two small GEMMs.
// out[b] = (concat(h[inv[i0]], h[inv[i1]]) @ Wd1 + bd1) @ Wd2 + bd2
// ---------------------------------------------------------------------------
__global__ __launch_bounds__(128) void dec_fused(
    const float* __restrict__ h, const int* __restrict__ inv,
    const int* __restrict__ idx0, const int* __restrict__ idx1,
    const float* __restrict__ Wd1, const float* __restrict__ bd1,
    const float* __restrict__ Wd2, const float* __restrict__ bd2,
    float* __restrict__ out, int B)
{
    __shared__ __align__(16) float fs[16 * 256];
    __shared__ __align__(16) float os[16 * 128];
    const int t = threadIdx.x;
    const int b0 = blockIdx.x * 16;
    #pragma unroll
    for (int r = 0; r < 16; ++r) {
        const int b = b0 + r;
        fs[r * 256 + t]       = h[(long)inv[idx0[b]] * 128 + t];
        fs[r * 256 + 128 + t] = h[(long)inv[idx1[b]] * 128 + t];
    }
    __syncthreads();

    {
        const float4* fs4 = (const float4*)fs;
        float acc[16];
        #pragma unroll
        for (int r = 0; r < 16; ++r) acc[r] = 0.f;
        for (int kc = 0; kc < 64; ++kc) {
            const float w0 = Wd1[(kc * 4 + 0) * 128 + t];
            const float w1 = Wd1[(kc * 4 + 1) * 128 + t];
            const float w2 = Wd1[(kc * 4 + 2) * 128 + t];
            const float w3 = Wd1[(kc * 4 + 3) * 128 + t];
            #pragma unroll
            for (int r = 0; r < 16; ++r) {
                const float4 xv = fs4[r * 64 + kc];
                acc[r] = fmaf(xv.x, w0, acc[r]);
                acc[r] = fmaf(xv.y, w1, acc[r]);
                acc[r] = fmaf(xv.z, w2, acc[r]);
                acc[r] = fmaf(xv.w, w3, acc[r]);
            }
        }
        #pragma unroll
        for (int r = 0; r < 16; ++r)
            os[r * 128 + t] = acc[r] + bd1[t];
    }
    __syncthreads();

    {
        const float4* os4 = (const float4*)os;
        float acc[16];
        #pragma unroll
        for (int r = 0; r < 16; ++r) acc[r] = 0.f;
        const bool act = (t < RELL);
        for (int kc = 0; kc < 32; ++kc) {
            const float w0 = act ? Wd2[(kc * 4 + 0) * RELL + t] : 0.f;
            const float w1 = act ? Wd2[(kc * 4 + 1) * RELL + t] : 0.f;
            const float w2 = act ? Wd2[(kc * 4 + 2) * RELL + t] : 0.f;
            const float w3 = act ? Wd2[(kc * 4 + 3) * RELL + t] : 0.f;
            #pragma unroll
            for (int r = 0; r < 16; ++r) {
                const float4 xv = os4[r * 32 + kc];
                acc[r] = fmaf(xv.x, w0, acc[r]);
                acc[r] = fmaf(xv.y, w1, acc[r]);
                acc[r] = fmaf(xv.z, w2, acc[r]);
                acc[r] = fmaf(xv.w, w3, acc[r]);
            }
        }
        if (act) {
            #pragma unroll
            for (int r = 0; r < 16; ++r)
                out[(long)(b0 + r) * RELL + t] = acc[r] + bd2[t];
        }
    }
}

extern "C" void kernel_launch(void* const* d_in, const int* in_sizes, int n_in,
                              void* d_out, int out_size, void* d_ws, size_t ws_size,
                              hipStream_t stream) {
    const float* x      = (const float*)d_in[0];
    const int*   o_rows = (const int*)  d_in[1];
    const int*   o_cols = (const int*)  d_in[2];
    const float* o_vals = (const float*)d_in[3];
    const int*   s_rows = (const int*)  d_in[4];
    const int*   s_cols = (const int*)  d_in[5];
    const float* s_vals = (const float*)d_in[6];
    const int*   idx    = (const int*)  d_in[7];
    const float* W_ogc1  = (const float*)d_in[8];   const float* b_ogc1  = (const float*)d_in[9];
    const float* W_sgc1o = (const float*)d_in[10];  const float* b_sgc1o = (const float*)d_in[11];
    const float* W_sgc1  = (const float*)d_in[12];  const float* b_sgc1  = (const float*)d_in[13];
    const float* W_ogc1s = (const float*)d_in[14];  const float* b_ogc1s = (const float*)d_in[15];
    const float* W_ogc2  = (const float*)d_in[16];  const float* b_ogc2  = (const float*)d_in[17];
    const float* W_sgc2o = (const float*)d_in[18];  const float* b_sgc2o = (const float*)d_in[19];
    const float* W_dec1  = (const float*)d_in[20];  const float* b_dec1  = (const float*)d_in[21];
    const float* W_dec2  = (const float*)d_in[22];  const float* b_dec2  = (const float*)d_in[23];

    const int N = in_sizes[0] / NFEAT;   // 100000
    const int E = in_sizes[1];           // 1600000
    const int B = in_sizes[7] / 2;       // 16384
    const int* idx0 = idx;
    const int* idx1 = idx + B;

    // ---- workspace layout (float units) ----
    float* p = (float*)d_ws;
    const size_t N64 = (size_t)N * 64;    // one bf16 [N,128] table in float units
    float* h    = p;  p += (size_t)N * 128;          // compact fp32 [<=2B,128]
    unsigned short* oxb  = (unsigned short*)p; p += N64;   // o_x bf16
    unsigned short* sxb  = (unsigned short*)p; p += N64;   // s_x bf16
    unsigned short* tabA = (unsigned short*)p; p += N64;
    unsigned short* tabB = (unsigned short*)p; p += N64;
    unsigned short* tabC = (unsigned short*)p; p += N64;
    unsigned short* tabD = (unsigned short*)p; p += N64;
    unsigned short* wt1 = (unsigned short*)p; p += 16384;   // [128,256] bf16
    unsigned short* wt2 = (unsigned short*)p; p += 16384;
    unsigned short* wt3 = (unsigned short*)p; p += 16384;
    unsigned short* wt4 = (unsigned short*)p; p += 8192;    // [128,128] bf16
    unsigned short* wt5 = (unsigned short*)p; p += 8192;
    unsigned short* wt6 = (unsigned short*)p; p += 8192;
    int* rp_o = (int*)p; p += (size_t)N + 2;
    int* rp_s = (int*)p; p += (size_t)N + 2;
    int2* ev_o = (int2*)p; p += 2 * (size_t)E;
    int2* ev_s = (int2*)p; p += 2 * (size_t)E;
    int* bbase = (int*)p; p += 516;                  // [2][257] bucket bases
    int* bcur  = (int*)p; p += 512;                  // [2][256] bucket cursors
    int* flag  = (int*)p; p += (size_t)N;            // needed-row flags
    int* rlist = (int*)p; p += (size_t)N;            // compact row list
    int* inv   = (int*)p; p += (size_t)N;            // node -> compact index
    int* ctr   = (int*)p; p += 2;                    // compact count
    // temp binning buffers alias tabA/tabB (dead until first GEMM)
    int2* temp_o = (int2*)tabA;                      // 256*TEMPCAP int2 = 25.2 MB
    int2* temp_s = (int2*)tabB;

    const int gM64 = (N + 63) / 64;       // 1563
    const int gR = (N + 3) / 4;           // 25000
    const int gRs = (2 * B + 3) / 4;      // 8192 (sparse rows <= 2B)
    const int gB = B / 16;                // 1024
    const int gT = (E + SCAT_TILE - 1) / SCAT_TILE;                   // 196
    const int gBuck = (N + (1 << BSHIFT) - 1) >> BSHIFT;              // 196

    // ---- CSR build (both graphs via y-grid), no pre-count pass
    hipMemsetAsync(flag, 0, (size_t)N * sizeof(int), stream);
    hipMemsetAsync(ctr, 0, sizeof(int), stream);
    binit2<<<1, 512, 0, stream>>>(bcur);
    binscat1<<<dim3(gT, 2), 256, 0, stream>>>(o_rows, o_cols, o_vals,
                                              s_rows, s_cols, s_vals,
                                              bcur, temp_o, temp_s, E);
    bucket_scan2<<<1, 256, 0, stream>>>(bcur, bbase, E);
    binscat2<<<dim3(gBuck, 2), 512, 0, stream>>>(bbase, bcur, temp_o, temp_s,
                                                 rp_o, rp_s, ev_o, ev_s, N);

    // ---- needed-row compaction for layer 3
    mark_rows<<<(2 * B + 255) / 256, 256, 0, stream>>>(idx, flag, 2 * B);
    compact_rows<<<(N + 255) / 256, 256, 0, stream>>>(flag, rlist, inv, ctr, N);

    // ---- weight prep (all 6 in one launch)
    wt_prep6<<<dim3(128, 6), 256, 0, stream>>>(W_ogc1, W_sgc1o, W_sgc1,
                                               W_ogc1s, W_ogc2, W_sgc2o,
                                               wt1, wt2, wt3, wt4, wt5, wt6);

    // ---- Layer 1 GEMMs (x read once): tabA=x@W_ogc1, tabB=x@W_sgc1o, tabC=x@W_sgc1
    gemm_fused<NFEAT, 3, false><<<gM64, 256, 0, stream>>>(
        x, wt1, tabA, wt2, tabB, wt3, tabC, N);
    spmm2_csr<true, false><<<gR, 256, 0, stream>>>(
        rp_o, ev_o, tabA, rp_s, ev_s, tabB,
        b_ogc1, b_sgc1o, oxb, N, 1, nullptr, nullptr);     // o_x

    // ---- Layer 2+3a GEMMs (oxb read once): tabD = o_x@W_ogc1s, tabA = o_x@W_ogc2
    gemm_fused<NHID, 2, true><<<gM64, 256, 0, stream>>>(
        oxb, wt4, tabD, wt5, tabA, nullptr, nullptr, N);
    spmm2_csr<true, false><<<gR, 256, 0, stream>>>(
        rp_o, ev_o, tabD, rp_s, ev_s, tabC,
        b_ogc1s, b_sgc1, sxb, N, 1, nullptr, nullptr);     // s_x

    // ---- Layer 3b GEMM: tabB = s_x@W_sgc2o; sparse spmm -> compact h
    gemm_fused<NHID, 1, true><<<gM64, 256, 0, stream>>>(
        sxb, wt6, tabB, nullptr, nullptr, nullptr, nullptr, N);
    spmm2_csr<false, true><<<gRs, 256, 0, stream>>>(
        rp_o, ev_o, tabA, rp_s, ev_s, tabB,
        b_ogc2, b_sgc2o, h, N, 0, rlist, ctr);             // compact h

    // ---- Fused decoder
    dec_fused<<<gB, 128, 0, stream>>>(h, inv, idx0, idx1,
                                      W_dec1, b_dec1, W_dec2, b_dec2,
                                      (float*)d_out, B);
}

// Round 12
// 569.359 us; speedup vs baseline: 8.9313x; 1.0449x over previous
//
#include <hip/hip_runtime.h>
#include <hip/hip_bf16.h>

#define NFEAT 256
#define NHID 128
#define RELL 86
#define BSHIFT 9                 // bucket = row >> 9 (512 rows)
#define SCAT_TILE 8192           // edges per binscat block (32/thread)
#define TEMPCAP 12288            // per-bucket temp capacity (mean 8163, max ~8600)

typedef __attribute__((ext_vector_type(8))) short short8v;
typedef __attribute__((ext_vector_type(4))) float float4v;

static __device__ __forceinline__ unsigned short f2bf(float f) {
    union { float f; unsigned int u; } v; v.f = f;
    unsigned int r = v.u + 0x7FFF + ((v.u >> 16) & 1);   // RNE
    return (unsigned short)(r >> 16);
}
static __device__ __forceinline__ float asf(unsigned int u) {
    union { unsigned int u; float f; } v; v.u = u; return v.f;
}

// ---------------------------------------------------------------------------
// Init + weight prep mega-kernel: y<6 -> wt_prep for matrix y;
// y==6 -> zero flag, init bucket cursors, zero compact counter.
// ---------------------------------------------------------------------------
__global__ __launch_bounds__(256) void init_prep(
    const float* __restrict__ W0, const float* __restrict__ W1,
    const float* __restrict__ W2, const float* __restrict__ W3,
    const float* __restrict__ W4, const float* __restrict__ W5,
    unsigned short* __restrict__ T0, unsigned short* __restrict__ T1,
    unsigned short* __restrict__ T2, unsigned short* __restrict__ T3,
    unsigned short* __restrict__ T4, unsigned short* __restrict__ T5,
    int* __restrict__ bcur, int* __restrict__ flag, int* __restrict__ ctr,
    int N)
{
    const int y = blockIdx.y;
    if (y < 6) {
        const int K = (y < 3) ? NFEAT : NHID;
        const float* W = (y == 0) ? W0 : (y == 1) ? W1 : (y == 2) ? W2
                       : (y == 3) ? W3 : (y == 4) ? W4 : W5;
        unsigned short* T = (y == 0) ? T0 : (y == 1) ? T1 : (y == 2) ? T2
                          : (y == 3) ? T3 : (y == 4) ? T4 : T5;
        int i = blockIdx.x * 256 + threadIdx.x;
        if (i < K * 128) {
            int col = i & 127, k = i >> 7;
            T[col * K + k] = f2bf(W[i]);
        }
        return;
    }
    // y == 6: housekeeping
    const int i = blockIdx.x * 256 + threadIdx.x;
    if (i < N) flag[i] = 0;
    if (blockIdx.x == 0) {
        const int t = threadIdx.x;
        bcur[t] = t * TEMPCAP;           // graph o cursors
        bcur[256 + t] = t * TEMPCAP;     // graph s cursors
        if (t == 0) ctr[0] = 0;
    }
}

// ---------------------------------------------------------------------------
// Phase 1: bin edges by row>>9 into fixed-capacity temp slots,
// packed (row&511 | col<<9, val_bits).
// ---------------------------------------------------------------------------
__global__ __launch_bounds__(256) void binscat1(
    const int* __restrict__ ro, const int* __restrict__ co,
    const float* __restrict__ vo,
    const int* __restrict__ rs, const int* __restrict__ cs,
    const float* __restrict__ vs,
    int* __restrict__ bcur, int2* __restrict__ temp_o,
    int2* __restrict__ temp_s, int E)
{
    const int g = blockIdx.y;
    const int* rows = g ? rs : ro;
    const int* cols = g ? cs : co;
    const float* vals = g ? vs : vo;
    int* bc = bcur + g * 256;
    int2* temp = g ? temp_s : temp_o;

    __shared__ int hist[256];
    __shared__ int base[256];
    const int t = threadIdx.x;
    hist[t] = 0;
    __syncthreads();

    const int e0 = blockIdx.x * SCAT_TILE;
    int myrow[32];
    #pragma unroll
    for (int i = 0; i < 32; ++i) {
        int e = e0 + i * 256 + t;
        int r = (e < E) ? rows[e] : -1;
        myrow[i] = r;
        if (r >= 0) atomicAdd(&hist[r >> BSHIFT], 1);
    }
    __syncthreads();
    const int h = hist[t];
    if (h > 0) base[t] = atomicAdd(&bc[t], h);
    __syncthreads();
    hist[t] = (h > 0) ? base[t] : 0;     // reuse hist as within-block cursor
    __syncthreads();
    #pragma unroll
    for (int i = 0; i < 32; ++i) {
        const int r = myrow[i];
        if (r >= 0) {
            int e = e0 + i * 256 + t;
            int off = atomicAdd(&hist[r >> BSHIFT], 1);
            temp[off] = make_int2((r & 511) | (cols[e] << BSHIFT),
                                  __float_as_int(vals[e]));
        }
    }
}

// ---------------------------------------------------------------------------
// block 0: bucket-base scan from end cursors (count = bcur[b] - b*TEMPCAP).
// blocks 1..: mark needed rows from idx.
// ---------------------------------------------------------------------------
__global__ __launch_bounds__(512) void scan_mark(
    const int* __restrict__ bcur, int* __restrict__ bbase,
    const int* __restrict__ idx, int* __restrict__ flag, int E, int n2)
{
    if (blockIdx.x == 0) {
        __shared__ int sh[256];
        const int t = threadIdx.x;
        for (int g = 0; g < 2; ++g) {
            int v = 0;
            if (t < 256) { v = bcur[g * 256 + t] - t * TEMPCAP; sh[t] = v; }
            __syncthreads();
            for (int off = 1; off < 256; off <<= 1) {
                int u = (t < 256 && t >= off) ? sh[t - off] : 0;
                __syncthreads();
                if (t < 256) sh[t] += u;
                __syncthreads();
            }
            if (t < 256) {
                bbase[g * 257 + t] = sh[t] - v;   // exclusive
                if (t == 255) bbase[g * 257 + 256] = E;
            }
            __syncthreads();
        }
    } else {
        int i = (blockIdx.x - 1) * 512 + threadIdx.x;
        if (i < n2) flag[idx[i]] = 1;
    }
}

// ---------------------------------------------------------------------------
// y<2: per-bucket local counting sort (single temp read; edges staged in
// registers via static unroll). Writes rp + final CSR ev.
// y==2: compact marked rows -> rlist/inv/ctr.
// ---------------------------------------------------------------------------
__global__ __launch_bounds__(512) void bs2_compact(
    const int* __restrict__ bbase,
    const int2* __restrict__ temp_o, const int2* __restrict__ temp_s,
    int* __restrict__ rp_o, int* __restrict__ rp_s,
    int2* __restrict__ ev_o, int2* __restrict__ ev_s,
    const int* __restrict__ flag, int* __restrict__ rlist,
    int* __restrict__ inv, int* __restrict__ ctr, int N)
{
    if (blockIdx.y == 2) {
        int r = blockIdx.x * 512 + threadIdx.x;
        if (r < N && flag[r]) {
            int i = atomicAdd(ctr, 1);
            rlist[i] = r;
            inv[r] = i;
        }
        return;
    }
    const int g = blockIdx.y;
    const int2* temp = g ? temp_s : temp_o;
    int2* ev = g ? ev_s : ev_o;
    int* rp = g ? rp_s : rp_o;
    const int* bb = bbase + g * 257;

    __shared__ int lcnt[512];
    __shared__ int lpre[512];
    const int b = blockIdx.x;
    const int r0 = b << BSHIFT;
    const int t = threadIdx.x;
    const int e0 = bb[b];                      // final CSR base
    const int cntE = bb[b + 1] - e0;           // edges in bucket (<= TEMPCAP)
    const int t0 = b * TEMPCAP;                // temp base

    int2 myed[24];                             // 24*512 = TEMPCAP
    lcnt[t] = 0;
    __syncthreads();
    #pragma unroll
    for (int i = 0; i < 24; ++i) {
        int k = i * 512 + t;
        int2 pk = make_int2(0, 0);
        if (k < cntE) {
            pk = temp[t0 + k];
            atomicAdd(&lcnt[pk.x & 511], 1);
        }
        myed[i] = pk;
    }
    __syncthreads();
    const int v = lcnt[t];
    lpre[t] = v;
    __syncthreads();
    for (int off = 1; off < 512; off <<= 1) {
        int u = (t >= off) ? lpre[t - off] : 0;
        __syncthreads();
        lpre[t] += u;
        __syncthreads();
    }
    const int base = e0 + lpre[t] - v;
    const int r = r0 + t;
    if (r <= N) rp[r] = base;
    __syncthreads();
    lcnt[t] = base;                            // row cursors
    __syncthreads();
    #pragma unroll
    for (int i = 0; i < 24; ++i) {
        int k = i * 512 + t;
        if (k < cntE) {
            int2 pk = myed[i];
            int q = atomicAdd(&lcnt[pk.x & 511], 1);
            ev[q] = make_int2(pk.x >> BSHIFT, pk.y);
        }
    }
}

// ---------------------------------------------------------------------------
// Fused MFMA GEMM: S_m = X @ W_m for NM matrices, X staged ONCE (full K) in LDS.
// 4 waves over a 2x2 (row-half x col-half) grid: 6 LDS b128 reads per 8 MFMA.
// ---------------------------------------------------------------------------
template <int K, int NM, bool XBF>
__global__ __launch_bounds__(256) void gemm_fused(
    const void* __restrict__ Xv,
    const unsigned short* __restrict__ Wt0, unsigned short* __restrict__ S0,
    const unsigned short* __restrict__ Wt1, unsigned short* __restrict__ S1,
    const unsigned short* __restrict__ Wt2, unsigned short* __restrict__ S2,
    int Nrows)
{
    constexpr int AST = K + 8;
    __shared__ unsigned short As[64 * AST];
    __shared__ unsigned short Bs[128 * 72];

    const int t = threadIdx.x;
    const int l = t & 63;
    const int w = t >> 6;
    const int row_in = l & 15;
    const int kgrp = l >> 4;        // 0..3
    const int rhalf = w & 1;
    const int chalf = w >> 1;
    const int row0 = blockIdx.x * 64;

    {
        constexpr int QPR = K / 4;
        #pragma unroll
        for (int it = 0; it < 64 * QPR / 256; ++it) {
            int i = t + it * 256;
            int r = i / QPR, c4 = i % QPR;
            int gr = row0 + r;
            if (XBF) {
                ushort4 v = make_ushort4(0, 0, 0, 0);
                if (gr < Nrows)
                    v = *(const ushort4*)((const unsigned short*)Xv + (size_t)gr * K + c4 * 4);
                *(ushort4*)&As[r * AST + c4 * 4] = v;
            } else {
                float4 v = make_float4(0.f, 0.f, 0.f, 0.f);
                if (gr < Nrows)
                    v = *(const float4*)((const float*)Xv + (size_t)gr * K + c4 * 4);
                ushort4 b4;
                b4.x = f2bf(v.x); b4.y = f2bf(v.y); b4.z = f2bf(v.z); b4.w = f2bf(v.w);
                *(ushort4*)&As[r * AST + c4 * 4] = b4;
            }
        }
    }

    #pragma unroll
    for (int m = 0; m < NM; ++m) {
        const unsigned short* Wt = (m == 0) ? Wt0 : ((m == 1) ? Wt1 : Wt2);
        unsigned short* S = (m == 0) ? S0 : ((m == 1) ? S1 : S2);
        float4v acc[2][4];
        #pragma unroll
        for (int mi = 0; mi < 2; ++mi)
            #pragma unroll
            for (int n = 0; n < 4; ++n) acc[mi][n] = (float4v)(0.f);

        for (int kt = 0; kt < K / 64; ++kt) {
            __syncthreads();
            #pragma unroll
            for (int it = 0; it < 8; ++it) {
                int i = t + it * 256;
                int r = i >> 4, c4 = i & 15;
                *(ushort4*)&Bs[r * 72 + c4 * 4] =
                    *(const ushort4*)(Wt + (size_t)r * K + kt * 64 + c4 * 4);
            }
            __syncthreads();
            #pragma unroll
            for (int kc = 0; kc < 2; ++kc) {
                short8v a[2], b[4];
                #pragma unroll
                for (int mi = 0; mi < 2; ++mi) {
                    const unsigned short* pa =
                        &As[(rhalf * 32 + mi * 16 + row_in) * AST + kt * 64 + kc * 32 + kgrp * 8];
                    ((uint2*)&a[mi])[0] = *(const uint2*)pa;
                    ((uint2*)&a[mi])[1] = *(const uint2*)(pa + 4);
                }
                #pragma unroll
                for (int n = 0; n < 4; ++n) {
                    const unsigned short* pb =
                        &Bs[(chalf * 64 + n * 16 + row_in) * 72 + kc * 32 + kgrp * 8];
                    ((uint2*)&b[n])[0] = *(const uint2*)pb;
                    ((uint2*)&b[n])[1] = *(const uint2*)(pb + 4);
                }
                #pragma unroll
                for (int mi = 0; mi < 2; ++mi)
                    #pragma unroll
                    for (int n = 0; n < 4; ++n)
                        acc[mi][n] = __builtin_amdgcn_mfma_f32_16x16x32_bf16(
                            a[mi], b[n], acc[mi][n], 0, 0, 0);
            }
        }
        #pragma unroll
        for (int mi = 0; mi < 2; ++mi)
            #pragma unroll
            for (int n = 0; n < 4; ++n)
                #pragma unroll
                for (int r = 0; r < 4; ++r) {
                    int gr = row0 + rhalf * 32 + mi * 16 + kgrp * 4 + r;
                    int gc = chalf * 64 + n * 16 + row_in;
                    if (gr < Nrows) S[(size_t)gr * 128 + gc] = f2bf(acc[mi][n][r]);
                }
    }
}

// ---------------------------------------------------------------------------
// Fused dual-graph CSR SpMM, interleaved A/B gather streams (4+4 per iter).
// One wave per row; lane l owns features 2l, 2l+1. Tables bf16.
// SPARSE: row list indirection, compact output indexing.
// ---------------------------------------------------------------------------
#define GA(pk) (*(const unsigned*)(Sa + ((size_t)(pk).x << 7) + l2))
#define GB(pk) (*(const unsigned*)(Sb + ((size_t)(pk).x << 7) + l2))
#define ACC(pk, uu) { float vv = __int_as_float((pk).y); \
    ax = fmaf(vv, asf((uu) << 16), ax); ay = fmaf(vv, asf((uu) & 0xffff0000u), ay); }

template <bool OBF, bool SPARSE>
__global__ __launch_bounds__(256) void spmm2_csr(
    const int* __restrict__ rp_a, const int2* __restrict__ ev_a,
    const unsigned short* __restrict__ Sa,
    const int* __restrict__ rp_b, const int2* __restrict__ ev_b,
    const unsigned short* __restrict__ Sb,
    const float* __restrict__ b1, const float* __restrict__ b2,
    void* __restrict__ outv, int N, int do_relu,
    const int* __restrict__ rlist, const int* __restrict__ pcnt)
{
    const int gi = blockIdx.x * 4 + (threadIdx.x >> 6);
    int row;
    if (SPARSE) {
        if (gi >= *pcnt) return;
        row = rlist[gi];
    } else {
        if (gi >= N) return;
        row = gi;
    }
    const int l2 = (threadIdx.x & 63) << 1;

    float2 bv1 = *(const float2*)(b1 + l2);
    float2 bv2 = *(const float2*)(b2 + l2);
    float ax = bv1.x + bv2.x;
    float ay = bv1.y + bv2.y;

    int eA = rp_a[row]; const int eA1 = rp_a[row + 1];
    int eB = rp_b[row]; const int eB1 = rp_b[row + 1];

    while (eA + 4 <= eA1 && eB + 4 <= eB1) {
        const int2 a0 = ev_a[eA], a1 = ev_a[eA + 1], a2 = ev_a[eA + 2], a3 = ev_a[eA + 3];
        const int2 c0 = ev_b[eB], c1 = ev_b[eB + 1], c2 = ev_b[eB + 2], c3 = ev_b[eB + 3];
        const unsigned u0 = GA(a0), u1 = GA(a1), u2 = GA(a2), u3 = GA(a3);
        const unsigned w0 = GB(c0), w1 = GB(c1), w2 = GB(c2), w3 = GB(c3);
        ACC(a0, u0) ACC(a1, u1) ACC(a2, u2) ACC(a3, u3)
        ACC(c0, w0) ACC(c1, w1) ACC(c2, w2) ACC(c3, w3)
        eA += 4; eB += 4;
    }
    for (; eA + 8 <= eA1; eA += 8) {
        const int2 a0 = ev_a[eA], a1 = ev_a[eA + 1], a2 = ev_a[eA + 2], a3 = ev_a[eA + 3];
        const int2 a4 = ev_a[eA + 4], a5 = ev_a[eA + 5], a6 = ev_a[eA + 6], a7 = ev_a[eA + 7];
        const unsigned u0 = GA(a0), u1 = GA(a1), u2 = GA(a2), u3 = GA(a3);
        const unsigned u4 = GA(a4), u5 = GA(a5), u6 = GA(a6), u7 = GA(a7);
        ACC(a0, u0) ACC(a1, u1) ACC(a2, u2) ACC(a3, u3)
        ACC(a4, u4) ACC(a5, u5) ACC(a6, u6) ACC(a7, u7)
    }
    for (; eA + 4 <= eA1; eA += 4) {
        const int2 a0 = ev_a[eA], a1 = ev_a[eA + 1], a2 = ev_a[eA + 2], a3 = ev_a[eA + 3];
        const unsigned u0 = GA(a0), u1 = GA(a1), u2 = GA(a2), u3 = GA(a3);
        ACC(a0, u0) ACC(a1, u1) ACC(a2, u2) ACC(a3, u3)
    }
    for (; eA < eA1; ++eA) {
        const int2 a0 = ev_a[eA];
        const unsigned u0 = GA(a0);
        ACC(a0, u0)
    }
    for (; eB + 8 <= eB1; eB += 8) {
        const int2 c0 = ev_b[eB], c1 = ev_b[eB + 1], c2 = ev_b[eB + 2], c3 = ev_b[eB + 3];
        const int2 c4 = ev_b[eB + 4], c5 = ev_b[eB + 5], c6 = ev_b[eB + 6], c7 = ev_b[eB + 7];
        const unsigned w0 = GB(c0), w1 = GB(c1), w2 = GB(c2), w3 = GB(c3);
        const unsigned w4 = GB(c4), w5 = GB(c5), w6 = GB(c6), w7 = GB(c7);
        ACC(c0, w0) ACC(c1, w1) ACC(c2, w2) ACC(c3, w3)
        ACC(c4, w4) ACC(c5, w5) ACC(c6, w6) ACC(c7, w7)
    }
    for (; eB + 4 <= eB1; eB += 4) {
        const int2 c0 = ev_b[eB], c1 = ev_b[eB + 1], c2 = ev_b[eB + 2], c3 = ev_b[eB + 3];
        const unsigned w0 = GB(c0), w1 = GB(c1), w2 = GB(c2), w3 = GB(c3);
        ACC(c0, w0) ACC(c1, w1) ACC(c2, w2) ACC(c3, w3)
    }
    for (; eB < eB1; ++eB) {
        const int2 c0 = ev_b[eB];
        const unsigned w0 = GB(c0);
        ACC(c0, w0)
    }

    if (do_relu) { ax = fmaxf(ax, 0.f); ay = fmaxf(ay, 0.f); }
    const size_t oidx = SPARSE ? (size_t)gi : (size_t)row;
    if (OBF) {
        unsigned pk = (unsigned)f2bf(ax) | ((unsigned)f2bf(ay) << 16);
        ((unsigned*)outv)[(oidx << 6) + (l2 >> 1)] = pk;
    } else {
        float2 o; o.x = ax; o.y = ay;
        *(float2*)((float*)outv + (oidx << 7) + l2) = o;
    }
}
#undef GA
#undef GB
#undef ACC

// ---------------------------------------------------------------------------
// Fused decoder: o1 tile stays in LDS between the two small GEMMs.
// ---------------------------------------------------------------------------
__global__ __launch_bounds__(128) void dec_fused(
    const float* __restrict__ h, const int* __restrict__ inv,
    const int* __restrict__ idx0, const int* __restrict__ idx1,
    const float* __restrict__ Wd1, const float* __restrict__ bd1,
    const float* __restrict__ Wd2, const float* __restrict__ bd2,
    float* __restrict__ out, int B)
{
    __shared__ __align__(16) float fs[16 * 256];
    __shared__ __align__(16) float os[16 * 128];
    const int t = threadIdx.x;
    const int b0 = blockIdx.x * 16;
    #pragma unroll
    for (int r = 0; r < 16; ++r) {
        const int b = b0 + r;
        fs[r * 256 + t]       = h[(long)inv[idx0[b]] * 128 + t];
        fs[r * 256 + 128 + t] = h[(long)inv[idx1[b]] * 128 + t];
    }
    __syncthreads();

    {
        const float4* fs4 = (const float4*)fs;
        float acc[16];
        #pragma unroll
        for (int r = 0; r < 16; ++r) acc[r] = 0.f;
        for (int kc = 0; kc < 64; ++kc) {
            const float w0 = Wd1[(kc * 4 + 0) * 128 + t];
            const float w1 = Wd1[(kc * 4 + 1) * 128 + t];
            const float w2 = Wd1[(kc * 4 + 2) * 128 + t];
            const float w3 = Wd1[(kc * 4 + 3) * 128 + t];
            #pragma unroll
            for (int r = 0; r < 16; ++r) {
                const float4 xv = fs4[r * 64 + kc];
                acc[r] = fmaf(xv.x, w0, acc[r]);
                acc[r] = fmaf(xv.y, w1, acc[r]);
                acc[r] = fmaf(xv.z, w2, acc[r]);
                acc[r] = fmaf(xv.w, w3, acc[r]);
            }
        }
        #pragma unroll
        for (int r = 0; r < 16; ++r)
            os[r * 128 + t] = acc[r] + bd1[t];
    }
    __syncthreads();

    {
        const float4* os4 = (const float4*)os;
        float acc[16];
        #pragma unroll
        for (int r = 0; r < 16; ++r) acc[r] = 0.f;
        const bool act = (t < RELL);
        for (int kc = 0; kc < 32; ++kc) {
            const float w0 = act ? Wd2[(kc * 4 + 0) * RELL + t] : 0.f;
            const float w1 = act ? Wd2[(kc * 4 + 1) * RELL + t] : 0.f;
            const float w2 = act ? Wd2[(kc * 4 + 2) * RELL + t] : 0.f;
            const float w3 = act ? Wd2[(kc * 4 + 3) * RELL + t] : 0.f;
            #pragma unroll
            for (int r = 0; r < 16; ++r) {
                const float4 xv = os4[r * 32 + kc];
                acc[r] = fmaf(xv.x, w0, acc[r]);
                acc[r] = fmaf(xv.y, w1, acc[r]);
                acc[r] = fmaf(xv.z, w2, acc[r]);
                acc[r] = fmaf(xv.w, w3, acc[r]);
            }
        }
        if (act) {
            #pragma unroll
            for (int r = 0; r < 16; ++r)
                out[(long)(b0 + r) * RELL + t] = acc[r] + bd2[t];
        }
    }
}

extern "C" void kernel_launch(void* const* d_in, const int* in_sizes, int n_in,
                              void* d_out, int out_size, void* d_ws, size_t ws_size,
                              hipStream_t stream) {
    const float* x      = (const float*)d_in[0];
    const int*   o_rows = (const int*)  d_in[1];
    const int*   o_cols = (const int*)  d_in[2];
    const float* o_vals = (const float*)d_in[3];
    const int*   s_rows = (const int*)  d_in[4];
    const int*   s_cols = (const int*)  d_in[5];
    const float* s_vals = (const float*)d_in[6];
    const int*   idx    = (const int*)  d_in[7];
    const float* W_ogc1  = (const float*)d_in[8];   const float* b_ogc1  = (const float*)d_in[9];
    const float* W_sgc1o = (const float*)d_in[10];  const float* b_sgc1o = (const float*)d_in[11];
    const float* W_sgc1  = (const float*)d_in[12];  const float* b_sgc1  = (const float*)d_in[13];
    const float* W_ogc1s = (const float*)d_in[14];  const float* b_ogc1s = (const float*)d_in[15];
    const float* W_ogc2  = (const float*)d_in[16];  const float* b_ogc2  = (const float*)d_in[17];
    const float* W_sgc2o = (const float*)d_in[18];  const float* b_sgc2o = (const float*)d_in[19];
    const float* W_dec1  = (const float*)d_in[20];  const float* b_dec1  = (const float*)d_in[21];
    const float* W_dec2  = (const float*)d_in[22];  const float* b_dec2  = (const float*)d_in[23];

    const int N = in_sizes[0] / NFEAT;   // 100000
    const int E = in_sizes[1];           // 1600000
    const int B = in_sizes[7] / 2;       // 16384
    const int* idx0 = idx;
    const int* idx1 = idx + B;

    // ---- workspace layout (float units) ----
    float* p = (float*)d_ws;
    const size_t N64 = (size_t)N * 64;    // one bf16 [N,128] table in float units
    float* h    = p;  p += (size_t)N * 128;          // compact fp32 [<=2B,128]
    unsigned short* oxb  = (unsigned short*)p; p += N64;   // o_x bf16
    unsigned short* sxb  = (unsigned short*)p; p += N64;   // s_x bf16
    unsigned short* tabA = (unsigned short*)p; p += N64;
    unsigned short* tabB = (unsigned short*)p; p += N64;
    unsigned short* tabC = (unsigned short*)p; p += N64;
    unsigned short* tabD = (unsigned short*)p; p += N64;
    unsigned short* wt1 = (unsigned short*)p; p += 16384;   // [128,256] bf16
    unsigned short* wt2 = (unsigned short*)p; p += 16384;
    unsigned short* wt3 = (unsigned short*)p; p += 16384;
    unsigned short* wt4 = (unsigned short*)p; p += 8192;    // [128,128] bf16
    unsigned short* wt5 = (unsigned short*)p; p += 8192;
    unsigned short* wt6 = (unsigned short*)p; p += 8192;
    int* rp_o = (int*)p; p += (size_t)N + 2;
    int* rp_s = (int*)p; p += (size_t)N + 2;
    int2* ev_o = (int2*)p; p += 2 * (size_t)E;
    int2* ev_s = (int2*)p; p += 2 * (size_t)E;
    int* bbase = (int*)p; p += 516;                  // [2][257] bucket bases
    int* bcur  = (int*)p; p += 512;                  // [2][256] bucket cursors
    int* flag  = (int*)p; p += (size_t)N;            // needed-row flags
    int* rlist = (int*)p; p += (size_t)N;            // compact row list
    int* inv   = (int*)p; p += (size_t)N;            // node -> compact index
    int* ctr   = (int*)p; p += 2;                    // compact count
    // temp binning buffers alias tabA/tabB (dead until first GEMM)
    int2* temp_o = (int2*)tabA;                      // 256*TEMPCAP int2 = 25.2 MB
    int2* temp_s = (int2*)tabB;

    const int gM64 = (N + 63) / 64;       // 1563
    const int gR = (N + 3) / 4;           // 25000
    const int gRs = (2 * B + 3) / 4;      // 8192 (sparse rows <= 2B)
    const int gB = B / 16;                // 1024
    const int gT = (E + SCAT_TILE - 1) / SCAT_TILE;                   // 196
    const int gBuck = (N + (1 << BSHIFT) - 1) >> BSHIFT;              // 196
    const int gFlag = (N + 255) / 256;                                // 391
    const int gMark = (2 * B + 511) / 512;                            // 64

    // ---- init + weight prep (1 launch, replaces 2 memsets + 3 kernels)
    init_prep<<<dim3(gFlag, 7), 256, 0, stream>>>(
        W_ogc1, W_sgc1o, W_sgc1, W_ogc1s, W_ogc2, W_sgc2o,
        wt1, wt2, wt3, wt4, wt5, wt6, bcur, flag, ctr, N);

    // ---- CSR build (both graphs via y-grid)
    binscat1<<<dim3(gT, 2), 256, 0, stream>>>(o_rows, o_cols, o_vals,
                                              s_rows, s_cols, s_vals,
                                              bcur, temp_o, temp_s, E);
    scan_mark<<<1 + gMark, 512, 0, stream>>>(bcur, bbase, idx, flag, E, 2 * B);
    bs2_compact<<<dim3(gBuck, 3), 512, 0, stream>>>(
        bbase, temp_o, temp_s, rp_o, rp_s, ev_o, ev_s,
        flag, rlist, inv, ctr, N);

    // ---- Layer 1 GEMMs (x read once): tabA=x@W_ogc1, tabB=x@W_sgc1o, tabC=x@W_sgc1
    gemm_fused<NFEAT, 3, false><<<gM64, 256, 0, stream>>>(
        x, wt1, tabA, wt2, tabB, wt3, tabC, N);
    spmm2_csr<true, false><<<gR, 256, 0, stream>>>(
        rp_o, ev_o, tabA, rp_s, ev_s, tabB,
        b_ogc1, b_sgc1o, oxb, N, 1, nullptr, nullptr);     // o_x

    // ---- Layer 2+3a GEMMs (oxb read once): tabD = o_x@W_ogc1s, tabA = o_x@W_ogc2
    gemm_fused<NHID, 2, true><<<gM64, 256, 0, stream>>>(
        oxb, wt4, tabD, wt5, tabA, nullptr, nullptr, N);
    spmm2_csr<true, false><<<gR, 256, 0, stream>>>(
        rp_o, ev_o, tabD, rp_s, ev_s, tabC,
        b_ogc1s, b_sgc1, sxb, N, 1, nullptr, nullptr);     // s_x

    // ---- Layer 3b GEMM: tabB = s_x@W_sgc2o; sparse spmm -> compact h
    gemm_fused<NHID, 1, true><<<gM64, 256, 0, stream>>>(
        sxb, wt6, tabB, nullptr, nullptr, nullptr, nullptr, N);
    spmm2_csr<false, true><<<gRs, 256, 0, stream>>>(
        rp_o, ev_o, tabA, rp_s, ev_s, tabB,
        b_ogc2, b_sgc2o, h, N, 0, rlist, ctr);             // compact h

    // ---- Fused decoder
    dec_fused<<<gB, 128, 0, stream>>>(h, inv, idx0, idx1,
                                      W_dec1, b_dec1, W_dec2, b_dec2,
                                      (float*)d_out, B);
}

// Round 13
// 558.769 us; speedup vs baseline: 9.1006x; 1.0190x over previous
//
#include <hip/hip_runtime.h>
#include <hip/hip_bf16.h>

#define NFEAT 256
#define NHID 128
#define RELL 86
#define BSHIFT 9                 // bucket = row >> 9 (512 rows)
#define SCAT_TILE 8192           // edges per binscat block (32/thread)
#define TEMPCAP 12288            // per-bucket temp capacity (mean 8163, max ~8600)

typedef __attribute__((ext_vector_type(8))) short short8v;
typedef __attribute__((ext_vector_type(4))) float float4v;

static __device__ __forceinline__ unsigned short f2bf(float f) {
    union { float f; unsigned int u; } v; v.f = f;
    unsigned int r = v.u + 0x7FFF + ((v.u >> 16) & 1);   // RNE
    return (unsigned short)(r >> 16);
}
static __device__ __forceinline__ float asf(unsigned int u) {
    union { unsigned int u; float f; } v; v.u = u; return v.f;
}
static __device__ __forceinline__ float bf2f(unsigned short s) {
    return asf((unsigned int)s << 16);
}

// ---------------------------------------------------------------------------
// Init + weight prep mega-kernel: y<6 -> wt_prep for matrix y;
// y==6 -> zero flag, init bucket cursors, zero compact counter.
// ---------------------------------------------------------------------------
__global__ __launch_bounds__(256) void init_prep(
    const float* __restrict__ W0, const float* __restrict__ W1,
    const float* __restrict__ W2, const float* __restrict__ W3,
    const float* __restrict__ W4, const float* __restrict__ W5,
    unsigned short* __restrict__ T0, unsigned short* __restrict__ T1,
    unsigned short* __restrict__ T2, unsigned short* __restrict__ T3,
    unsigned short* __restrict__ T4, unsigned short* __restrict__ T5,
    int* __restrict__ bcur, int* __restrict__ flag, int* __restrict__ ctr,
    int N)
{
    const int y = blockIdx.y;
    if (y < 6) {
        const int K = (y < 3) ? NFEAT : NHID;
        const float* W = (y == 0) ? W0 : (y == 1) ? W1 : (y == 2) ? W2
                       : (y == 3) ? W3 : (y == 4) ? W4 : W5;
        unsigned short* T = (y == 0) ? T0 : (y == 1) ? T1 : (y == 2) ? T2
                          : (y == 3) ? T3 : (y == 4) ? T4 : T5;
        int i = blockIdx.x * 256 + threadIdx.x;
        if (i < K * 128) {
            int col = i & 127, k = i >> 7;
            T[col * K + k] = f2bf(W[i]);
        }
        return;
    }
    // y == 6: housekeeping
    const int i = blockIdx.x * 256 + threadIdx.x;
    if (i < N) flag[i] = 0;
    if (blockIdx.x == 0) {
        const int t = threadIdx.x;
        bcur[t] = t * TEMPCAP;           // graph o cursors
        bcur[256 + t] = t * TEMPCAP;     // graph s cursors
        if (t == 0) ctr[0] = 0;
    }
}

// ---------------------------------------------------------------------------
// Phase 1: bin edges by row>>9 into fixed-capacity temp slots,
// packed (row&511 | col<<9, val_bits).
// ---------------------------------------------------------------------------
__global__ __launch_bounds__(256) void binscat1(
    const int* __restrict__ ro, const int* __restrict__ co,
    const float* __restrict__ vo,
    const int* __restrict__ rs, const int* __restrict__ cs,
    const float* __restrict__ vs,
    int* __restrict__ bcur, int2* __restrict__ temp_o,
    int2* __restrict__ temp_s, int E)
{
    const int g = blockIdx.y;
    const int* rows = g ? rs : ro;
    const int* cols = g ? cs : co;
    const float* vals = g ? vs : vo;
    int* bc = bcur + g * 256;
    int2* temp = g ? temp_s : temp_o;

    __shared__ int hist[256];
    __shared__ int base[256];
    const int t = threadIdx.x;
    hist[t] = 0;
    __syncthreads();

    const int e0 = blockIdx.x * SCAT_TILE;
    int myrow[32];
    #pragma unroll
    for (int i = 0; i < 32; ++i) {
        int e = e0 + i * 256 + t;
        int r = (e < E) ? rows[e] : -1;
        myrow[i] = r;
        if (r >= 0) atomicAdd(&hist[r >> BSHIFT], 1);
    }
    __syncthreads();
    const int h = hist[t];
    if (h > 0) base[t] = atomicAdd(&bc[t], h);
    __syncthreads();
    hist[t] = (h > 0) ? base[t] : 0;     // reuse hist as within-block cursor
    __syncthreads();
    #pragma unroll
    for (int i = 0; i < 32; ++i) {
        const int r = myrow[i];
        if (r >= 0) {
            int e = e0 + i * 256 + t;
            int off = atomicAdd(&hist[r >> BSHIFT], 1);
            temp[off] = make_int2((r & 511) | (cols[e] << BSHIFT),
                                  __float_as_int(vals[e]));
        }
    }
}

// ---------------------------------------------------------------------------
// block 0: bucket-base scan from end cursors (count = bcur[b] - b*TEMPCAP).
// blocks 1..: mark needed rows from idx.
// ---------------------------------------------------------------------------
__global__ __launch_bounds__(512) void scan_mark(
    const int* __restrict__ bcur, int* __restrict__ bbase,
    const int* __restrict__ idx, int* __restrict__ flag, int E, int n2)
{
    if (blockIdx.x == 0) {
        __shared__ int sh[256];
        const int t = threadIdx.x;
        for (int g = 0; g < 2; ++g) {
            int v = 0;
            if (t < 256) { v = bcur[g * 256 + t] - t * TEMPCAP; sh[t] = v; }
            __syncthreads();
            for (int off = 1; off < 256; off <<= 1) {
                int u = (t < 256 && t >= off) ? sh[t - off] : 0;
                __syncthreads();
                if (t < 256) sh[t] += u;
                __syncthreads();
            }
            if (t < 256) {
                bbase[g * 257 + t] = sh[t] - v;   // exclusive
                if (t == 255) bbase[g * 257 + 256] = E;
            }
            __syncthreads();
        }
    } else {
        int i = (blockIdx.x - 1) * 512 + threadIdx.x;
        if (i < n2) flag[idx[i]] = 1;
    }
}

// ---------------------------------------------------------------------------
// y<2: per-bucket local counting sort (single temp read; edges staged in
// registers via static unroll). Writes rp + final CSR ev.
// y==2: compact marked rows -> rlist/inv/ctr.
// ---------------------------------------------------------------------------
__global__ __launch_bounds__(512) void bs2_compact(
    const int* __restrict__ bbase,
    const int2* __restrict__ temp_o, const int2* __restrict__ temp_s,
    int* __restrict__ rp_o, int* __restrict__ rp_s,
    int2* __restrict__ ev_o, int2* __restrict__ ev_s,
    const int* __restrict__ flag, int* __restrict__ rlist,
    int* __restrict__ inv, int* __restrict__ ctr, int N)
{
    if (blockIdx.y == 2) {
        int r = blockIdx.x * 512 + threadIdx.x;
        if (r < N && flag[r]) {
            int i = atomicAdd(ctr, 1);
            rlist[i] = r;
            inv[r] = i;
        }
        return;
    }
    const int g = blockIdx.y;
    const int2* temp = g ? temp_s : temp_o;
    int2* ev = g ? ev_s : ev_o;
    int* rp = g ? rp_s : rp_o;
    const int* bb = bbase + g * 257;

    __shared__ int lcnt[512];
    __shared__ int lpre[512];
    const int b = blockIdx.x;
    const int r0 = b << BSHIFT;
    const int t = threadIdx.x;
    const int e0 = bb[b];                      // final CSR base
    const int cntE = bb[b + 1] - e0;           // edges in bucket (<= TEMPCAP)
    const int t0 = b * TEMPCAP;                // temp base

    int2 myed[24];                             // 24*512 = TEMPCAP
    lcnt[t] = 0;
    __syncthreads();
    #pragma unroll
    for (int i = 0; i < 24; ++i) {
        int k = i * 512 + t;
        int2 pk = make_int2(0, 0);
        if (k < cntE) {
            pk = temp[t0 + k];
            atomicAdd(&lcnt[pk.x & 511], 1);
        }
        myed[i] = pk;
    }
    __syncthreads();
    const int v = lcnt[t];
    lpre[t] = v;
    __syncthreads();
    for (int off = 1; off < 512; off <<= 1) {
        int u = (t >= off) ? lpre[t - off] : 0;
        __syncthreads();
        lpre[t] += u;
        __syncthreads();
    }
    const int base = e0 + lpre[t] - v;
    const int r = r0 + t;
    if (r <= N) rp[r] = base;
    __syncthreads();
    lcnt[t] = base;                            // row cursors
    __syncthreads();
    #pragma unroll
    for (int i = 0; i < 24; ++i) {
        int k = i * 512 + t;
        if (k < cntE) {
            int2 pk = myed[i];
            int q = atomicAdd(&lcnt[pk.x & 511], 1);
            ev[q] = make_int2(pk.x >> BSHIFT, pk.y);
        }
    }
}

// ---------------------------------------------------------------------------
// Fused MFMA GEMM: S_m = X @ W_m for NM matrices, X staged ONCE (full K) in LDS.
// 4 waves over a 2x2 (row-half x col-half) grid: 6 LDS b128 reads per 8 MFMA.
// ---------------------------------------------------------------------------
template <int K, int NM, bool XBF>
__global__ __launch_bounds__(256) void gemm_fused(
    const void* __restrict__ Xv,
    const unsigned short* __restrict__ Wt0, unsigned short* __restrict__ S0,
    const unsigned short* __restrict__ Wt1, unsigned short* __restrict__ S1,
    const unsigned short* __restrict__ Wt2, unsigned short* __restrict__ S2,
    int Nrows)
{
    constexpr int AST = K + 8;
    __shared__ unsigned short As[64 * AST];
    __shared__ unsigned short Bs[128 * 72];

    const int t = threadIdx.x;
    const int l = t & 63;
    const int w = t >> 6;
    const int row_in = l & 15;
    const int kgrp = l >> 4;        // 0..3
    const int rhalf = w & 1;
    const int chalf = w >> 1;
    const int row0 = blockIdx.x * 64;

    {
        constexpr int QPR = K / 4;
        #pragma unroll
        for (int it = 0; it < 64 * QPR / 256; ++it) {
            int i = t + it * 256;
            int r = i / QPR, c4 = i % QPR;
            int gr = row0 + r;
            if (XBF) {
                ushort4 v = make_ushort4(0, 0, 0, 0);
                if (gr < Nrows)
                    v = *(const ushort4*)((const unsigned short*)Xv + (size_t)gr * K + c4 * 4);
                *(ushort4*)&As[r * AST + c4 * 4] = v;
            } else {
                float4 v = make_float4(0.f, 0.f, 0.f, 0.f);
                if (gr < Nrows)
                    v = *(const float4*)((const float*)Xv + (size_t)gr * K + c4 * 4);
                ushort4 b4;
                b4.x = f2bf(v.x); b4.y = f2bf(v.y); b4.z = f2bf(v.z); b4.w = f2bf(v.w);
                *(ushort4*)&As[r * AST + c4 * 4] = b4;
            }
        }
    }

    #pragma unroll
    for (int m = 0; m < NM; ++m) {
        const unsigned short* Wt = (m == 0) ? Wt0 : ((m == 1) ? Wt1 : Wt2);
        unsigned short* S = (m == 0) ? S0 : ((m == 1) ? S1 : S2);
        float4v acc[2][4];
        #pragma unroll
        for (int mi = 0; mi < 2; ++mi)
            #pragma unroll
            for (int n = 0; n < 4; ++n) acc[mi][n] = (float4v)(0.f);

        for (int kt = 0; kt < K / 64; ++kt) {
            __syncthreads();
            #pragma unroll
            for (int it = 0; it < 8; ++it) {
                int i = t + it * 256;
                int r = i >> 4, c4 = i & 15;
                *(ushort4*)&Bs[r * 72 + c4 * 4] =
                    *(const ushort4*)(Wt + (size_t)r * K + kt * 64 + c4 * 4);
            }
            __syncthreads();
            #pragma unroll
            for (int kc = 0; kc < 2; ++kc) {
                short8v a[2], b[4];
                #pragma unroll
                for (int mi = 0; mi < 2; ++mi) {
                    const unsigned short* pa =
                        &As[(rhalf * 32 + mi * 16 + row_in) * AST + kt * 64 + kc * 32 + kgrp * 8];
                    ((uint2*)&a[mi])[0] = *(const uint2*)pa;
                    ((uint2*)&a[mi])[1] = *(const uint2*)(pa + 4);
                }
                #pragma unroll
                for (int n = 0; n < 4; ++n) {
                    const unsigned short* pb =
                        &Bs[(chalf * 64 + n * 16 + row_in) * 72 + kc * 32 + kgrp * 8];
                    ((uint2*)&b[n])[0] = *(const uint2*)pb;
                    ((uint2*)&b[n])[1] = *(const uint2*)(pb + 4);
                }
                #pragma unroll
                for (int mi = 0; mi < 2; ++mi)
                    #pragma unroll
                    for (int n = 0; n < 4; ++n)
                        acc[mi][n] = __builtin_amdgcn_mfma_f32_16x16x32_bf16(
                            a[mi], b[n], acc[mi][n], 0, 0, 0);
            }
        }
        #pragma unroll
        for (int mi = 0; mi < 2; ++mi)
            #pragma unroll
            for (int n = 0; n < 4; ++n)
                #pragma unroll
                for (int r = 0; r < 4; ++r) {
                    int gr = row0 + rhalf * 32 + mi * 16 + kgrp * 4 + r;
                    int gc = chalf * 64 + n * 16 + row_in;
                    if (gr < Nrows) S[(size_t)gr * 128 + gc] = f2bf(acc[mi][n][r]);
                }
    }
}

// ---------------------------------------------------------------------------
// GEMM for s_x: sxb = relu(Yo @ Wt4 + Zs + b1 + b2), all K=128, bf16 in/out.
// ---------------------------------------------------------------------------
__global__ __launch_bounds__(256) void gemm_sx(
    const unsigned short* __restrict__ Yo,
    const unsigned short* __restrict__ Wt,
    const unsigned short* __restrict__ Zs,
    const float* __restrict__ b1, const float* __restrict__ b2,
    unsigned short* __restrict__ sxb, int Nrows)
{
    constexpr int AST = 136;
    __shared__ unsigned short As[64 * AST];
    __shared__ unsigned short Bs[128 * 72];

    const int t = threadIdx.x;
    const int l = t & 63;
    const int w = t >> 6;
    const int row_in = l & 15;
    const int kgrp = l >> 4;
    const int rhalf = w & 1;
    const int chalf = w >> 1;
    const int row0 = blockIdx.x * 64;

    #pragma unroll
    for (int it = 0; it < 8; ++it) {        // 64 rows * 32 quads / 256
        int i = t + it * 256;
        int r = i >> 5, c4 = i & 31;
        int gr = row0 + r;
        ushort4 v = make_ushort4(0, 0, 0, 0);
        if (gr < Nrows) v = *(const ushort4*)(Yo + (size_t)gr * 128 + c4 * 4);
        *(ushort4*)&As[r * AST + c4 * 4] = v;
    }

    float4v acc[2][4];
    #pragma unroll
    for (int mi = 0; mi < 2; ++mi)
        #pragma unroll
        for (int n = 0; n < 4; ++n) acc[mi][n] = (float4v)(0.f);

    for (int kt = 0; kt < 2; ++kt) {
        __syncthreads();
        #pragma unroll
        for (int it = 0; it < 8; ++it) {
            int i = t + it * 256;
            int r = i >> 4, c4 = i & 15;
            *(ushort4*)&Bs[r * 72 + c4 * 4] =
                *(const ushort4*)(Wt + (size_t)r * 128 + kt * 64 + c4 * 4);
        }
        __syncthreads();
        #pragma unroll
        for (int kc = 0; kc < 2; ++kc) {
            short8v a[2], b[4];
            #pragma unroll
            for (int mi = 0; mi < 2; ++mi) {
                const unsigned short* pa =
                    &As[(rhalf * 32 + mi * 16 + row_in) * AST + kt * 64 + kc * 32 + kgrp * 8];
                ((uint2*)&a[mi])[0] = *(const uint2*)pa;
                ((uint2*)&a[mi])[1] = *(const uint2*)(pa + 4);
            }
            #pragma unroll
            for (int n = 0; n < 4; ++n) {
                const unsigned short* pb =
                    &Bs[(chalf * 64 + n * 16 + row_in) * 72 + kc * 32 + kgrp * 8];
                ((uint2*)&b[n])[0] = *(const uint2*)pb;
                ((uint2*)&b[n])[1] = *(const uint2*)(pb + 4);
            }
            #pragma unroll
            for (int mi = 0; mi < 2; ++mi)
                #pragma unroll
                for (int n = 0; n < 4; ++n)
                    acc[mi][n] = __builtin_amdgcn_mfma_f32_16x16x32_bf16(
                        a[mi], b[n], acc[mi][n], 0, 0, 0);
        }
    }
    #pragma unroll
    for (int mi = 0; mi < 2; ++mi)
        #pragma unroll
        for (int n = 0; n < 4; ++n)
            #pragma unroll
            for (int r = 0; r < 4; ++r) {
                int gr = row0 + rhalf * 32 + mi * 16 + kgrp * 4 + r;
                int gc = chalf * 64 + n * 16 + row_in;
                if (gr < Nrows) {
                    float vfin = acc[mi][n][r] + bf2f(Zs[(size_t)gr * 128 + gc])
                               + b1[gc] + b2[gc];
                    sxb[(size_t)gr * 128 + gc] = f2bf(fmaxf(vfin, 0.f));
                }
            }
}

// ---------------------------------------------------------------------------
// GEMM for h (compact rows): h[i] = Yo[rlist[i]]@Wt5 + Ys2[i]@Wt6 + b1 + b2
// ---------------------------------------------------------------------------
__global__ __launch_bounds__(256) void gemm_h(
    const unsigned short* __restrict__ Yo, const int* __restrict__ rlist,
    const int* __restrict__ pcnt,
    const unsigned short* __restrict__ Ys2,
    const unsigned short* __restrict__ Wt5, const unsigned short* __restrict__ Wt6,
    const float* __restrict__ b1, const float* __restrict__ b2,
    float* __restrict__ h)
{
    constexpr int AST = 136;
    __shared__ unsigned short As1[64 * AST];
    __shared__ unsigned short As2[64 * AST];
    __shared__ unsigned short Bs[128 * 72];

    const int cnt = *pcnt;
    const int row0 = blockIdx.x * 64;
    if (row0 >= cnt) return;

    const int t = threadIdx.x;
    const int l = t & 63;
    const int w = t >> 6;
    const int row_in = l & 15;
    const int kgrp = l >> 4;
    const int rhalf = w & 1;
    const int chalf = w >> 1;

    #pragma unroll
    for (int it = 0; it < 8; ++it) {
        int i = t + it * 256;
        int r = i >> 5, c4 = i & 31;
        int gr = row0 + r;
        ushort4 v1 = make_ushort4(0, 0, 0, 0);
        ushort4 v2 = make_ushort4(0, 0, 0, 0);
        if (gr < cnt) {
            int src = rlist[gr];
            v1 = *(const ushort4*)(Yo + (size_t)src * 128 + c4 * 4);
            v2 = *(const ushort4*)(Ys2 + (size_t)gr * 128 + c4 * 4);
        }
        *(ushort4*)&As1[r * AST + c4 * 4] = v1;
        *(ushort4*)&As2[r * AST + c4 * 4] = v2;
    }

    float4v acc[2][4];
    #pragma unroll
    for (int mi = 0; mi < 2; ++mi)
        #pragma unroll
        for (int n = 0; n < 4; ++n) acc[mi][n] = (float4v)(0.f);

    #pragma unroll
    for (int pp = 0; pp < 2; ++pp) {
        const unsigned short* Wt = pp ? Wt6 : Wt5;
        const unsigned short* As = pp ? As2 : As1;
        for (int kt = 0; kt < 2; ++kt) {
            __syncthreads();
            #pragma unroll
            for (int it = 0; it < 8; ++it) {
                int i = t + it * 256;
                int r = i >> 4, c4 = i & 15;
                *(ushort4*)&Bs[r * 72 + c4 * 4] =
                    *(const ushort4*)(Wt + (size_t)r * 128 + kt * 64 + c4 * 4);
            }
            __syncthreads();
            #pragma unroll
            for (int kc = 0; kc < 2; ++kc) {
                short8v a[2], b[4];
                #pragma unroll
                for (int mi = 0; mi < 2; ++mi) {
                    const unsigned short* pa =
                        &As[(rhalf * 32 + mi * 16 + row_in) * AST + kt * 64 + kc * 32 + kgrp * 8];
                    ((uint2*)&a[mi])[0] = *(const uint2*)pa;
                    ((uint2*)&a[mi])[1] = *(const uint2*)(pa + 4);
                }
                #pragma unroll
                for (int n = 0; n < 4; ++n) {
                    const unsigned short* pb =
                        &Bs[(chalf * 64 + n * 16 + row_in) * 72 + kc * 32 + kgrp * 8];
                    ((uint2*)&b[n])[0] = *(const uint2*)pb;
                    ((uint2*)&b[n])[1] = *(const uint2*)(pb + 4);
                }
                #pragma unroll
                for (int mi = 0; mi < 2; ++mi)
                    #pragma unroll
                    for (int n = 0; n < 4; ++n)
                        acc[mi][n] = __builtin_amdgcn_mfma_f32_16x16x32_bf16(
                            a[mi], b[n], acc[mi][n], 0, 0, 0);
            }
        }
    }
    #pragma unroll
    for (int mi = 0; mi < 2; ++mi)
        #pragma unroll
        for (int n = 0; n < 4; ++n)
            #pragma unroll
            for (int r = 0; r < 4; ++r) {
                int gr = row0 + rhalf * 32 + mi * 16 + kgrp * 4 + r;
                int gc = chalf * 64 + n * 16 + row_in;
                if (gr < cnt)
                    h[(size_t)gr * 128 + gc] = acc[mi][n][r] + b1[gc] + b2[gc];
            }
}

// ---------------------------------------------------------------------------
// spmm1: fused dual-graph CSR SpMM with bias+relu, bf16 out (layer 1).
// ---------------------------------------------------------------------------
#define GS(S, pk) (*(const unsigned*)((S) + ((size_t)(pk).x << 7) + l2))
#define ACCV(pk, uu) { float vv = __int_as_float((pk).y); \
    ax = fmaf(vv, asf((uu) << 16), ax); ay = fmaf(vv, asf((uu) & 0xffff0000u), ay); }

__global__ __launch_bounds__(256) void spmm1_k(
    const int* __restrict__ rp_a, const int2* __restrict__ ev_a,
    const unsigned short* __restrict__ Sa,
    const int* __restrict__ rp_b, const int2* __restrict__ ev_b,
    const unsigned short* __restrict__ Sb,
    const float* __restrict__ b1, const float* __restrict__ b2,
    unsigned short* __restrict__ out, int N)
{
    const int row = blockIdx.x * 4 + (threadIdx.x >> 6);
    if (row >= N) return;
    const int l2 = (threadIdx.x & 63) << 1;

    float2 bv1 = *(const float2*)(b1 + l2);
    float2 bv2 = *(const float2*)(b2 + l2);
    float ax = bv1.x + bv2.x;
    float ay = bv1.y + bv2.y;

    #pragma unroll
    for (int g = 0; g < 2; ++g) {
        const int* __restrict__ rp = g ? rp_b : rp_a;
        const int2* __restrict__ ev = g ? ev_b : ev_a;
        const unsigned short* __restrict__ S = g ? Sb : Sa;
        int e = rp[row];
        const int e1 = rp[row + 1];
        for (; e + 8 <= e1; e += 8) {
            const int2 p0 = ev[e], p1 = ev[e+1], p2 = ev[e+2], p3 = ev[e+3];
            const int2 p4 = ev[e+4], p5 = ev[e+5], p6 = ev[e+6], p7 = ev[e+7];
            const unsigned u0 = GS(S,p0), u1 = GS(S,p1), u2 = GS(S,p2), u3 = GS(S,p3);
            const unsigned u4 = GS(S,p4), u5 = GS(S,p5), u6 = GS(S,p6), u7 = GS(S,p7);
            ACCV(p0,u0) ACCV(p1,u1) ACCV(p2,u2) ACCV(p3,u3)
            ACCV(p4,u4) ACCV(p5,u5) ACCV(p6,u6) ACCV(p7,u7)
        }
        for (; e + 4 <= e1; e += 4) {
            const int2 p0 = ev[e], p1 = ev[e+1], p2 = ev[e+2], p3 = ev[e+3];
            const unsigned u0 = GS(S,p0), u1 = GS(S,p1), u2 = GS(S,p2), u3 = GS(S,p3);
            ACCV(p0,u0) ACCV(p1,u1) ACCV(p2,u2) ACCV(p3,u3)
        }
        for (; e < e1; ++e) {
            const int2 p0 = ev[e];
            const unsigned u0 = GS(S,p0);
            ACCV(p0,u0)
        }
    }
    ax = fmaxf(ax, 0.f); ay = fmaxf(ay, 0.f);
    unsigned pk = (unsigned)f2bf(ax) | ((unsigned)f2bf(ay) << 16);
    ((unsigned*)out)[((size_t)row << 6) + (l2 >> 1)] = pk;
}

// ---------------------------------------------------------------------------
// spmm_split: Yo = A_o * oxb, Zs = A_s * tabC (no bias, no relu), bf16 out.
// ---------------------------------------------------------------------------
__global__ __launch_bounds__(256) void spmm_split(
    const int* __restrict__ rp_a, const int2* __restrict__ ev_a,
    const unsigned short* __restrict__ Sa,
    const int* __restrict__ rp_b, const int2* __restrict__ ev_b,
    const unsigned short* __restrict__ Sb,
    unsigned short* __restrict__ Yo, unsigned short* __restrict__ Zs, int N)
{
    const int row = blockIdx.x * 4 + (threadIdx.x >> 6);
    if (row >= N) return;
    const int l2 = (threadIdx.x & 63) << 1;

    #pragma unroll
    for (int g = 0; g < 2; ++g) {
        const int* __restrict__ rp = g ? rp_b : rp_a;
        const int2* __restrict__ ev = g ? ev_b : ev_a;
        const unsigned short* __restrict__ S = g ? Sb : Sa;
        unsigned short* __restrict__ out = g ? Zs : Yo;
        float ax = 0.f, ay = 0.f;
        int e = rp[row];
        const int e1 = rp[row + 1];
        for (; e + 8 <= e1; e += 8) {
            const int2 p0 = ev[e], p1 = ev[e+1], p2 = ev[e+2], p3 = ev[e+3];
            const int2 p4 = ev[e+4], p5 = ev[e+5], p6 = ev[e+6], p7 = ev[e+7];
            const unsigned u0 = GS(S,p0), u1 = GS(S,p1), u2 = GS(S,p2), u3 = GS(S,p3);
            const unsigned u4 = GS(S,p4), u5 = GS(S,p5), u6 = GS(S,p6), u7 = GS(S,p7);
            ACCV(p0,u0) ACCV(p1,u1) ACCV(p2,u2) ACCV(p3,u3)
            ACCV(p4,u4) ACCV(p5,u5) ACCV(p6,u6) ACCV(p7,u7)
        }
        for (; e + 4 <= e1; e += 4) {
            const int2 p0 = ev[e], p1 = ev[e+1], p2 = ev[e+2], p3 = ev[e+3];
            const unsigned u0 = GS(S,p0), u1 = GS(S,p1), u2 = GS(S,p2), u3 = GS(S,p3);
            ACCV(p0,u0) ACCV(p1,u1) ACCV(p2,u2) ACCV(p3,u3)
        }
        for (; e < e1; ++e) {
            const int2 p0 = ev[e];
            const unsigned u0 = GS(S,p0);
            ACCV(p0,u0)
        }
        unsigned pk = (unsigned)f2bf(ax) | ((unsigned)f2bf(ay) << 16);
        ((unsigned*)out)[((size_t)row << 6) + (l2 >> 1)] = pk;
    }
}

// ---------------------------------------------------------------------------
// spmm_s_sparse: Ys2[i] = A_s * sxb at row rlist[i], bf16 compact out.
// ---------------------------------------------------------------------------
__global__ __launch_bounds__(256) void spmm_s_sparse(
    const int* __restrict__ rp, const int2* __restrict__ ev,
    const unsigned short* __restrict__ S,
    const int* __restrict__ rlist, const int* __restrict__ pcnt,
    unsigned short* __restrict__ out)
{
    const int gi = blockIdx.x * 4 + (threadIdx.x >> 6);
    if (gi >= *pcnt) return;
    const int row = rlist[gi];
    const int l2 = (threadIdx.x & 63) << 1;

    float ax = 0.f, ay = 0.f;
    int e = rp[row];
    const int e1 = rp[row + 1];
    for (; e + 8 <= e1; e += 8) {
        const int2 p0 = ev[e], p1 = ev[e+1], p2 = ev[e+2], p3 = ev[e+3];
        const int2 p4 = ev[e+4], p5 = ev[e+5], p6 = ev[e+6], p7 = ev[e+7];
        const unsigned u0 = GS(S,p0), u1 = GS(S,p1), u2 = GS(S,p2), u3 = GS(S,p3);
        const unsigned u4 = GS(S,p4), u5 = GS(S,p5), u6 = GS(S,p6), u7 = GS(S,p7);
        ACCV(p0,u0) ACCV(p1,u1) ACCV(p2,u2) ACCV(p3,u3)
        ACCV(p4,u4) ACCV(p5,u5) ACCV(p6,u6) ACCV(p7,u7)
    }
    for (; e + 4 <= e1; e += 4) {
        const int2 p0 = ev[e], p1 = ev[e+1], p2 = ev[e+2], p3 = ev[e+3];
        const unsigned u0 = GS(S,p0), u1 = GS(S,p1), u2 = GS(S,p2), u3 = GS(S,p3);
        ACCV(p0,u0) ACCV(p1,u1) ACCV(p2,u2) ACCV(p3,u3)
    }
    for (; e < e1; ++e) {
        const int2 p0 = ev[e];
        const unsigned u0 = GS(S,p0);
        ACCV(p0,u0)
    }
    unsigned pk = (unsigned)f2bf(ax) | ((unsigned)f2bf(ay) << 16);
    ((unsigned*)out)[((size_t)gi << 6) + (l2 >> 1)] = pk;
}
#undef GS
#undef ACCV

// ---------------------------------------------------------------------------
// Fused decoder: o1 tile stays in LDS between the two small GEMMs.
// ---------------------------------------------------------------------------
__global__ __launch_bounds__(128) void dec_fused(
    const float* __restrict__ h, const int* __restrict__ inv,
    const int* __restrict__ idx0, const int* __restrict__ idx1,
    const float* __restrict__ Wd1, const float* __restrict__ bd1,
    const float* __restrict__ Wd2, const float* __restrict__ bd2,
    float* __restrict__ out, int B)
{
    __shared__ __align__(16) float fs[16 * 256];
    __shared__ __align__(16) float os[16 * 128];
    const int t = threadIdx.x;
    const int b0 = blockIdx.x * 16;
    #pragma unroll
    for (int r = 0; r < 16; ++r) {
        const int b = b0 + r;
        fs[r * 256 + t]       = h[(long)inv[idx0[b]] * 128 + t];
        fs[r * 256 + 128 + t] = h[(long)inv[idx1[b]] * 128 + t];
    }
    __syncthreads();

    {
        const float4* fs4 = (const float4*)fs;
        float acc[16];
        #pragma unroll
        for (int r = 0; r < 16; ++r) acc[r] = 0.f;
        for (int kc = 0; kc < 64; ++kc) {
            const float w0 = Wd1[(kc * 4 + 0) * 128 + t];
            const float w1 = Wd1[(kc * 4 + 1) * 128 + t];
            const float w2 = Wd1[(kc * 4 + 2) * 128 + t];
            const float w3 = Wd1[(kc * 4 + 3) * 128 + t];
            #pragma unroll
            for (int r = 0; r < 16; ++r) {
                const float4 xv = fs4[r * 64 + kc];
                acc[r] = fmaf(xv.x, w0, acc[r]);
                acc[r] = fmaf(xv.y, w1, acc[r]);
                acc[r] = fmaf(xv.z, w2, acc[r]);
                acc[r] = fmaf(xv.w, w3, acc[r]);
            }
        }
        #pragma unroll
        for (int r = 0; r < 16; ++r)
            os[r * 128 + t] = acc[r] + bd1[t];
    }
    __syncthreads();

    {
        const float4* os4 = (const float4*)os;
        float acc[16];
        #pragma unroll
        for (int r = 0; r < 16; ++r) acc[r] = 0.f;
        const bool act = (t < RELL);
        for (int kc = 0; kc < 32; ++kc) {
            const float w0 = act ? Wd2[(kc * 4 + 0) * RELL + t] : 0.f;
            const float w1 = act ? Wd2[(kc * 4 + 1) * RELL + t] : 0.f;
            const float w2 = act ? Wd2[(kc * 4 + 2) * RELL + t] : 0.f;
            const float w3 = act ? Wd2[(kc * 4 + 3) * RELL + t] : 0.f;
            #pragma unroll
            for (int r = 0; r < 16; ++r) {
                const float4 xv = os4[r * 32 + kc];
                acc[r] = fmaf(xv.x, w0, acc[r]);
                acc[r] = fmaf(xv.y, w1, acc[r]);
                acc[r] = fmaf(xv.z, w2, acc[r]);
                acc[r] = fmaf(xv.w, w3, acc[r]);
            }
        }
        if (act) {
            #pragma unroll
            for (int r = 0; r < 16; ++r)
                out[(long)(b0 + r) * RELL + t] = acc[r] + bd2[t];
        }
    }
}

extern "C" void kernel_launch(void* const* d_in, const int* in_sizes, int n_in,
                              void* d_out, int out_size, void* d_ws, size_t ws_size,
                              hipStream_t stream) {
    const float* x      = (const float*)d_in[0];
    const int*   o_rows = (const int*)  d_in[1];
    const int*   o_cols = (const int*)  d_in[2];
    const float* o_vals = (const float*)d_in[3];
    const int*   s_rows = (const int*)  d_in[4];
    const int*   s_cols = (const int*)  d_in[5];
    const float* s_vals = (const float*)d_in[6];
    const int*   idx    = (const int*)  d_in[7];
    const float* W_ogc1  = (const float*)d_in[8];   const float* b_ogc1  = (const float*)d_in[9];
    const float* W_sgc1o = (const float*)d_in[10];  const float* b_sgc1o = (const float*)d_in[11];
    const float* W_sgc1  = (const float*)d_in[12];  const float* b_sgc1  = (const float*)d_in[13];
    const float* W_ogc1s = (const float*)d_in[14];  const float* b_ogc1s = (const float*)d_in[15];
    const float* W_ogc2  = (const float*)d_in[16];  const float* b_ogc2  = (const float*)d_in[17];
    const float* W_sgc2o = (const float*)d_in[18];  const float* b_sgc2o = (const float*)d_in[19];
    const float* W_dec1  = (const float*)d_in[20];  const float* b_dec1  = (const float*)d_in[21];
    const float* W_dec2  = (const float*)d_in[22];  const float* b_dec2  = (const float*)d_in[23];

    const int N = in_sizes[0] / NFEAT;   // 100000
    const int E = in_sizes[1];           // 1600000
    const int B = in_sizes[7] / 2;       // 16384
    const int* idx0 = idx;
    const int* idx1 = idx + B;

    // ---- workspace layout (float units) ----
    float* p = (float*)d_ws;
    const size_t N64 = (size_t)N * 64;    // one bf16 [N,128] table in float units
    float* h    = p;  p += (size_t)2 * B * 128;      // compact fp32 [<=2B,128]
    unsigned short* oxb  = (unsigned short*)p; p += N64;   // o_x bf16
    unsigned short* sxb  = (unsigned short*)p; p += N64;   // s_x bf16
    unsigned short* tabA = (unsigned short*)p; p += N64;
    unsigned short* tabB = (unsigned short*)p; p += N64;
    unsigned short* tabC = (unsigned short*)p; p += N64;
    unsigned short* Yo   = (unsigned short*)p; p += N64;   // A_o * o_x
    unsigned short* Zs   = (unsigned short*)p; p += N64;   // A_s * tabC
    unsigned short* Ys2  = (unsigned short*)p; p += (size_t)2 * B * 64;  // compact A_s*s_x
    unsigned short* wt1 = (unsigned short*)p; p += 16384;   // [128,256] bf16
    unsigned short* wt2 = (unsigned short*)p; p += 16384;
    unsigned short* wt3 = (unsigned short*)p; p += 16384;
    unsigned short* wt4 = (unsigned short*)p; p += 8192;    // [128,128] bf16
    unsigned short* wt5 = (unsigned short*)p; p += 8192;
    unsigned short* wt6 = (unsigned short*)p; p += 8192;
    int* rp_o = (int*)p; p += (size_t)N + 2;
    int* rp_s = (int*)p; p += (size_t)N + 2;
    int2* ev_o = (int2*)p; p += 2 * (size_t)E;
    int2* ev_s = (int2*)p; p += 2 * (size_t)E;
    int* bbase = (int*)p; p += 516;                  // [2][257] bucket bases
    int* bcur  = (int*)p; p += 512;                  // [2][256] bucket cursors
    int* flag  = (int*)p; p += (size_t)N;            // needed-row flags
    int* rlist = (int*)p; p += (size_t)N;            // compact row list
    int* inv   = (int*)p; p += (size_t)N;            // node -> compact index
    int* ctr   = (int*)p; p += 2;                    // compact count
    // temp binning buffers alias tabA/tabB (dead until first GEMM)
    int2* temp_o = (int2*)tabA;                      // 256*TEMPCAP int2 = 25.2 MB
    int2* temp_s = (int2*)tabB;

    const int gM64 = (N + 63) / 64;       // 1563
    const int gR = (N + 3) / 4;           // 25000
    const int gRs = (2 * B + 3) / 4;      // 8192 (sparse rows <= 2B)
    const int gH = (2 * B + 63) / 64;     // 512
    const int gB = B / 16;                // 1024
    const int gT = (E + SCAT_TILE - 1) / SCAT_TILE;                   // 196
    const int gBuck = (N + (1 << BSHIFT) - 1) >> BSHIFT;              // 196
    const int gFlag = (N + 255) / 256;                                // 391
    const int gMark = (2 * B + 511) / 512;                            // 64

    // ---- init + weight prep
    init_prep<<<dim3(gFlag, 7), 256, 0, stream>>>(
        W_ogc1, W_sgc1o, W_sgc1, W_ogc1s, W_ogc2, W_sgc2o,
        wt1, wt2, wt3, wt4, wt5, wt6, bcur, flag, ctr, N);

    // ---- CSR build (both graphs via y-grid)
    binscat1<<<dim3(gT, 2), 256, 0, stream>>>(o_rows, o_cols, o_vals,
                                              s_rows, s_cols, s_vals,
                                              bcur, temp_o, temp_s, E);
    scan_mark<<<1 + gMark, 512, 0, stream>>>(bcur, bbase, idx, flag, E, 2 * B);
    bs2_compact<<<dim3(gBuck, 3), 512, 0, stream>>>(
        bbase, temp_o, temp_s, rp_o, rp_s, ev_o, ev_s,
        flag, rlist, inv, ctr, N);

    // ---- Layer 1 GEMMs (x read once): tabA=x@W_ogc1, tabB=x@W_sgc1o, tabC=x@W_sgc1
    gemm_fused<NFEAT, 3, false><<<gM64, 256, 0, stream>>>(
        x, wt1, tabA, wt2, tabB, wt3, tabC, N);
    spmm1_k<<<gR, 256, 0, stream>>>(rp_o, ev_o, tabA, rp_s, ev_s, tabB,
                                    b_ogc1, b_sgc1o, oxb, N);        // o_x

    // ---- spmm_split: Yo = A_o*o_x, Zs = A_s*tabC  (serves layers 2 AND 3)
    spmm_split<<<gR, 256, 0, stream>>>(rp_o, ev_o, oxb, rp_s, ev_s, tabC,
                                       Yo, Zs, N);

    // ---- s_x = relu(Yo@W_ogc1s + Zs + b_ogc1s + b_sgc1)
    gemm_sx<<<gM64, 256, 0, stream>>>(Yo, wt4, Zs, b_ogc1s, b_sgc1, sxb, N);

    // ---- Ys2 = A_s*s_x (sparse rows); h = Yo[rlist]@W_ogc2 + Ys2@W_sgc2o + b
    spmm_s_sparse<<<gRs, 256, 0, stream>>>(rp_s, ev_s, sxb, rlist, ctr, Ys2);
    gemm_h<<<gH, 256, 0, stream>>>(Yo, rlist, ctr, Ys2, wt5, wt6,
                                   b_ogc2, b_sgc2o, h);

    // ---- Fused decoder
    dec_fused<<<gB, 128, 0, stream>>>(h, inv, idx0, idx1,
                                      W_dec1, b_dec1, W_dec2, b_dec2,
                                      (float*)d_out, B);
}